// Round 2
// baseline (6513.469 us; speedup 1.0000x reference)
//
#include <hip/hip_runtime.h>

// Sizes
#define TW 120     // window / number of parallel t-steps
#define TB 2       // batch
#define TJ 24      // joints
#define TH 128     // hidden
#define TNH 8      // heads
#define THD 16     // head dim
#define TF 256     // ffn
#define TD 216     // input dim
#define TROWS (TW*TB*TJ)   // 5760 rows of H
#define TEMB (TJ*TH)       // 3072

// ---------------- embedding + positional encoding ----------------
// x0[(t*TB+b)*TEMB + e] = sum_d concat[t,b,d]*Wemb[e,d] + bemb[e] + pe[t,e]
__global__ void embed_kernel(const float* __restrict__ src, const float* __restrict__ tgt,
                             const float* __restrict__ Wemb, const float* __restrict__ bemb,
                             float* __restrict__ x0) {
    int idx = blockIdx.x * 256 + threadIdx.x;
    if (idx >= TW * TB * TEMB) return;
    int e = idx % TEMB;
    int b = (idx / TEMB) % TB;
    int t = idx / (TEMB * TB);
    const float* row = (t < 60) ? (src + ((size_t)b * 60 + t) * TD)
                                : (tgt + ((size_t)b * 61 + (t - 60)) * TD);
    const float* wrow = Wemb + (size_t)e * TD;
    float acc = bemb[e];
    #pragma unroll 4
    for (int d = 0; d < TD; ++d) acc += row[d] * wrow[d];
    // positional encoding: freq = exp(-(e & ~1) * ln(10000)/3072)
    float freq = expf((float)(e & ~1) * (-9.2103403719761836f / 3072.0f));
    float ang = (float)t * freq;
    acc += (e & 1) ? cosf(ang) : sinf(ang);
    x0[idx] = acc;
}

// ---------------- qkv projection, per-joint weights (temporal) ----------------
// X rows laid out [(t*TB+b)*TJ + j]*TH. Wqkv: (TJ, 3H, H) for one layer. bqkv: (TJ, 3H)
__global__ void qkv_joint_kernel(const float* __restrict__ X,
                                 const float* __restrict__ Wqkv, const float* __restrict__ bqkv,
                                 float* __restrict__ Q, float* __restrict__ K, float* __restrict__ V) {
    int idx = blockIdx.x * 256 + threadIdx.x;
    if (idx >= TROWS * 3 * TH) return;
    int hp = idx % (3 * TH);
    int rj = idx / (3 * TH);
    int j = rj % TJ;
    const float* x = X + (size_t)rj * TH;
    const float* wt = Wqkv + ((size_t)j * 3 * TH + hp) * TH;
    float acc = bqkv[j * 3 * TH + hp];
    #pragma unroll 4
    for (int k = 0; k < TH; ++k) acc += x[k] * wt[k];
    float* dst = (hp < TH) ? Q : ((hp < 2 * TH) ? K : V);
    dst[(size_t)rj * TH + (hp & (TH - 1))] = acc;
}

// ---------------- qkv projection, shared weights (spatial) ----------------
__global__ void qkv_shared_kernel(const float* __restrict__ X,
                                  const float* __restrict__ Wqkv, const float* __restrict__ bqkv,
                                  float* __restrict__ Q, float* __restrict__ K, float* __restrict__ V) {
    int idx = blockIdx.x * 256 + threadIdx.x;
    if (idx >= TROWS * 3 * TH) return;
    int hp = idx % (3 * TH);
    int rj = idx / (3 * TH);
    const float* x = X + (size_t)rj * TH;
    const float* wt = Wqkv + (size_t)hp * TH;
    float acc = bqkv[hp];
    #pragma unroll 4
    for (int k = 0; k < TH; ++k) acc += x[k] * wt[k];
    float* dst = (hp < TH) ? Q : ((hp < 2 * TH) ? K : V);
    dst[(size_t)rj * TH + (hp & (TH - 1))] = acc;
}

// ---------------- baseline causal temporal attention ----------------
// block per (q, b, j, head); 128 threads; keys 0..q
__global__ void attn_causal_kernel(const float* __restrict__ Q, const float* __restrict__ K,
                                   const float* __restrict__ V, float* __restrict__ O) {
    int blk = blockIdx.x;
    int head = blk % TNH;
    int j = (blk / TNH) % TJ;
    int b = (blk / (TNH * TJ)) % TB;
    int q = blk / (TNH * TJ * TB);
    int tid = threadIdx.x;
    __shared__ float p[128];
    __shared__ float red[128];
    __shared__ float qv[THD];
    int rowq = (q * TB + b) * TJ + j;
    if (tid < THD) qv[tid] = Q[(size_t)rowq * TH + head * THD + tid];
    __syncthreads();
    float s = -1e30f;
    if (tid <= q) {
        int rowk = (tid * TB + b) * TJ + j;
        const float* kv = K + (size_t)rowk * TH + head * THD;
        float acc = 0.f;
        #pragma unroll
        for (int d = 0; d < THD; ++d) acc += qv[d] * kv[d];
        s = acc * 0.25f;
    }
    red[tid] = s; __syncthreads();
    for (int off = 64; off > 0; off >>= 1) { if (tid < off) red[tid] = fmaxf(red[tid], red[tid + off]); __syncthreads(); }
    float m = red[0];
    __syncthreads();
    float e = (tid <= q) ? __expf(s - m) : 0.f;
    p[tid] = e; red[tid] = e; __syncthreads();
    for (int off = 64; off > 0; off >>= 1) { if (tid < off) red[tid] += red[tid + off]; __syncthreads(); }
    float denom = red[0];
    if (tid < THD) {
        float acc = 0.f;
        for (int k = 0; k <= q; ++k)
            acc += p[k] * V[(size_t)((k * TB + b) * TJ + j) * TH + head * THD + tid];
        O[(size_t)rowq * TH + head * THD + tid] = acc / denom;
    }
}

// ---------------- special-row temporal attention (single query t) ----------------
// keys 0..t-1 from baseline Kb/Vb; key t from special Ks/Vs
__global__ void attn_special_kernel(const float* __restrict__ Qs, const float* __restrict__ Ks,
                                    const float* __restrict__ Vs, const float* __restrict__ Kb,
                                    const float* __restrict__ Vb, float* __restrict__ O) {
    int blk = blockIdx.x;
    int head = blk % TNH;
    int j = (blk / TNH) % TJ;
    int b = (blk / (TNH * TJ)) % TB;
    int t = blk / (TNH * TJ * TB);
    int tid = threadIdx.x;
    __shared__ float p[128];
    __shared__ float red[128];
    __shared__ float qv[THD];
    int rowq = (t * TB + b) * TJ + j;
    if (tid < THD) qv[tid] = Qs[(size_t)rowq * TH + head * THD + tid];
    __syncthreads();
    float s = -1e30f;
    if (tid <= t) {
        int rowk = (tid * TB + b) * TJ + j;
        const float* kv = ((tid == t) ? Ks : Kb) + (size_t)rowk * TH + head * THD;
        float acc = 0.f;
        #pragma unroll
        for (int d = 0; d < THD; ++d) acc += qv[d] * kv[d];
        s = acc * 0.25f;
    }
    red[tid] = s; __syncthreads();
    for (int off = 64; off > 0; off >>= 1) { if (tid < off) red[tid] = fmaxf(red[tid], red[tid + off]); __syncthreads(); }
    float m = red[0];
    __syncthreads();
    float e = (tid <= t) ? __expf(s - m) : 0.f;
    p[tid] = e; red[tid] = e; __syncthreads();
    for (int off = 64; off > 0; off >>= 1) { if (tid < off) red[tid] += red[tid + off]; __syncthreads(); }
    float denom = red[0];
    if (tid < THD) {
        float acc = 0.f;
        for (int k = 0; k < t; ++k)
            acc += p[k] * Vb[(size_t)((k * TB + b) * TJ + j) * TH + head * THD + tid];
        acc += p[t] * Vs[(size_t)rowq * TH + head * THD + tid];
        O[(size_t)rowq * TH + head * THD + tid] = acc / denom;
    }
}

// ---------------- spatial attention over joints (no mask) ----------------
// block per (t, b, head, qj); 64 threads; 24 keys
__global__ void attn_spatial_kernel(const float* __restrict__ Q, const float* __restrict__ K,
                                    const float* __restrict__ V, float* __restrict__ O) {
    int blk = blockIdx.x;
    int qj = blk % TJ;
    int head = (blk / TJ) % TNH;
    int b = (blk / (TJ * TNH)) % TB;
    int t = blk / (TJ * TNH * TB);
    int tid = threadIdx.x;
    __shared__ float p[64];
    __shared__ float red[64];
    __shared__ float qv[THD];
    int base = (t * TB + b) * TJ;
    if (tid < THD) qv[tid] = Q[(size_t)(base + qj) * TH + head * THD + tid];
    __syncthreads();
    float s = -1e30f;
    if (tid < TJ) {
        const float* kv = K + (size_t)(base + tid) * TH + head * THD;
        float acc = 0.f;
        #pragma unroll
        for (int d = 0; d < THD; ++d) acc += qv[d] * kv[d];
        s = acc * 0.25f;
    }
    red[tid] = s; __syncthreads();
    for (int off = 32; off > 0; off >>= 1) { if (tid < off) red[tid] = fmaxf(red[tid], red[tid + off]); __syncthreads(); }
    float m = red[0];
    __syncthreads();
    float e = (tid < TJ) ? __expf(s - m) : 0.f;
    p[tid] = e; red[tid] = e; __syncthreads();
    for (int off = 32; off > 0; off >>= 1) { if (tid < off) red[tid] += red[tid + off]; __syncthreads(); }
    float denom = red[0];
    if (tid < THD) {
        float acc = 0.f;
        for (int k = 0; k < TJ; ++k)
            acc += p[k] * V[(size_t)(base + k) * TH + head * THD + tid];
        O[(size_t)(base + qj) * TH + head * THD + tid] = acc / denom;
    }
}

// ---------------- out-proj + residual + LayerNorm (+ optional add) ----------------
// block per row, 128 threads. perJoint: Wo is (TJ,H,H), bo is (TJ,H); else (H,H)/(H)
__global__ void oproj_ln_kernel(const float* __restrict__ A, const float* __restrict__ Wo,
                                const float* __restrict__ bo, const float* __restrict__ resid,
                                const float* __restrict__ g, const float* __restrict__ bln,
                                const float* __restrict__ addv, float* __restrict__ Y,
                                int perJoint) {
    int row = blockIdx.x;
    int h = threadIdx.x;
    int j = row % TJ;
    __shared__ float a[TH];
    __shared__ float red[TH];
    a[h] = A[(size_t)row * TH + h];
    __syncthreads();
    const float* wrow = perJoint ? (Wo + ((size_t)j * TH + h) * TH) : (Wo + (size_t)h * TH);
    float acc = perJoint ? bo[j * TH + h] : bo[h];
    #pragma unroll 4
    for (int k = 0; k < TH; ++k) acc += a[k] * wrow[k];
    float val = resid[(size_t)row * TH + h] + acc;
    red[h] = val; __syncthreads();
    for (int off = 64; off > 0; off >>= 1) { if (h < off) red[h] += red[h + off]; __syncthreads(); }
    float mean = red[0] * (1.0f / TH);
    __syncthreads();
    float dv = val - mean;
    red[h] = dv * dv; __syncthreads();
    for (int off = 64; off > 0; off >>= 1) { if (h < off) red[h] += red[h + off]; __syncthreads(); }
    float var = red[0] * (1.0f / TH);
    float out = dv * rsqrtf(var + 1e-5f) * g[h] + bln[h];
    if (addv) out += addv[(size_t)row * TH + h];
    Y[(size_t)row * TH + h] = out;
}

// ---------------- FFN ----------------
__global__ void ffn1_kernel(const float* __restrict__ Y, const float* __restrict__ W1,
                            const float* __restrict__ b1, float* __restrict__ Fb) {
    int idx = blockIdx.x * 256 + threadIdx.x;
    if (idx >= TROWS * TF) return;
    int ff = idx % TF;
    int row = idx / TF;
    const float* y = Y + (size_t)row * TH;
    const float* wt = W1 + (size_t)ff * TH;
    float acc = b1[ff];
    #pragma unroll 4
    for (int k = 0; k < TH; ++k) acc += y[k] * wt[k];
    Fb[idx] = 2.0f * fmaxf(acc, 0.0f);
}

__global__ void ffn2_kernel(const float* __restrict__ Fb, const float* __restrict__ W2,
                            const float* __restrict__ b2, float* __restrict__ Out) {
    int idx = blockIdx.x * 256 + threadIdx.x;
    if (idx >= TROWS * TH) return;
    int h = idx % TH;
    int row = idx / TH;
    const float* f = Fb + (size_t)row * TF;
    const float* wt = W2 + (size_t)h * TF;
    float acc = b2[h];
    #pragma unroll 4
    for (int k = 0; k < TF; ++k) acc += f[k] * wt[k];
    Out[idx] = acc;
}

// ---------------- final projection + residual ----------------
// out[b*TW*TD + t*TD + d] = Wout[o,:]·r4[t,b,j,:] + bout[o] + concat[t,b,d]
__global__ void final_kernel(const float* __restrict__ r4, const float* __restrict__ Wout,
                             const float* __restrict__ bout, const float* __restrict__ src,
                             const float* __restrict__ tgt, float* __restrict__ out) {
    int idx = blockIdx.x * 256 + threadIdx.x;
    if (idx >= TB * TW * TD) return;
    int d = idx % TD;
    int t = (idx / TD) % TW;
    int b = idx / (TD * TW);
    int j = d / 9, o = d % 9;
    const float* rr = r4 + (size_t)((t * TB + b) * TJ + j) * TH;
    const float* wt = Wout + (size_t)o * TH;
    float acc = bout[o];
    #pragma unroll 4
    for (int h = 0; h < TH; ++h) acc += rr[h] * wt[h];
    float cv = (t < 60) ? src[((size_t)b * 60 + t) * TD + d]
                        : tgt[((size_t)b * 61 + (t - 60)) * TD + d];
    out[idx] = acc + cv;
}

extern "C" void kernel_launch(void* const* d_in, const int* in_sizes, int n_in,
                              void* d_out, int out_size, void* d_ws, size_t ws_size,
                              hipStream_t stream) {
    const float* src    = (const float*)d_in[0];
    const float* tgt    = (const float*)d_in[1];
    const float* Wemb   = (const float*)d_in[2];
    const float* bemb   = (const float*)d_in[3];
    const float* Wqkv_s = (const float*)d_in[4];
    const float* bqkv_s = (const float*)d_in[5];
    const float* Wo_s   = (const float*)d_in[6];
    const float* bo_s   = (const float*)d_in[7];
    const float* sn_g   = (const float*)d_in[8];
    const float* sn_b   = (const float*)d_in[9];
    const float* Wqkv_t = (const float*)d_in[10];
    const float* bqkv_t = (const float*)d_in[11];
    const float* Wo_t   = (const float*)d_in[12];
    const float* bo_t   = (const float*)d_in[13];
    const float* tn_g   = (const float*)d_in[14];
    const float* tn_b   = (const float*)d_in[15];
    const float* W1     = (const float*)d_in[16];
    const float* b1     = (const float*)d_in[17];
    const float* W2     = (const float*)d_in[18];
    const float* b2     = (const float*)d_in[19];
    const float* Wout   = (const float*)d_in[20];
    const float* bout   = (const float*)d_in[21];
    float* out = (float*)d_out;

    float* ws = (float*)d_ws;
    const size_t RH = (size_t)TROWS * TH;   // 737280
    float* x0    = ws;
    float* Kbase = x0 + RH;          // 4*RH
    float* Vbase = Kbase + 4 * RH;   // 4*RH
    float* r     = Vbase + 4 * RH;
    float* Qb    = r + RH;
    float* Kb    = Qb + RH;
    float* Vb    = Kb + RH;
    float* attnb = Vb + RH;
    float* yb    = attnb + RH;
    float* spoutb= yb + RH;
    float* Bb0   = spoutb + RH;
    float* Bb1   = Bb0 + RH;
    float* fbuf  = Bb1 + RH;         // TROWS*TF

    // 1. embedding (+PE)
    embed_kernel<<<(TW * TB * TEMB + 255) / 256, 256, 0, stream>>>(src, tgt, Wemb, bemb, x0);

    // 2. baseline pass (temporal-only stack); save per-layer K/V projections
    const float* Bin = x0;
    for (int l = 0; l < 4; ++l) {
        qkv_joint_kernel<<<(TROWS * 3 * TH + 255) / 256, 256, 0, stream>>>(
            Bin, Wqkv_t + (size_t)l * TJ * 3 * TH * TH, bqkv_t + (size_t)l * TJ * 3 * TH,
            Qb, Kbase + l * RH, Vbase + l * RH);
        if (l < 3) {
            attn_causal_kernel<<<TW * TB * TJ * TNH, 128, 0, stream>>>(
                Qb, Kbase + l * RH, Vbase + l * RH, attnb);
            oproj_ln_kernel<<<TROWS, TH, 0, stream>>>(
                attnb, Wo_t + (size_t)l * TJ * TH * TH, bo_t + (size_t)l * TJ * TH,
                Bin, tn_g + l * TH, tn_b + l * TH, nullptr, yb, 1);
            ffn1_kernel<<<(TROWS * TF + 255) / 256, 256, 0, stream>>>(
                yb, W1 + (size_t)l * TF * TH, b1 + (size_t)l * TF, fbuf);
            float* Bout = (l & 1) ? Bb1 : Bb0;
            ffn2_kernel<<<(TROWS * TH + 255) / 256, 256, 0, stream>>>(
                fbuf, W2 + (size_t)l * TH * TF, b2 + (size_t)l * TH, Bout);
            Bin = Bout;
        }
    }

    // 3. per-t special-row chains (all 120 t in parallel)
    hipMemcpyAsync(r, x0, RH * sizeof(float), hipMemcpyDeviceToDevice, stream);
    for (int l = 0; l < 4; ++l) {
        // spatial MHA over joints at frame t
        qkv_shared_kernel<<<(TROWS * 3 * TH + 255) / 256, 256, 0, stream>>>(
            r, Wqkv_s + (size_t)l * 3 * TH * TH, bqkv_s + (size_t)l * 3 * TH, Qb, Kb, Vb);
        attn_spatial_kernel<<<TW * TB * TNH * TJ, 64, 0, stream>>>(Qb, Kb, Vb, attnb);
        oproj_ln_kernel<<<TROWS, TH, 0, stream>>>(
            attnb, Wo_s + (size_t)l * TH * TH, bo_s + (size_t)l * TH,
            r, sn_g + l * TH, sn_b + l * TH, nullptr, spoutb, 0);
        // temporal single-query attention at row t
        qkv_joint_kernel<<<(TROWS * 3 * TH + 255) / 256, 256, 0, stream>>>(
            r, Wqkv_t + (size_t)l * TJ * 3 * TH * TH, bqkv_t + (size_t)l * TJ * 3 * TH,
            Qb, Kb, Vb);
        attn_special_kernel<<<TW * TB * TJ * TNH, 128, 0, stream>>>(
            Qb, Kb, Vb, Kbase + l * RH, Vbase + l * RH, attnb);
        oproj_ln_kernel<<<TROWS, TH, 0, stream>>>(
            attnb, Wo_t + (size_t)l * TJ * TH * TH, bo_t + (size_t)l * TJ * TH,
            r, tn_g + l * TH, tn_b + l * TH, spoutb, yb, 1);
        // FFN on the special row
        ffn1_kernel<<<(TROWS * TF + 255) / 256, 256, 0, stream>>>(
            yb, W1 + (size_t)l * TF * TH, b1 + (size_t)l * TF, fbuf);
        ffn2_kernel<<<(TROWS * TH + 255) / 256, 256, 0, stream>>>(
            fbuf, W2 + (size_t)l * TH * TF, b2 + (size_t)l * TH, r);
    }

    // 4. output projection + residual
    final_kernel<<<(TB * TW * TD + 255) / 256, 256, 0, stream>>>(r, Wout, bout, src, tgt, out);
}

// Round 4
// 1265.978 us; speedup vs baseline: 5.1450x; 5.1450x over previous
//
#include <hip/hip_runtime.h>

// Sizes
#define TW 120     // window / number of parallel t-steps
#define TB 2       // batch
#define TJ 24      // joints
#define TH 128     // hidden
#define TNH 8      // heads
#define THD 16     // head dim
#define TF 256     // ffn
#define TD 216     // input dim
#define TROWS (TW*TB*TJ)   // 5760 rows of H
#define TEMB (TJ*TH)       // 3072
#define TBF 240            // t*b frames

#define KC 32
#define LDA 68     // 64 + 4 pad (keeps 16B alignment for f4 reads)
#define LDB2 132   // 128 + 4 pad

typedef float f4 __attribute__((ext_vector_type(4)));

// ---------- GEMM building blocks: C[m][n] = sum_k A[m][k]*B[n][k] ----------
// LDS tiles stored transposed: As[k][m], Bs[k][n] -> outer-product inner loop.

__device__ __forceinline__ void stageA(float* As, const float* __restrict__ A,
                                       int a_stride, int mrem, int K, int k0, int tid) {
    int r = tid >> 2;              // 0..63 (tile row)
    int kk = (tid & 3) << 3;       // 0,8,16,24
    bool rowok = r < mrem;
    const float* ap = A + (size_t)r * a_stride + k0 + kk;
    #pragma unroll
    for (int c = 0; c < 8; c += 4) {
        f4 v = {0.f, 0.f, 0.f, 0.f};
        int kg = k0 + kk + c;
        if (rowok) {
            if (kg + 4 <= K) v = *(const f4*)(ap + c);
            else {
                #pragma unroll
                for (int u = 0; u < 4; ++u) if (kg + u < K) v[u] = ap[c + u];
            }
        }
        As[(kk + c + 0) * LDA + r] = v[0];
        As[(kk + c + 1) * LDA + r] = v[1];
        As[(kk + c + 2) * LDA + r] = v[2];
        As[(kk + c + 3) * LDA + r] = v[3];
    }
}

__device__ __forceinline__ void stageB64(float* Bs, const float* __restrict__ Bw,
                                         int K, int k0, int tid) {
    int r = tid >> 2;              // n index 0..63
    int kk = (tid & 3) << 3;
    const float* bp = Bw + (size_t)r * K + k0 + kk;
    #pragma unroll
    for (int c = 0; c < 8; c += 4) {
        f4 v = {0.f, 0.f, 0.f, 0.f};
        int kg = k0 + kk + c;
        if (kg + 4 <= K) v = *(const f4*)(bp + c);
        else {
            #pragma unroll
            for (int u = 0; u < 4; ++u) if (kg + u < K) v[u] = bp[c + u];
        }
        Bs[(kk + c + 0) * LDA + r] = v[0];
        Bs[(kk + c + 1) * LDA + r] = v[1];
        Bs[(kk + c + 2) * LDA + r] = v[2];
        Bs[(kk + c + 3) * LDA + r] = v[3];
    }
}

__device__ __forceinline__ void mac64(const float* As, const float* Bs, int tr, int tc, f4 acc[4]) {
    #pragma unroll
    for (int kk = 0; kk < KC; ++kk) {
        f4 a = *(const f4*)&As[kk * LDA + tr * 4];
        f4 b = *(const f4*)&Bs[kk * LDA + tc * 4];
        acc[0] += a[0] * b;
        acc[1] += a[1] * b;
        acc[2] += a[2] * b;
        acc[3] += a[3] * b;
    }
}

// ---------------- gather concat into contiguous [240][216] ----------------
__global__ void gather_kernel(const float* __restrict__ src, const float* __restrict__ tgt,
                              float* __restrict__ cbuf) {
    int idx = blockIdx.x * 256 + threadIdx.x;
    if (idx >= TBF * TD) return;
    int d = idx % TD;
    int row = idx / TD;
    int b = row & 1, t = row >> 1;
    cbuf[idx] = (t < 60) ? src[((size_t)b * 60 + t) * TD + d]
                         : tgt[((size_t)b * 61 + (t - 60)) * TD + d];
}

// ---------------- embedding GEMM + bias + PE ----------------
// grid (4, 48): M=240 (rows t*2+b), N=3072, K=216
__global__ __launch_bounds__(256) void gemm_embed_kernel(
        const float* __restrict__ cbuf, const float* __restrict__ Wemb,
        const float* __restrict__ bemb, float* __restrict__ x0) {
    __shared__ __align__(16) float As[KC * LDA];
    __shared__ __align__(16) float Bs[KC * LDA];
    int tid = threadIdx.x;
    int m0 = blockIdx.x * 64;
    int n0 = blockIdx.y * 64;
    int mrem = TBF - m0; if (mrem > 64) mrem = 64;
    const float* A = cbuf + (size_t)m0 * TD;
    const float* Bw = Wemb + (size_t)n0 * TD;
    f4 acc[4] = {{0,0,0,0},{0,0,0,0},{0,0,0,0},{0,0,0,0}};
    for (int k0 = 0; k0 < TD; k0 += KC) {
        stageA(As, A, TD, mrem, TD, k0, tid);
        stageB64(Bs, Bw, TD, k0, tid);
        __syncthreads();
        mac64(As, Bs, tid >> 4, tid & 15, acc);
        __syncthreads();
    }
    int tr = tid >> 4, tc = tid & 15;
    int nb = n0 + tc * 4;
    f4 b4 = *(const f4*)&bemb[nb];
    #pragma unroll
    for (int i = 0; i < 4; ++i) {
        int row = tr * 4 + i;
        if (row < mrem) {
            int grow = m0 + row;
            int t = grow >> 1;
            f4 o = acc[i] + b4;
            #pragma unroll
            for (int u = 0; u < 4; ++u) {
                int n = nb + u;
                float freq = expf((float)(n & ~1) * (-9.2103403719761836f / 3072.0f));
                float ang = (float)t * freq;
                o[u] += (n & 1) ? cosf(ang) : sinf(ang);
            }
            *(f4*)&x0[(size_t)grow * TEMB + nb] = o;
        }
    }
}

// ---------------- QKV GEMM (per-joint or shared weights) ----------------
// grid (4, 6, 24): per joint j, M=240 frames (rows strided TJ*TH), N=384, K=128
__global__ __launch_bounds__(256) void gemm_qkv_kernel(
        const float* __restrict__ X, const float* __restrict__ W, const float* __restrict__ bias,
        float* __restrict__ Q, float* __restrict__ Kd, float* __restrict__ V, int perJoint) {
    __shared__ __align__(16) float As[KC * LDA];
    __shared__ __align__(16) float Bs[KC * LDA];
    int tid = threadIdx.x;
    int m0 = blockIdx.x * 64;
    int n0 = blockIdx.y * 64;
    int j  = blockIdx.z;
    int mrem = TBF - m0; if (mrem > 64) mrem = 64;
    const float* A = X + (size_t)m0 * (TJ * TH) + (size_t)j * TH;
    const float* Bw = W + (perJoint ? (size_t)j * 3 * TH * TH : 0) + (size_t)n0 * TH;
    f4 acc[4] = {{0,0,0,0},{0,0,0,0},{0,0,0,0},{0,0,0,0}};
    for (int k0 = 0; k0 < TH; k0 += KC) {
        stageA(As, A, TJ * TH, mrem, TH, k0, tid);
        stageB64(Bs, Bw, TH, k0, tid);
        __syncthreads();
        mac64(As, Bs, tid >> 4, tid & 15, acc);
        __syncthreads();
    }
    int tr = tid >> 4, tc = tid & 15;
    float* dst = (n0 < TH) ? Q : ((n0 < 2 * TH) ? Kd : V);
    int col = (n0 & (TH - 1)) + tc * 4;
    f4 b4 = *(const f4*)&bias[(perJoint ? j * 3 * TH : 0) + n0 + tc * 4];
    #pragma unroll
    for (int i = 0; i < 4; ++i) {
        int row = tr * 4 + i;
        if (row < mrem) {
            int rj = (m0 + row) * TJ + j;
            *(f4*)&dst[(size_t)rj * TH + col] = acc[i] + b4;
        }
    }
}

// ---------------- out-proj GEMM + residual + LayerNorm (+ optional add) ----------------
// grid (4, 1, 24): per joint j, M=240, N=TH (full row in block), K=TH
__global__ __launch_bounds__(256) void gemm_oln_kernel(
        const float* __restrict__ Ain, const float* __restrict__ W, const float* __restrict__ bias,
        const float* __restrict__ resid, const float* __restrict__ g, const float* __restrict__ bln,
        const float* __restrict__ addv, float* __restrict__ Y, int perJoint) {
    __shared__ __align__(16) float As[KC * LDA];
    __shared__ __align__(16) float Bs[KC * LDB2];
    __shared__ float rsum[64 * 17];
    __shared__ float rsq[64 * 17];
    __shared__ float lnm[64], lnr[64];
    int tid = threadIdx.x;
    int m0 = blockIdx.x * 64;
    int j = blockIdx.z;
    int mrem = TBF - m0; if (mrem > 64) mrem = 64;
    const float* A = Ain + (size_t)m0 * (TJ * TH) + (size_t)j * TH;
    const float* Bw = W + (perJoint ? (size_t)j * TH * TH : 0);
    f4 acc[4][2] = {{{0,0,0,0},{0,0,0,0}},{{0,0,0,0},{0,0,0,0}},
                    {{0,0,0,0},{0,0,0,0}},{{0,0,0,0},{0,0,0,0}}};
    int tr = tid >> 4, tc = tid & 15;
    for (int k0 = 0; k0 < TH; k0 += KC) {
        stageA(As, A, TJ * TH, mrem, TH, k0, tid);
        {   // stage B: 128 n-rows, transposed
            int r2 = tid >> 1, kk2 = (tid & 1) << 4;
            const float* bp = Bw + (size_t)r2 * TH + k0 + kk2;
            #pragma unroll
            for (int c = 0; c < 16; c += 4) {
                f4 v = *(const f4*)(bp + c);
                Bs[(kk2 + c + 0) * LDB2 + r2] = v[0];
                Bs[(kk2 + c + 1) * LDB2 + r2] = v[1];
                Bs[(kk2 + c + 2) * LDB2 + r2] = v[2];
                Bs[(kk2 + c + 3) * LDB2 + r2] = v[3];
            }
        }
        __syncthreads();
        #pragma unroll
        for (int kk = 0; kk < KC; ++kk) {
            f4 a = *(const f4*)&As[kk * LDA + tr * 4];
            f4 b0 = *(const f4*)&Bs[kk * LDB2 + tc * 8];
            f4 b1 = *(const f4*)&Bs[kk * LDB2 + tc * 8 + 4];
            #pragma unroll
            for (int i = 0; i < 4; ++i) { acc[i][0] += a[i] * b0; acc[i][1] += a[i] * b1; }
        }
        __syncthreads();
    }
    int colb = tc * 8;
    f4 bb0 = *(const f4*)&bias[(perJoint ? j * TH : 0) + colb];
    f4 bb1 = *(const f4*)&bias[(perJoint ? j * TH : 0) + colb + 4];
    #pragma unroll
    for (int i = 0; i < 4; ++i) {
        int row = tr * 4 + i;
        float s = 0.f, q = 0.f;
        if (row < mrem) {
            size_t off = (size_t)((m0 + row) * TJ + j) * TH + colb;
            f4 r0 = *(const f4*)&resid[off];
            f4 r1 = *(const f4*)&resid[off + 4];
            acc[i][0] += bb0 + r0;
            acc[i][1] += bb1 + r1;
            #pragma unroll
            for (int u = 0; u < 4; ++u) {
                s += acc[i][0][u] + acc[i][1][u];
                q += acc[i][0][u] * acc[i][0][u] + acc[i][1][u] * acc[i][1][u];
            }
        }
        rsum[row * 17 + tc] = s;
        rsq[row * 17 + tc] = q;
    }
    __syncthreads();
    if (tid < 64) {
        float s = 0.f, q = 0.f;
        #pragma unroll
        for (int c = 0; c < 16; ++c) { s += rsum[tid * 17 + c]; q += rsq[tid * 17 + c]; }
        float mean = s * (1.0f / TH);
        float var = q * (1.0f / TH) - mean * mean;
        lnm[tid] = mean;
        lnr[tid] = rsqrtf(var + 1e-5f);
    }
    __syncthreads();
    f4 g0 = *(const f4*)&g[colb], g1 = *(const f4*)&g[colb + 4];
    f4 l0 = *(const f4*)&bln[colb], l1 = *(const f4*)&bln[colb + 4];
    #pragma unroll
    for (int i = 0; i < 4; ++i) {
        int row = tr * 4 + i;
        if (row < mrem) {
            float mean = lnm[row], rstd = lnr[row];
            size_t off = (size_t)((m0 + row) * TJ + j) * TH + colb;
            f4 o0 = (acc[i][0] - mean) * rstd * g0 + l0;
            f4 o1 = (acc[i][1] - mean) * rstd * g1 + l1;
            if (addv) { o0 += *(const f4*)&addv[off]; o1 += *(const f4*)&addv[off + 4]; }
            *(f4*)&Y[off] = o0;
            *(f4*)&Y[off + 4] = o1;
        }
    }
}

// ---------------- FFN GEMMs ----------------
// grid (90, 4): M=5760 contiguous, N=256, K=128; relu*2 epilogue
__global__ __launch_bounds__(256) void gemm_ffn1_kernel(
        const float* __restrict__ Y, const float* __restrict__ W1,
        const float* __restrict__ b1, float* __restrict__ Fb) {
    __shared__ __align__(16) float As[KC * LDA];
    __shared__ __align__(16) float Bs[KC * LDA];
    int tid = threadIdx.x;
    int m0 = blockIdx.x * 64;
    int n0 = blockIdx.y * 64;
    const float* A = Y + (size_t)m0 * TH;
    const float* Bw = W1 + (size_t)n0 * TH;
    f4 acc[4] = {{0,0,0,0},{0,0,0,0},{0,0,0,0},{0,0,0,0}};
    for (int k0 = 0; k0 < TH; k0 += KC) {
        stageA(As, A, TH, 64, TH, k0, tid);
        stageB64(Bs, Bw, TH, k0, tid);
        __syncthreads();
        mac64(As, Bs, tid >> 4, tid & 15, acc);
        __syncthreads();
    }
    int tr = tid >> 4, tc = tid & 15;
    f4 b4 = *(const f4*)&b1[n0 + tc * 4];
    #pragma unroll
    for (int i = 0; i < 4; ++i) {
        f4 o = acc[i] + b4;
        #pragma unroll
        for (int u = 0; u < 4; ++u) o[u] = 2.0f * fmaxf(o[u], 0.0f);
        *(f4*)&Fb[(size_t)(m0 + tr * 4 + i) * TF + n0 + tc * 4] = o;
    }
}

// grid (90, 2): M=5760, N=128, K=256
__global__ __launch_bounds__(256) void gemm_ffn2_kernel(
        const float* __restrict__ Fb, const float* __restrict__ W2,
        const float* __restrict__ b2, float* __restrict__ Out) {
    __shared__ __align__(16) float As[KC * LDA];
    __shared__ __align__(16) float Bs[KC * LDA];
    int tid = threadIdx.x;
    int m0 = blockIdx.x * 64;
    int n0 = blockIdx.y * 64;
    const float* A = Fb + (size_t)m0 * TF;
    const float* Bw = W2 + (size_t)n0 * TF;
    f4 acc[4] = {{0,0,0,0},{0,0,0,0},{0,0,0,0},{0,0,0,0}};
    for (int k0 = 0; k0 < TF; k0 += KC) {
        stageA(As, A, TF, 64, TF, k0, tid);
        stageB64(Bs, Bw, TF, k0, tid);
        __syncthreads();
        mac64(As, Bs, tid >> 4, tid & 15, acc);
        __syncthreads();
    }
    int tr = tid >> 4, tc = tid & 15;
    f4 b4 = *(const f4*)&b2[n0 + tc * 4];
    #pragma unroll
    for (int i = 0; i < 4; ++i)
        *(f4*)&Out[(size_t)(m0 + tr * 4 + i) * TH + n0 + tc * 4] = acc[i] + b4;
}

// ---------------- baseline causal temporal attention ----------------
__global__ void attn_causal_kernel(const float* __restrict__ Q, const float* __restrict__ K,
                                   const float* __restrict__ V, float* __restrict__ O) {
    int blk = blockIdx.x;
    int head = blk % TNH;
    int j = (blk / TNH) % TJ;
    int b = (blk / (TNH * TJ)) % TB;
    int q = blk / (TNH * TJ * TB);
    int tid = threadIdx.x;
    __shared__ float p[128];
    __shared__ float red[128];
    __shared__ float qv[THD];
    int rowq = (q * TB + b) * TJ + j;
    if (tid < THD) qv[tid] = Q[(size_t)rowq * TH + head * THD + tid];
    __syncthreads();
    float s = -1e30f;
    if (tid <= q) {
        int rowk = (tid * TB + b) * TJ + j;
        const float* kv = K + (size_t)rowk * TH + head * THD;
        float acc = 0.f;
        #pragma unroll
        for (int d = 0; d < THD; ++d) acc += qv[d] * kv[d];
        s = acc * 0.25f;
    }
    red[tid] = s; __syncthreads();
    for (int off = 64; off > 0; off >>= 1) { if (tid < off) red[tid] = fmaxf(red[tid], red[tid + off]); __syncthreads(); }
    float m = red[0];
    __syncthreads();
    float e = (tid <= q) ? __expf(s - m) : 0.f;
    p[tid] = e; red[tid] = e; __syncthreads();
    for (int off = 64; off > 0; off >>= 1) { if (tid < off) red[tid] += red[tid + off]; __syncthreads(); }
    float denom = red[0];
    if (tid < THD) {
        float acc = 0.f;
        for (int k = 0; k <= q; ++k)
            acc += p[k] * V[(size_t)((k * TB + b) * TJ + j) * TH + head * THD + tid];
        O[(size_t)rowq * TH + head * THD + tid] = acc / denom;
    }
}

// ---------------- special-row temporal attention (single query t) ----------------
__global__ void attn_special_kernel(const float* __restrict__ Qs, const float* __restrict__ Ks,
                                    const float* __restrict__ Vs, const float* __restrict__ Kb,
                                    const float* __restrict__ Vb, float* __restrict__ O) {
    int blk = blockIdx.x;
    int head = blk % TNH;
    int j = (blk / TNH) % TJ;
    int b = (blk / (TNH * TJ)) % TB;
    int t = blk / (TNH * TJ * TB);
    int tid = threadIdx.x;
    __shared__ float p[128];
    __shared__ float red[128];
    __shared__ float qv[THD];
    int rowq = (t * TB + b) * TJ + j;
    if (tid < THD) qv[tid] = Qs[(size_t)rowq * TH + head * THD + tid];
    __syncthreads();
    float s = -1e30f;
    if (tid <= t) {
        int rowk = (tid * TB + b) * TJ + j;
        const float* kv = ((tid == t) ? Ks : Kb) + (size_t)rowk * TH + head * THD;
        float acc = 0.f;
        #pragma unroll
        for (int d = 0; d < THD; ++d) acc += qv[d] * kv[d];
        s = acc * 0.25f;
    }
    red[tid] = s; __syncthreads();
    for (int off = 64; off > 0; off >>= 1) { if (tid < off) red[tid] = fmaxf(red[tid], red[tid + off]); __syncthreads(); }
    float m = red[0];
    __syncthreads();
    float e = (tid <= t) ? __expf(s - m) : 0.f;
    p[tid] = e; red[tid] = e; __syncthreads();
    for (int off = 64; off > 0; off >>= 1) { if (tid < off) red[tid] += red[tid + off]; __syncthreads(); }
    float denom = red[0];
    if (tid < THD) {
        float acc = 0.f;
        for (int k = 0; k < t; ++k)
            acc += p[k] * Vb[(size_t)((k * TB + b) * TJ + j) * TH + head * THD + tid];
        acc += p[t] * Vs[(size_t)rowq * TH + head * THD + tid];
        O[(size_t)rowq * TH + head * THD + tid] = acc / denom;
    }
}

// ---------------- spatial attention over joints ----------------
__global__ void attn_spatial_kernel(const float* __restrict__ Q, const float* __restrict__ K,
                                    const float* __restrict__ V, float* __restrict__ O) {
    int blk = blockIdx.x;
    int qj = blk % TJ;
    int head = (blk / TJ) % TNH;
    int b = (blk / (TJ * TNH)) % TB;
    int t = blk / (TJ * TNH * TB);
    int tid = threadIdx.x;
    __shared__ float p[64];
    __shared__ float red[64];
    __shared__ float qv[THD];
    int base = (t * TB + b) * TJ;
    if (tid < THD) qv[tid] = Q[(size_t)(base + qj) * TH + head * THD + tid];
    __syncthreads();
    float s = -1e30f;
    if (tid < TJ) {
        const float* kv = K + (size_t)(base + tid) * TH + head * THD;
        float acc = 0.f;
        #pragma unroll
        for (int d = 0; d < THD; ++d) acc += qv[d] * kv[d];
        s = acc * 0.25f;
    }
    red[tid] = s; __syncthreads();
    for (int off = 32; off > 0; off >>= 1) { if (tid < off) red[tid] = fmaxf(red[tid], red[tid + off]); __syncthreads(); }
    float m = red[0];
    __syncthreads();
    float e = (tid < TJ) ? __expf(s - m) : 0.f;
    p[tid] = e; red[tid] = e; __syncthreads();
    for (int off = 32; off > 0; off >>= 1) { if (tid < off) red[tid] += red[tid + off]; __syncthreads(); }
    float denom = red[0];
    if (tid < THD) {
        float acc = 0.f;
        for (int k = 0; k < TJ; ++k)
            acc += p[k] * V[(size_t)(base + k) * TH + head * THD + tid];
        O[(size_t)(base + qj) * TH + head * THD + tid] = acc / denom;
    }
}

// ---------------- final projection + residual ----------------
__global__ void final_kernel(const float* __restrict__ r4, const float* __restrict__ Wout,
                             const float* __restrict__ bout, const float* __restrict__ src,
                             const float* __restrict__ tgt, float* __restrict__ out) {
    int idx = blockIdx.x * 256 + threadIdx.x;
    if (idx >= TB * TW * TD) return;
    int d = idx % TD;
    int t = (idx / TD) % TW;
    int b = idx / (TD * TW);
    int j = d / 9, o = d % 9;
    const float* rr = r4 + (size_t)((t * TB + b) * TJ + j) * TH;
    const float* wt = Wout + (size_t)o * TH;
    float acc = bout[o];
    #pragma unroll 4
    for (int h = 0; h < TH; ++h) acc += rr[h] * wt[h];
    float cv = (t < 60) ? src[((size_t)b * 60 + t) * TD + d]
                        : tgt[((size_t)b * 61 + (t - 60)) * TD + d];
    out[idx] = acc + cv;
}

extern "C" void kernel_launch(void* const* d_in, const int* in_sizes, int n_in,
                              void* d_out, int out_size, void* d_ws, size_t ws_size,
                              hipStream_t stream) {
    const float* src    = (const float*)d_in[0];
    const float* tgt    = (const float*)d_in[1];
    const float* Wemb   = (const float*)d_in[2];
    const float* bemb   = (const float*)d_in[3];
    const float* Wqkv_s = (const float*)d_in[4];
    const float* bqkv_s = (const float*)d_in[5];
    const float* Wo_s   = (const float*)d_in[6];
    const float* bo_s   = (const float*)d_in[7];
    const float* sn_g   = (const float*)d_in[8];
    const float* sn_b   = (const float*)d_in[9];
    const float* Wqkv_t = (const float*)d_in[10];
    const float* bqkv_t = (const float*)d_in[11];
    const float* Wo_t   = (const float*)d_in[12];
    const float* bo_t   = (const float*)d_in[13];
    const float* tn_g   = (const float*)d_in[14];
    const float* tn_b   = (const float*)d_in[15];
    const float* W1     = (const float*)d_in[16];
    const float* b1     = (const float*)d_in[17];
    const float* W2     = (const float*)d_in[18];
    const float* b2     = (const float*)d_in[19];
    const float* Wout   = (const float*)d_in[20];
    const float* bout   = (const float*)d_in[21];
    float* out = (float*)d_out;

    float* ws = (float*)d_ws;
    const size_t RH = (size_t)TROWS * TH;   // 737280
    float* x0    = ws;
    float* Kbase = x0 + RH;          // 4*RH
    float* Vbase = Kbase + 4 * RH;   // 4*RH
    float* r     = Vbase + 4 * RH;
    float* Qb    = r + RH;
    float* Kb    = Qb + RH;
    float* Vb    = Kb + RH;
    float* attnb = Vb + RH;
    float* yb    = attnb + RH;
    float* spoutb= yb + RH;
    float* Bb0   = spoutb + RH;
    float* Bb1   = Bb0 + RH;
    float* fbuf  = Bb1 + RH;         // TROWS*TF (also reused as cbuf for embed)

    // 1. gather concat, then embedding GEMM (+PE)
    gather_kernel<<<(TBF * TD + 255) / 256, 256, 0, stream>>>(src, tgt, fbuf);
    gemm_embed_kernel<<<dim3(4, 48), 256, 0, stream>>>(fbuf, Wemb, bemb, x0);

    // 2. baseline pass (temporal-only stack); save per-layer K/V projections
    const float* Bin = x0;
    for (int l = 0; l < 4; ++l) {
        gemm_qkv_kernel<<<dim3(4, 6, 24), 256, 0, stream>>>(
            Bin, Wqkv_t + (size_t)l * TJ * 3 * TH * TH, bqkv_t + (size_t)l * TJ * 3 * TH,
            Qb, Kbase + l * RH, Vbase + l * RH, 1);
        if (l < 3) {
            attn_causal_kernel<<<TW * TB * TJ * TNH, 128, 0, stream>>>(
                Qb, Kbase + l * RH, Vbase + l * RH, attnb);
            gemm_oln_kernel<<<dim3(4, 1, 24), 256, 0, stream>>>(
                attnb, Wo_t + (size_t)l * TJ * TH * TH, bo_t + (size_t)l * TJ * TH,
                Bin, tn_g + l * TH, tn_b + l * TH, nullptr, yb, 1);
            gemm_ffn1_kernel<<<dim3(90, 4), 256, 0, stream>>>(
                yb, W1 + (size_t)l * TF * TH, b1 + (size_t)l * TF, fbuf);
            float* Bout = (l & 1) ? Bb1 : Bb0;
            gemm_ffn2_kernel<<<dim3(90, 2), 256, 0, stream>>>(
                fbuf, W2 + (size_t)l * TH * TF, b2 + (size_t)l * TH, Bout);
            Bin = Bout;
        }
    }

    // 3. per-t special-row chains (all 120 t in parallel)
    hipMemcpyAsync(r, x0, RH * sizeof(float), hipMemcpyDeviceToDevice, stream);
    for (int l = 0; l < 4; ++l) {
        gemm_qkv_kernel<<<dim3(4, 6, 24), 256, 0, stream>>>(
            r, Wqkv_s + (size_t)l * 3 * TH * TH, bqkv_s + (size_t)l * 3 * TH, Qb, Kb, Vb, 0);
        attn_spatial_kernel<<<TW * TB * TNH * TJ, 64, 0, stream>>>(Qb, Kb, Vb, attnb);
        gemm_oln_kernel<<<dim3(4, 1, 24), 256, 0, stream>>>(
            attnb, Wo_s + (size_t)l * TH * TH, bo_s + (size_t)l * TH,
            r, sn_g + l * TH, sn_b + l * TH, nullptr, spoutb, 0);
        gemm_qkv_kernel<<<dim3(4, 6, 24), 256, 0, stream>>>(
            r, Wqkv_t + (size_t)l * TJ * 3 * TH * TH, bqkv_t + (size_t)l * TJ * 3 * TH,
            Qb, Kb, Vb, 1);
        attn_special_kernel<<<TW * TB * TJ * TNH, 128, 0, stream>>>(
            Qb, Kb, Vb, Kbase + l * RH, Vbase + l * RH, attnb);
        gemm_oln_kernel<<<dim3(4, 1, 24), 256, 0, stream>>>(
            attnb, Wo_t + (size_t)l * TJ * TH * TH, bo_t + (size_t)l * TJ * TH,
            r, tn_g + l * TH, tn_b + l * TH, spoutb, yb, 1);
        gemm_ffn1_kernel<<<dim3(90, 4), 256, 0, stream>>>(
            yb, W1 + (size_t)l * TF * TH, b1 + (size_t)l * TF, fbuf);
        gemm_ffn2_kernel<<<dim3(90, 2), 256, 0, stream>>>(
            fbuf, W2 + (size_t)l * TH * TF, b2 + (size_t)l * TH, r);
    }

    // 4. output projection + residual
    final_kernel<<<(TB * TW * TD + 255) / 256, 256, 0, stream>>>(r, Wout, bout, src, tgt, out);
}

// Round 5
// 1038.490 us; speedup vs baseline: 6.2721x; 1.2191x over previous
//
#include <hip/hip_runtime.h>

// Sizes
#define TW 120     // window / number of parallel t-steps
#define TB 2       // batch
#define TJ 24      // joints
#define TH 128     // hidden
#define TNH 8      // heads
#define THD 16     // head dim
#define TF 256     // ffn
#define TD 216     // input dim
#define TROWS (TW*TB*TJ)   // 5760 rows of H
#define TEMB (TJ*TH)       // 3072
#define TBF 240            // t*b frames

#define KC 32
#define LDA 68     // 64 + 4 pad (keeps 16B alignment for f4 reads)
#define LDB2 132   // 128 + 4 pad
#define APAD 17    // attention LDS row pad: 17 coprime 32 -> conflict-free

typedef float f4 __attribute__((ext_vector_type(4)));

// ---------- GEMM building blocks: C[m][n] = sum_k A[m][k]*B[n][k] ----------
// LDS tiles stored transposed: As[k][m], Bs[k][n] -> outer-product inner loop.

__device__ __forceinline__ void stageA(float* As, const float* __restrict__ A,
                                       int a_stride, int mrem, int K, int k0, int tid) {
    int r = tid >> 2;              // 0..63 (tile row)
    int kk = (tid & 3) << 3;       // 0,8,16,24
    bool rowok = r < mrem;
    const float* ap = A + (size_t)r * a_stride + k0 + kk;
    #pragma unroll
    for (int c = 0; c < 8; c += 4) {
        f4 v = {0.f, 0.f, 0.f, 0.f};
        int kg = k0 + kk + c;
        if (rowok) {
            if (kg + 4 <= K) v = *(const f4*)(ap + c);
            else {
                #pragma unroll
                for (int u = 0; u < 4; ++u) if (kg + u < K) v[u] = ap[c + u];
            }
        }
        As[(kk + c + 0) * LDA + r] = v[0];
        As[(kk + c + 1) * LDA + r] = v[1];
        As[(kk + c + 2) * LDA + r] = v[2];
        As[(kk + c + 3) * LDA + r] = v[3];
    }
}

__device__ __forceinline__ void stageB64(float* Bs, const float* __restrict__ Bw,
                                         int K, int k0, int tid) {
    int r = tid >> 2;              // n index 0..63
    int kk = (tid & 3) << 3;
    const float* bp = Bw + (size_t)r * K + k0 + kk;
    #pragma unroll
    for (int c = 0; c < 8; c += 4) {
        f4 v = {0.f, 0.f, 0.f, 0.f};
        int kg = k0 + kk + c;
        if (kg + 4 <= K) v = *(const f4*)(bp + c);
        else {
            #pragma unroll
            for (int u = 0; u < 4; ++u) if (kg + u < K) v[u] = bp[c + u];
        }
        Bs[(kk + c + 0) * LDA + r] = v[0];
        Bs[(kk + c + 1) * LDA + r] = v[1];
        Bs[(kk + c + 2) * LDA + r] = v[2];
        Bs[(kk + c + 3) * LDA + r] = v[3];
    }
}

__device__ __forceinline__ void mac64(const float* As, const float* Bs, int tr, int tc, f4 acc[4]) {
    #pragma unroll
    for (int kk = 0; kk < KC; ++kk) {
        f4 a = *(const f4*)&As[kk * LDA + tr * 4];
        f4 b = *(const f4*)&Bs[kk * LDA + tc * 4];
        acc[0] += a[0] * b;
        acc[1] += a[1] * b;
        acc[2] += a[2] * b;
        acc[3] += a[3] * b;
    }
}

// ---------------- gather concat into contiguous [240][216] ----------------
__global__ void gather_kernel(const float* __restrict__ src, const float* __restrict__ tgt,
                              float* __restrict__ cbuf) {
    int idx = blockIdx.x * 256 + threadIdx.x;
    if (idx >= TBF * TD) return;
    int d = idx % TD;
    int row = idx / TD;
    int b = row & 1, t = row >> 1;
    cbuf[idx] = (t < 60) ? src[((size_t)b * 60 + t) * TD + d]
                         : tgt[((size_t)b * 61 + (t - 60)) * TD + d];
}

// ---------------- embedding GEMM + bias + PE ----------------
// grid (4, 48): M=240 (rows t*2+b), N=3072, K=216
__global__ __launch_bounds__(256) void gemm_embed_kernel(
        const float* __restrict__ cbuf, const float* __restrict__ Wemb,
        const float* __restrict__ bemb, float* __restrict__ x0) {
    __shared__ __align__(16) float As[KC * LDA];
    __shared__ __align__(16) float Bs[KC * LDA];
    int tid = threadIdx.x;
    int m0 = blockIdx.x * 64;
    int n0 = blockIdx.y * 64;
    int mrem = TBF - m0; if (mrem > 64) mrem = 64;
    const float* A = cbuf + (size_t)m0 * TD;
    const float* Bw = Wemb + (size_t)n0 * TD;
    f4 acc[4] = {{0,0,0,0},{0,0,0,0},{0,0,0,0},{0,0,0,0}};
    for (int k0 = 0; k0 < TD; k0 += KC) {
        stageA(As, A, TD, mrem, TD, k0, tid);
        stageB64(Bs, Bw, TD, k0, tid);
        __syncthreads();
        mac64(As, Bs, tid >> 4, tid & 15, acc);
        __syncthreads();
    }
    int tr = tid >> 4, tc = tid & 15;
    int nb = n0 + tc * 4;
    f4 b4 = *(const f4*)&bemb[nb];
    #pragma unroll
    for (int i = 0; i < 4; ++i) {
        int row = tr * 4 + i;
        if (row < mrem) {
            int grow = m0 + row;
            int t = grow >> 1;
            f4 o = acc[i] + b4;
            #pragma unroll
            for (int u = 0; u < 4; ++u) {
                int n = nb + u;
                float freq = expf((float)(n & ~1) * (-9.2103403719761836f / 3072.0f));
                float ang = (float)t * freq;
                o[u] += (n & 1) ? cosf(ang) : sinf(ang);
            }
            *(f4*)&x0[(size_t)grow * TEMB + nb] = o;
        }
    }
}

// ---------------- QKV GEMM (per-joint or shared weights) ----------------
// grid (4, 6, 24): per joint j, M=240 frames (rows strided TJ*TH), N=384, K=128
__global__ __launch_bounds__(256) void gemm_qkv_kernel(
        const float* __restrict__ X, const float* __restrict__ W, const float* __restrict__ bias,
        float* __restrict__ Q, float* __restrict__ Kd, float* __restrict__ V, int perJoint) {
    __shared__ __align__(16) float As[KC * LDA];
    __shared__ __align__(16) float Bs[KC * LDA];
    int tid = threadIdx.x;
    int m0 = blockIdx.x * 64;
    int n0 = blockIdx.y * 64;
    int j  = blockIdx.z;
    int mrem = TBF - m0; if (mrem > 64) mrem = 64;
    const float* A = X + (size_t)m0 * (TJ * TH) + (size_t)j * TH;
    const float* Bw = W + (perJoint ? (size_t)j * 3 * TH * TH : 0) + (size_t)n0 * TH;
    f4 acc[4] = {{0,0,0,0},{0,0,0,0},{0,0,0,0},{0,0,0,0}};
    for (int k0 = 0; k0 < TH; k0 += KC) {
        stageA(As, A, TJ * TH, mrem, TH, k0, tid);
        stageB64(Bs, Bw, TH, k0, tid);
        __syncthreads();
        mac64(As, Bs, tid >> 4, tid & 15, acc);
        __syncthreads();
    }
    int tr = tid >> 4, tc = tid & 15;
    float* dst = (n0 < TH) ? Q : ((n0 < 2 * TH) ? Kd : V);
    int col = (n0 & (TH - 1)) + tc * 4;
    f4 b4 = *(const f4*)&bias[(perJoint ? j * 3 * TH : 0) + n0 + tc * 4];
    #pragma unroll
    for (int i = 0; i < 4; ++i) {
        int row = tr * 4 + i;
        if (row < mrem) {
            int rj = (m0 + row) * TJ + j;
            *(f4*)&dst[(size_t)rj * TH + col] = acc[i] + b4;
        }
    }
}

// ---------------- out-proj GEMM + residual + LayerNorm (+ optional add) ----------------
// grid (4, 1, 24): per joint j, M=240, N=TH (full row in block), K=TH
__global__ __launch_bounds__(256) void gemm_oln_kernel(
        const float* __restrict__ Ain, const float* __restrict__ W, const float* __restrict__ bias,
        const float* __restrict__ resid, const float* __restrict__ g, const float* __restrict__ bln,
        const float* __restrict__ addv, float* __restrict__ Y, int perJoint) {
    __shared__ __align__(16) float As[KC * LDA];
    __shared__ __align__(16) float Bs[KC * LDB2];
    __shared__ float rsum[64 * 17];
    __shared__ float rsq[64 * 17];
    __shared__ float lnm[64], lnr[64];
    int tid = threadIdx.x;
    int m0 = blockIdx.x * 64;
    int j = blockIdx.z;
    int mrem = TBF - m0; if (mrem > 64) mrem = 64;
    const float* A = Ain + (size_t)m0 * (TJ * TH) + (size_t)j * TH;
    const float* Bw = W + (perJoint ? (size_t)j * TH * TH : 0);
    f4 acc[4][2] = {{{0,0,0,0},{0,0,0,0}},{{0,0,0,0},{0,0,0,0}},
                    {{0,0,0,0},{0,0,0,0}},{{0,0,0,0},{0,0,0,0}}};
    int tr = tid >> 4, tc = tid & 15;
    for (int k0 = 0; k0 < TH; k0 += KC) {
        stageA(As, A, TJ * TH, mrem, TH, k0, tid);
        {   // stage B: 128 n-rows, transposed
            int r2 = tid >> 1, kk2 = (tid & 1) << 4;
            const float* bp = Bw + (size_t)r2 * TH + k0 + kk2;
            #pragma unroll
            for (int c = 0; c < 16; c += 4) {
                f4 v = *(const f4*)(bp + c);
                Bs[(kk2 + c + 0) * LDB2 + r2] = v[0];
                Bs[(kk2 + c + 1) * LDB2 + r2] = v[1];
                Bs[(kk2 + c + 2) * LDB2 + r2] = v[2];
                Bs[(kk2 + c + 3) * LDB2 + r2] = v[3];
            }
        }
        __syncthreads();
        #pragma unroll
        for (int kk = 0; kk < KC; ++kk) {
            f4 a = *(const f4*)&As[kk * LDA + tr * 4];
            f4 b0 = *(const f4*)&Bs[kk * LDB2 + tc * 8];
            f4 b1 = *(const f4*)&Bs[kk * LDB2 + tc * 8 + 4];
            #pragma unroll
            for (int i = 0; i < 4; ++i) { acc[i][0] += a[i] * b0; acc[i][1] += a[i] * b1; }
        }
        __syncthreads();
    }
    int colb = tc * 8;
    f4 bb0 = *(const f4*)&bias[(perJoint ? j * TH : 0) + colb];
    f4 bb1 = *(const f4*)&bias[(perJoint ? j * TH : 0) + colb + 4];
    #pragma unroll
    for (int i = 0; i < 4; ++i) {
        int row = tr * 4 + i;
        float s = 0.f, q = 0.f;
        if (row < mrem) {
            size_t off = (size_t)((m0 + row) * TJ + j) * TH + colb;
            f4 r0 = *(const f4*)&resid[off];
            f4 r1 = *(const f4*)&resid[off + 4];
            acc[i][0] += bb0 + r0;
            acc[i][1] += bb1 + r1;
            #pragma unroll
            for (int u = 0; u < 4; ++u) {
                s += acc[i][0][u] + acc[i][1][u];
                q += acc[i][0][u] * acc[i][0][u] + acc[i][1][u] * acc[i][1][u];
            }
        }
        rsum[row * 17 + tc] = s;
        rsq[row * 17 + tc] = q;
    }
    __syncthreads();
    if (tid < 64) {
        float s = 0.f, q = 0.f;
        #pragma unroll
        for (int c = 0; c < 16; ++c) { s += rsum[tid * 17 + c]; q += rsq[tid * 17 + c]; }
        float mean = s * (1.0f / TH);
        float var = q * (1.0f / TH) - mean * mean;
        lnm[tid] = mean;
        lnr[tid] = rsqrtf(var + 1e-5f);
    }
    __syncthreads();
    f4 g0 = *(const f4*)&g[colb], g1 = *(const f4*)&g[colb + 4];
    f4 l0 = *(const f4*)&bln[colb], l1 = *(const f4*)&bln[colb + 4];
    #pragma unroll
    for (int i = 0; i < 4; ++i) {
        int row = tr * 4 + i;
        if (row < mrem) {
            float mean = lnm[row], rstd = lnr[row];
            size_t off = (size_t)((m0 + row) * TJ + j) * TH + colb;
            f4 o0 = (acc[i][0] - mean) * rstd * g0 + l0;
            f4 o1 = (acc[i][1] - mean) * rstd * g1 + l1;
            if (addv) { o0 += *(const f4*)&addv[off]; o1 += *(const f4*)&addv[off + 4]; }
            *(f4*)&Y[off] = o0;
            *(f4*)&Y[off + 4] = o1;
        }
    }
}

// ---------------- FFN GEMMs ----------------
// grid (90, 4): M=5760 contiguous, N=256, K=128; relu*2 epilogue
__global__ __launch_bounds__(256) void gemm_ffn1_kernel(
        const float* __restrict__ Y, const float* __restrict__ W1,
        const float* __restrict__ b1, float* __restrict__ Fb) {
    __shared__ __align__(16) float As[KC * LDA];
    __shared__ __align__(16) float Bs[KC * LDA];
    int tid = threadIdx.x;
    int m0 = blockIdx.x * 64;
    int n0 = blockIdx.y * 64;
    const float* A = Y + (size_t)m0 * TH;
    const float* Bw = W1 + (size_t)n0 * TH;
    f4 acc[4] = {{0,0,0,0},{0,0,0,0},{0,0,0,0},{0,0,0,0}};
    for (int k0 = 0; k0 < TH; k0 += KC) {
        stageA(As, A, TH, 64, TH, k0, tid);
        stageB64(Bs, Bw, TH, k0, tid);
        __syncthreads();
        mac64(As, Bs, tid >> 4, tid & 15, acc);
        __syncthreads();
    }
    int tr = tid >> 4, tc = tid & 15;
    f4 b4 = *(const f4*)&b1[n0 + tc * 4];
    #pragma unroll
    for (int i = 0; i < 4; ++i) {
        f4 o = acc[i] + b4;
        #pragma unroll
        for (int u = 0; u < 4; ++u) o[u] = 2.0f * fmaxf(o[u], 0.0f);
        *(f4*)&Fb[(size_t)(m0 + tr * 4 + i) * TF + n0 + tc * 4] = o;
    }
}

// grid (90, 2): M=5760, N=128, K=256
__global__ __launch_bounds__(256) void gemm_ffn2_kernel(
        const float* __restrict__ Fb, const float* __restrict__ W2,
        const float* __restrict__ b2, float* __restrict__ Out) {
    __shared__ __align__(16) float As[KC * LDA];
    __shared__ __align__(16) float Bs[KC * LDA];
    int tid = threadIdx.x;
    int m0 = blockIdx.x * 64;
    int n0 = blockIdx.y * 64;
    const float* A = Fb + (size_t)m0 * TF;
    const float* Bw = W2 + (size_t)n0 * TF;
    f4 acc[4] = {{0,0,0,0},{0,0,0,0},{0,0,0,0},{0,0,0,0}};
    for (int k0 = 0; k0 < TF; k0 += KC) {
        stageA(As, A, TF, 64, TF, k0, tid);
        stageB64(Bs, Bw, TF, k0, tid);
        __syncthreads();
        mac64(As, Bs, tid >> 4, tid & 15, acc);
        __syncthreads();
    }
    int tr = tid >> 4, tc = tid & 15;
    f4 b4 = *(const f4*)&b2[n0 + tc * 4];
    #pragma unroll
    for (int i = 0; i < 4; ++i)
        *(f4*)&Out[(size_t)(m0 + tr * 4 + i) * TH + n0 + tc * 4] = acc[i] + b4;
}

// ---------------- baseline causal temporal attention (batched) ----------------
// grid: TB*TJ*TNH = 384 blocks, 256 threads (4 waves). Stage Q/K/V head-slices
// in LDS ([120][17] pad: 17 coprime 32 -> conflict-free); wave w handles
// queries q = w, w+4, ... Lane k scores key k and k+64; shuffle reductions.
__global__ __launch_bounds__(256) void attn_causal2_kernel(
        const float* __restrict__ Q, const float* __restrict__ K,
        const float* __restrict__ V, float* __restrict__ O) {
    __shared__ float Qs[TW][APAD], Ks[TW][APAD], Vs[TW][APAD];
    __shared__ float Ps[4][TW];
    int blk = blockIdx.x;
    int head = blk & 7;
    int j = (blk >> 3) % TJ;
    int b = (blk >> 3) / TJ;
    int tid = threadIdx.x;
    int sd = tid & 15, sr = tid >> 4;
    for (int r = sr; r < TW; r += 16) {
        size_t off = (size_t)((r * TB + b) * TJ + j) * TH + head * THD + sd;
        Qs[r][sd] = Q[off]; Ks[r][sd] = K[off]; Vs[r][sd] = V[off];
    }
    __syncthreads();
    int wave = tid >> 6, lane = tid & 63;
    int dd = lane & 15, c = lane >> 4;
    for (int q = wave; q < TW; q += 4) {
        int k0 = lane, k1 = lane + 64;
        float s0 = -1e30f, s1 = -1e30f;
        if (k0 <= q) {
            float a = 0.f;
            #pragma unroll
            for (int u = 0; u < THD; ++u) a += Qs[q][u] * Ks[k0][u];
            s0 = a * 0.25f;
        }
        if (k1 <= q) {
            float a = 0.f;
            #pragma unroll
            for (int u = 0; u < THD; ++u) a += Qs[q][u] * Ks[k1][u];
            s1 = a * 0.25f;
        }
        float m = fmaxf(s0, s1);
        #pragma unroll
        for (int o = 32; o > 0; o >>= 1) m = fmaxf(m, __shfl_xor(m, o));
        float p0 = (k0 <= q) ? __expf(s0 - m) : 0.f;
        float p1 = (k1 <= q) ? __expf(s1 - m) : 0.f;
        float sum = p0 + p1;
        #pragma unroll
        for (int o = 32; o > 0; o >>= 1) sum += __shfl_xor(sum, o);
        float inv = 1.0f / sum;
        Ps[wave][k0] = p0;
        if (k1 < TW) Ps[wave][k1] = p1;
        // intra-wave LDS RAW: in-order DS pipe, no block barrier needed
        float acc = 0.f;
        for (int k = c; k <= q; k += 4) acc += Ps[wave][k] * Vs[k][dd];
        acc += __shfl_xor(acc, 16);
        acc += __shfl_xor(acc, 32);
        if (lane < 16)
            O[(size_t)((q * TB + b) * TJ + j) * TH + head * THD + dd] = acc * inv;
    }
}

// ---------------- special-row temporal attention (batched, single query t) ----
// keys 0..t-1 from baseline Kb/Vb; key t from special Ks/Vs (row t)
__global__ __launch_bounds__(256) void attn_special2_kernel(
        const float* __restrict__ Qsp_g, const float* __restrict__ Ksp_g,
        const float* __restrict__ Vsp_g, const float* __restrict__ Kb_g,
        const float* __restrict__ Vb_g, float* __restrict__ O) {
    __shared__ float Qsp[TW][APAD], Ksp[TW][APAD], Vsp[TW][APAD];
    __shared__ float Kb[TW][APAD], Vb[TW][APAD];
    __shared__ float Ps[4][TW];
    int blk = blockIdx.x;
    int head = blk & 7;
    int j = (blk >> 3) % TJ;
    int b = (blk >> 3) / TJ;
    int tid = threadIdx.x;
    int sd = tid & 15, sr = tid >> 4;
    for (int r = sr; r < TW; r += 16) {
        size_t off = (size_t)((r * TB + b) * TJ + j) * TH + head * THD + sd;
        Qsp[r][sd] = Qsp_g[off]; Ksp[r][sd] = Ksp_g[off]; Vsp[r][sd] = Vsp_g[off];
        Kb[r][sd] = Kb_g[off];   Vb[r][sd] = Vb_g[off];
    }
    __syncthreads();
    int wave = tid >> 6, lane = tid & 63;
    int dd = lane & 15, c = lane >> 4;
    for (int t = wave; t < TW; t += 4) {
        int k0 = lane, k1 = lane + 64;
        float s0 = -1e30f, s1 = -1e30f;
        if (k0 <= t) {
            const float* krow = (k0 == t) ? Ksp[t] : Kb[k0];
            float a = 0.f;
            #pragma unroll
            for (int u = 0; u < THD; ++u) a += Qsp[t][u] * krow[u];
            s0 = a * 0.25f;
        }
        if (k1 <= t) {
            const float* krow = (k1 == t) ? Ksp[t] : Kb[k1];
            float a = 0.f;
            #pragma unroll
            for (int u = 0; u < THD; ++u) a += Qsp[t][u] * krow[u];
            s1 = a * 0.25f;
        }
        float m = fmaxf(s0, s1);
        #pragma unroll
        for (int o = 32; o > 0; o >>= 1) m = fmaxf(m, __shfl_xor(m, o));
        float p0 = (k0 <= t) ? __expf(s0 - m) : 0.f;
        float p1 = (k1 <= t) ? __expf(s1 - m) : 0.f;
        float sum = p0 + p1;
        #pragma unroll
        for (int o = 32; o > 0; o >>= 1) sum += __shfl_xor(sum, o);
        float inv = 1.0f / sum;
        Ps[wave][k0] = p0;
        if (k1 < TW) Ps[wave][k1] = p1;
        float acc = 0.f;
        for (int k = c; k < t; k += 4) acc += Ps[wave][k] * Vb[k][dd];
        if ((t & 3) == c) acc += Ps[wave][t] * Vsp[t][dd];
        acc += __shfl_xor(acc, 16);
        acc += __shfl_xor(acc, 32);
        if (lane < 16)
            O[(size_t)((t * TB + b) * TJ + j) * TH + head * THD + dd] = acc * inv;
    }
}

// ---------------- spatial attention over joints (batched per frame) ----------
// grid TW*TB = 240 blocks, 192 threads; thread = (head, qj); K/V/Q rows for a
// frame are CONTIGUOUS (j fastest) -> f4-coalesced staging.
#define SPAD (TH + 4)
__global__ __launch_bounds__(192) void attn_spatial2_kernel(
        const float* __restrict__ Q, const float* __restrict__ K,
        const float* __restrict__ V, float* __restrict__ O) {
    __shared__ __align__(16) float Qs[TJ][SPAD], Ks[TJ][SPAD], Vs[TJ][SPAD];
    int blk = blockIdx.x;
    int b = blk & 1, t = blk >> 1;
    int base = (t * TB + b) * TJ;
    int tid = threadIdx.x;
    for (int i = tid; i < TJ * 32; i += 192) {
        int r = i >> 5, c4 = i & 31;
        ((f4*)&Qs[r][0])[c4] = ((const f4*)(Q + (size_t)(base + r) * TH))[c4];
        ((f4*)&Ks[r][0])[c4] = ((const f4*)(K + (size_t)(base + r) * TH))[c4];
        ((f4*)&Vs[r][0])[c4] = ((const f4*)(V + (size_t)(base + r) * TH))[c4];
    }
    __syncthreads();
    int qj = tid % TJ;
    int head = tid / TJ;   // 0..7
    int hb = head * THD;
    float qv[THD];
    #pragma unroll
    for (int u = 0; u < THD; ++u) qv[u] = Qs[qj][hb + u];
    float sc[TJ];
    float m = -1e30f;
    #pragma unroll
    for (int k = 0; k < TJ; ++k) {
        float a = 0.f;
        #pragma unroll
        for (int u = 0; u < THD; ++u) a += qv[u] * Ks[k][hb + u];
        sc[k] = a * 0.25f;
        m = fmaxf(m, sc[k]);
    }
    float sum = 0.f;
    #pragma unroll
    for (int k = 0; k < TJ; ++k) { sc[k] = __expf(sc[k] - m); sum += sc[k]; }
    float inv = 1.0f / sum;
    float o[THD];
    #pragma unroll
    for (int u = 0; u < THD; ++u) o[u] = 0.f;
    #pragma unroll
    for (int k = 0; k < TJ; ++k) {
        #pragma unroll
        for (int u = 0; u < THD; ++u) o[u] += sc[k] * Vs[k][hb + u];
    }
    size_t off = (size_t)(base + qj) * TH + hb;
    #pragma unroll
    for (int u = 0; u < THD; u += 4) {
        f4 v = {o[u] * inv, o[u+1] * inv, o[u+2] * inv, o[u+3] * inv};
        *(f4*)&O[off + u] = v;
    }
}

// ---------------- final projection + residual ----------------
__global__ void final_kernel(const float* __restrict__ r4, const float* __restrict__ Wout,
                             const float* __restrict__ bout, const float* __restrict__ src,
                             const float* __restrict__ tgt, float* __restrict__ out) {
    int idx = blockIdx.x * 256 + threadIdx.x;
    if (idx >= TB * TW * TD) return;
    int d = idx % TD;
    int t = (idx / TD) % TW;
    int b = idx / (TD * TW);
    int j = d / 9, o = d % 9;
    const float* rr = r4 + (size_t)((t * TB + b) * TJ + j) * TH;
    const float* wt = Wout + (size_t)o * TH;
    float acc = bout[o];
    #pragma unroll 4
    for (int h = 0; h < TH; ++h) acc += rr[h] * wt[h];
    float cv = (t < 60) ? src[((size_t)b * 60 + t) * TD + d]
                        : tgt[((size_t)b * 61 + (t - 60)) * TD + d];
    out[idx] = acc + cv;
}

extern "C" void kernel_launch(void* const* d_in, const int* in_sizes, int n_in,
                              void* d_out, int out_size, void* d_ws, size_t ws_size,
                              hipStream_t stream) {
    const float* src    = (const float*)d_in[0];
    const float* tgt    = (const float*)d_in[1];
    const float* Wemb   = (const float*)d_in[2];
    const float* bemb   = (const float*)d_in[3];
    const float* Wqkv_s = (const float*)d_in[4];
    const float* bqkv_s = (const float*)d_in[5];
    const float* Wo_s   = (const float*)d_in[6];
    const float* bo_s   = (const float*)d_in[7];
    const float* sn_g   = (const float*)d_in[8];
    const float* sn_b   = (const float*)d_in[9];
    const float* Wqkv_t = (const float*)d_in[10];
    const float* bqkv_t = (const float*)d_in[11];
    const float* Wo_t   = (const float*)d_in[12];
    const float* bo_t   = (const float*)d_in[13];
    const float* tn_g   = (const float*)d_in[14];
    const float* tn_b   = (const float*)d_in[15];
    const float* W1     = (const float*)d_in[16];
    const float* b1     = (const float*)d_in[17];
    const float* W2     = (const float*)d_in[18];
    const float* b2     = (const float*)d_in[19];
    const float* Wout   = (const float*)d_in[20];
    const float* bout   = (const float*)d_in[21];
    float* out = (float*)d_out;

    float* ws = (float*)d_ws;
    const size_t RH = (size_t)TROWS * TH;   // 737280
    float* x0    = ws;
    float* Kbase = x0 + RH;          // 4*RH
    float* Vbase = Kbase + 4 * RH;   // 4*RH
    float* r     = Vbase + 4 * RH;
    float* Qb    = r + RH;
    float* Kb    = Qb + RH;
    float* Vb    = Kb + RH;
    float* attnb = Vb + RH;
    float* yb    = attnb + RH;
    float* spoutb= yb + RH;
    float* Bb0   = spoutb + RH;
    float* Bb1   = Bb0 + RH;
    float* fbuf  = Bb1 + RH;         // TROWS*TF (also reused as cbuf for embed)

    // 1. gather concat, then embedding GEMM (+PE)
    gather_kernel<<<(TBF * TD + 255) / 256, 256, 0, stream>>>(src, tgt, fbuf);
    gemm_embed_kernel<<<dim3(4, 48), 256, 0, stream>>>(fbuf, Wemb, bemb, x0);

    // 2. baseline pass (temporal-only stack); save per-layer K/V projections
    const float* Bin = x0;
    for (int l = 0; l < 4; ++l) {
        gemm_qkv_kernel<<<dim3(4, 6, 24), 256, 0, stream>>>(
            Bin, Wqkv_t + (size_t)l * TJ * 3 * TH * TH, bqkv_t + (size_t)l * TJ * 3 * TH,
            Qb, Kbase + l * RH, Vbase + l * RH, 1);
        if (l < 3) {
            attn_causal2_kernel<<<TB * TJ * TNH, 256, 0, stream>>>(
                Qb, Kbase + l * RH, Vbase + l * RH, attnb);
            gemm_oln_kernel<<<dim3(4, 1, 24), 256, 0, stream>>>(
                attnb, Wo_t + (size_t)l * TJ * TH * TH, bo_t + (size_t)l * TJ * TH,
                Bin, tn_g + l * TH, tn_b + l * TH, nullptr, yb, 1);
            gemm_ffn1_kernel<<<dim3(90, 4), 256, 0, stream>>>(
                yb, W1 + (size_t)l * TF * TH, b1 + (size_t)l * TF, fbuf);
            float* Bout = (l & 1) ? Bb1 : Bb0;
            gemm_ffn2_kernel<<<dim3(90, 2), 256, 0, stream>>>(
                fbuf, W2 + (size_t)l * TH * TF, b2 + (size_t)l * TH, Bout);
            Bin = Bout;
        }
    }

    // 3. per-t special-row chains (all 120 t in parallel)
    hipMemcpyAsync(r, x0, RH * sizeof(float), hipMemcpyDeviceToDevice, stream);
    for (int l = 0; l < 4; ++l) {
        gemm_qkv_kernel<<<dim3(4, 6, 24), 256, 0, stream>>>(
            r, Wqkv_s + (size_t)l * 3 * TH * TH, bqkv_s + (size_t)l * 3 * TH, Qb, Kb, Vb, 0);
        attn_spatial2_kernel<<<TW * TB, 192, 0, stream>>>(Qb, Kb, Vb, attnb);
        gemm_oln_kernel<<<dim3(4, 1, 24), 256, 0, stream>>>(
            attnb, Wo_s + (size_t)l * TH * TH, bo_s + (size_t)l * TH,
            r, sn_g + l * TH, sn_b + l * TH, nullptr, spoutb, 0);
        gemm_qkv_kernel<<<dim3(4, 6, 24), 256, 0, stream>>>(
            r, Wqkv_t + (size_t)l * TJ * 3 * TH * TH, bqkv_t + (size_t)l * TJ * 3 * TH,
            Qb, Kb, Vb, 1);
        attn_special2_kernel<<<TB * TJ * TNH, 256, 0, stream>>>(
            Qb, Kb, Vb, Kbase + l * RH, Vbase + l * RH, attnb);
        gemm_oln_kernel<<<dim3(4, 1, 24), 256, 0, stream>>>(
            attnb, Wo_t + (size_t)l * TJ * TH * TH, bo_t + (size_t)l * TJ * TH,
            r, tn_g + l * TH, tn_b + l * TH, spoutb, yb, 1);
        gemm_ffn1_kernel<<<dim3(90, 4), 256, 0, stream>>>(
            yb, W1 + (size_t)l * TF * TH, b1 + (size_t)l * TF, fbuf);
        gemm_ffn2_kernel<<<dim3(90, 2), 256, 0, stream>>>(
            fbuf, W2 + (size_t)l * TH * TF, b2 + (size_t)l * TH, r);
    }

    // 4. output projection + residual
    final_kernel<<<(TB * TW * TD + 255) / 256, 256, 0, stream>>>(r, Wout, bout, src, tgt, out);
}

// Round 6
// 883.413 us; speedup vs baseline: 7.3731x; 1.1755x over previous
//
#include <hip/hip_runtime.h>

// Sizes
#define TW 120     // window / number of parallel t-steps
#define TB 2       // batch
#define TJ 24      // joints
#define TH 128     // hidden
#define TNH 8      // heads
#define THD 16     // head dim
#define TF 256     // ffn
#define TD 216     // input dim
#define TROWS (TW*TB*TJ)   // 5760 rows of H
#define TEMB (TJ*TH)       // 3072
#define TBF 240            // t*b frames

#define KC 32
#define LDA 68     // 64 + 4 pad (keeps 16B alignment for f4 reads)
#define LDB2 132   // 128 + 4 pad
#define APAD 17    // attention LDS row pad: 17 coprime 32 -> ~2-way max (free)
#define QCH 60     // query chunk per attention block

typedef float f4 __attribute__((ext_vector_type(4)));

// ---------- GEMM building blocks: C[m][n] = sum_k A[m][k]*B[n][k] ----------
// LDS tiles stored transposed: As[k][m], Bs[k][n] -> outer-product inner loop.

__device__ __forceinline__ void stageA(float* As, const float* __restrict__ A,
                                       int a_stride, int mrem, int K, int k0, int tid) {
    int r = tid >> 2;              // 0..63 (tile row)
    int kk = (tid & 3) << 3;       // 0,8,16,24
    bool rowok = r < mrem;
    const float* ap = A + (size_t)r * a_stride + k0 + kk;
    #pragma unroll
    for (int c = 0; c < 8; c += 4) {
        f4 v = {0.f, 0.f, 0.f, 0.f};
        int kg = k0 + kk + c;
        if (rowok) {
            if (kg + 4 <= K) v = *(const f4*)(ap + c);
            else {
                #pragma unroll
                for (int u = 0; u < 4; ++u) if (kg + u < K) v[u] = ap[c + u];
            }
        }
        As[(kk + c + 0) * LDA + r] = v[0];
        As[(kk + c + 1) * LDA + r] = v[1];
        As[(kk + c + 2) * LDA + r] = v[2];
        As[(kk + c + 3) * LDA + r] = v[3];
    }
}

__device__ __forceinline__ void stageB64(float* Bs, const float* __restrict__ Bw,
                                         int K, int k0, int tid) {
    int r = tid >> 2;              // n index 0..63
    int kk = (tid & 3) << 3;
    const float* bp = Bw + (size_t)r * K + k0 + kk;
    #pragma unroll
    for (int c = 0; c < 8; c += 4) {
        f4 v = {0.f, 0.f, 0.f, 0.f};
        int kg = k0 + kk + c;
        if (kg + 4 <= K) v = *(const f4*)(bp + c);
        else {
            #pragma unroll
            for (int u = 0; u < 4; ++u) if (kg + u < K) v[u] = bp[c + u];
        }
        Bs[(kk + c + 0) * LDA + r] = v[0];
        Bs[(kk + c + 1) * LDA + r] = v[1];
        Bs[(kk + c + 2) * LDA + r] = v[2];
        Bs[(kk + c + 3) * LDA + r] = v[3];
    }
}

__device__ __forceinline__ void mac64(const float* As, const float* Bs, int tr, int tc, f4 acc[4]) {
    #pragma unroll
    for (int kk = 0; kk < KC; ++kk) {
        f4 a = *(const f4*)&As[kk * LDA + tr * 4];
        f4 b = *(const f4*)&Bs[kk * LDA + tc * 4];
        acc[0] += a[0] * b;
        acc[1] += a[1] * b;
        acc[2] += a[2] * b;
        acc[3] += a[3] * b;
    }
}

// ---------------- gather concat into contiguous [240][216] ----------------
__global__ void gather_kernel(const float* __restrict__ src, const float* __restrict__ tgt,
                              float* __restrict__ cbuf) {
    int idx = blockIdx.x * 256 + threadIdx.x;
    if (idx >= TBF * TD) return;
    int d = idx % TD;
    int row = idx / TD;
    int b = row & 1, t = row >> 1;
    cbuf[idx] = (t < 60) ? src[((size_t)b * 60 + t) * TD + d]
                         : tgt[((size_t)b * 61 + (t - 60)) * TD + d];
}

// ---------------- embedding GEMM + bias + PE ----------------
// grid (4, 48): M=240 (rows t*2+b), N=3072, K=216
__global__ __launch_bounds__(256) void gemm_embed_kernel(
        const float* __restrict__ cbuf, const float* __restrict__ Wemb,
        const float* __restrict__ bemb, float* __restrict__ x0) {
    __shared__ __align__(16) float As[KC * LDA];
    __shared__ __align__(16) float Bs[KC * LDA];
    int tid = threadIdx.x;
    int m0 = blockIdx.x * 64;
    int n0 = blockIdx.y * 64;
    int mrem = TBF - m0; if (mrem > 64) mrem = 64;
    const float* A = cbuf + (size_t)m0 * TD;
    const float* Bw = Wemb + (size_t)n0 * TD;
    f4 acc[4] = {{0,0,0,0},{0,0,0,0},{0,0,0,0},{0,0,0,0}};
    for (int k0 = 0; k0 < TD; k0 += KC) {
        stageA(As, A, TD, mrem, TD, k0, tid);
        stageB64(Bs, Bw, TD, k0, tid);
        __syncthreads();
        mac64(As, Bs, tid >> 4, tid & 15, acc);
        __syncthreads();
    }
    int tr = tid >> 4, tc = tid & 15;
    int nb = n0 + tc * 4;
    f4 b4 = *(const f4*)&bemb[nb];
    #pragma unroll
    for (int i = 0; i < 4; ++i) {
        int row = tr * 4 + i;
        if (row < mrem) {
            int grow = m0 + row;
            int t = grow >> 1;
            f4 o = acc[i] + b4;
            #pragma unroll
            for (int u = 0; u < 4; ++u) {
                int n = nb + u;
                float freq = expf((float)(n & ~1) * (-9.2103403719761836f / 3072.0f));
                float ang = (float)t * freq;
                o[u] += (n & 1) ? cosf(ang) : sinf(ang);
            }
            *(f4*)&x0[(size_t)grow * TEMB + nb] = o;
        }
    }
}

// ---------------- QKV GEMM (per-joint or shared weights) ----------------
// grid (4, 6, 24): per joint j, M=240 frames (rows strided TJ*TH), N=384, K=128
__global__ __launch_bounds__(256) void gemm_qkv_kernel(
        const float* __restrict__ X, const float* __restrict__ W, const float* __restrict__ bias,
        float* __restrict__ Q, float* __restrict__ Kd, float* __restrict__ V, int perJoint) {
    __shared__ __align__(16) float As[KC * LDA];
    __shared__ __align__(16) float Bs[KC * LDA];
    int tid = threadIdx.x;
    int m0 = blockIdx.x * 64;
    int n0 = blockIdx.y * 64;
    int j  = blockIdx.z;
    int mrem = TBF - m0; if (mrem > 64) mrem = 64;
    const float* A = X + (size_t)m0 * (TJ * TH) + (size_t)j * TH;
    const float* Bw = W + (perJoint ? (size_t)j * 3 * TH * TH : 0) + (size_t)n0 * TH;
    f4 acc[4] = {{0,0,0,0},{0,0,0,0},{0,0,0,0},{0,0,0,0}};
    for (int k0 = 0; k0 < TH; k0 += KC) {
        stageA(As, A, TJ * TH, mrem, TH, k0, tid);
        stageB64(Bs, Bw, TH, k0, tid);
        __syncthreads();
        mac64(As, Bs, tid >> 4, tid & 15, acc);
        __syncthreads();
    }
    int tr = tid >> 4, tc = tid & 15;
    float* dst = (n0 < TH) ? Q : ((n0 < 2 * TH) ? Kd : V);
    int col = (n0 & (TH - 1)) + tc * 4;
    f4 b4 = *(const f4*)&bias[(perJoint ? j * 3 * TH : 0) + n0 + tc * 4];
    #pragma unroll
    for (int i = 0; i < 4; ++i) {
        int row = tr * 4 + i;
        if (row < mrem) {
            int rj = (m0 + row) * TJ + j;
            *(f4*)&dst[(size_t)rj * TH + col] = acc[i] + b4;
        }
    }
}

// ---------------- out-proj GEMM + residual + LayerNorm (+ optional add) ----------------
// grid (4, 1, 24): per joint j, M=240, N=TH (full row in block), K=TH
__global__ __launch_bounds__(256) void gemm_oln_kernel(
        const float* __restrict__ Ain, const float* __restrict__ W, const float* __restrict__ bias,
        const float* __restrict__ resid, const float* __restrict__ g, const float* __restrict__ bln,
        const float* __restrict__ addv, float* __restrict__ Y, int perJoint) {
    __shared__ __align__(16) float As[KC * LDA];
    __shared__ __align__(16) float Bs[KC * LDB2];
    __shared__ float rsum[64 * 17];
    __shared__ float rsq[64 * 17];
    __shared__ float lnm[64], lnr[64];
    int tid = threadIdx.x;
    int m0 = blockIdx.x * 64;
    int j = blockIdx.z;
    int mrem = TBF - m0; if (mrem > 64) mrem = 64;
    const float* A = Ain + (size_t)m0 * (TJ * TH) + (size_t)j * TH;
    const float* Bw = W + (perJoint ? (size_t)j * TH * TH : 0);
    f4 acc[4][2] = {{{0,0,0,0},{0,0,0,0}},{{0,0,0,0},{0,0,0,0}},
                    {{0,0,0,0},{0,0,0,0}},{{0,0,0,0},{0,0,0,0}}};
    int tr = tid >> 4, tc = tid & 15;
    for (int k0 = 0; k0 < TH; k0 += KC) {
        stageA(As, A, TJ * TH, mrem, TH, k0, tid);
        {   // stage B: 128 n-rows, transposed
            int r2 = tid >> 1, kk2 = (tid & 1) << 4;
            const float* bp = Bw + (size_t)r2 * TH + k0 + kk2;
            #pragma unroll
            for (int c = 0; c < 16; c += 4) {
                f4 v = *(const f4*)(bp + c);
                Bs[(kk2 + c + 0) * LDB2 + r2] = v[0];
                Bs[(kk2 + c + 1) * LDB2 + r2] = v[1];
                Bs[(kk2 + c + 2) * LDB2 + r2] = v[2];
                Bs[(kk2 + c + 3) * LDB2 + r2] = v[3];
            }
        }
        __syncthreads();
        #pragma unroll
        for (int kk = 0; kk < KC; ++kk) {
            f4 a = *(const f4*)&As[kk * LDA + tr * 4];
            f4 b0 = *(const f4*)&Bs[kk * LDB2 + tc * 8];
            f4 b1 = *(const f4*)&Bs[kk * LDB2 + tc * 8 + 4];
            #pragma unroll
            for (int i = 0; i < 4; ++i) { acc[i][0] += a[i] * b0; acc[i][1] += a[i] * b1; }
        }
        __syncthreads();
    }
    int colb = tc * 8;
    f4 bb0 = *(const f4*)&bias[(perJoint ? j * TH : 0) + colb];
    f4 bb1 = *(const f4*)&bias[(perJoint ? j * TH : 0) + colb + 4];
    #pragma unroll
    for (int i = 0; i < 4; ++i) {
        int row = tr * 4 + i;
        float s = 0.f, q = 0.f;
        if (row < mrem) {
            size_t off = (size_t)((m0 + row) * TJ + j) * TH + colb;
            f4 r0 = *(const f4*)&resid[off];
            f4 r1 = *(const f4*)&resid[off + 4];
            acc[i][0] += bb0 + r0;
            acc[i][1] += bb1 + r1;
            #pragma unroll
            for (int u = 0; u < 4; ++u) {
                s += acc[i][0][u] + acc[i][1][u];
                q += acc[i][0][u] * acc[i][0][u] + acc[i][1][u] * acc[i][1][u];
            }
        }
        rsum[row * 17 + tc] = s;
        rsq[row * 17 + tc] = q;
    }
    __syncthreads();
    if (tid < 64) {
        float s = 0.f, q = 0.f;
        #pragma unroll
        for (int c = 0; c < 16; ++c) { s += rsum[tid * 17 + c]; q += rsq[tid * 17 + c]; }
        float mean = s * (1.0f / TH);
        float var = q * (1.0f / TH) - mean * mean;
        lnm[tid] = mean;
        lnr[tid] = rsqrtf(var + 1e-5f);
    }
    __syncthreads();
    f4 g0 = *(const f4*)&g[colb], g1 = *(const f4*)&g[colb + 4];
    f4 l0 = *(const f4*)&bln[colb], l1 = *(const f4*)&bln[colb + 4];
    #pragma unroll
    for (int i = 0; i < 4; ++i) {
        int row = tr * 4 + i;
        if (row < mrem) {
            float mean = lnm[row], rstd = lnr[row];
            size_t off = (size_t)((m0 + row) * TJ + j) * TH + colb;
            f4 o0 = (acc[i][0] - mean) * rstd * g0 + l0;
            f4 o1 = (acc[i][1] - mean) * rstd * g1 + l1;
            if (addv) { o0 += *(const f4*)&addv[off]; o1 += *(const f4*)&addv[off + 4]; }
            *(f4*)&Y[off] = o0;
            *(f4*)&Y[off + 4] = o1;
        }
    }
}

// ---------------- FFN GEMMs ----------------
// grid (90, 4): M=5760 contiguous, N=256, K=128; relu*2 epilogue
__global__ __launch_bounds__(256) void gemm_ffn1_kernel(
        const float* __restrict__ Y, const float* __restrict__ W1,
        const float* __restrict__ b1, float* __restrict__ Fb) {
    __shared__ __align__(16) float As[KC * LDA];
    __shared__ __align__(16) float Bs[KC * LDA];
    int tid = threadIdx.x;
    int m0 = blockIdx.x * 64;
    int n0 = blockIdx.y * 64;
    const float* A = Y + (size_t)m0 * TH;
    const float* Bw = W1 + (size_t)n0 * TH;
    f4 acc[4] = {{0,0,0,0},{0,0,0,0},{0,0,0,0},{0,0,0,0}};
    for (int k0 = 0; k0 < TH; k0 += KC) {
        stageA(As, A, TH, 64, TH, k0, tid);
        stageB64(Bs, Bw, TH, k0, tid);
        __syncthreads();
        mac64(As, Bs, tid >> 4, tid & 15, acc);
        __syncthreads();
    }
    int tr = tid >> 4, tc = tid & 15;
    f4 b4 = *(const f4*)&b1[n0 + tc * 4];
    #pragma unroll
    for (int i = 0; i < 4; ++i) {
        f4 o = acc[i] + b4;
        #pragma unroll
        for (int u = 0; u < 4; ++u) o[u] = 2.0f * fmaxf(o[u], 0.0f);
        *(f4*)&Fb[(size_t)(m0 + tr * 4 + i) * TF + n0 + tc * 4] = o;
    }
}

// grid (90, 2): M=5760, N=128, K=256
__global__ __launch_bounds__(256) void gemm_ffn2_kernel(
        const float* __restrict__ Fb, const float* __restrict__ W2,
        const float* __restrict__ b2, float* __restrict__ Out) {
    __shared__ __align__(16) float As[KC * LDA];
    __shared__ __align__(16) float Bs[KC * LDA];
    int tid = threadIdx.x;
    int m0 = blockIdx.x * 64;
    int n0 = blockIdx.y * 64;
    const float* A = Fb + (size_t)m0 * TF;
    const float* Bw = W2 + (size_t)n0 * TF;
    f4 acc[4] = {{0,0,0,0},{0,0,0,0},{0,0,0,0},{0,0,0,0}};
    for (int k0 = 0; k0 < TF; k0 += KC) {
        stageA(As, A, TF, 64, TF, k0, tid);
        stageB64(Bs, Bw, TF, k0, tid);
        __syncthreads();
        mac64(As, Bs, tid >> 4, tid & 15, acc);
        __syncthreads();
    }
    int tr = tid >> 4, tc = tid & 15;
    f4 b4 = *(const f4*)&b2[n0 + tc * 4];
    #pragma unroll
    for (int i = 0; i < 4; ++i)
        *(f4*)&Out[(size_t)(m0 + tr * 4 + i) * TH + n0 + tc * 4] = acc[i] + b4;
}

// ---------------- baseline causal temporal attention (query-chunked) --------
// grid (TB*TJ*TNH, 2) = 768 blocks, 512 threads (8 waves). Chunk c owns
// queries [c*60, c*60+60); stages K/V rows 0..qhi-1 and Q rows of the chunk.
// Wave w handles q = qlo+w, +8, ... Lane k scores keys k and k+64.
__global__ __launch_bounds__(512) void attn_causal2_kernel(
        const float* __restrict__ Q, const float* __restrict__ K,
        const float* __restrict__ V, float* __restrict__ O) {
    __shared__ float Qs[QCH][APAD], Ks[TW][APAD], Vs[TW][APAD];
    __shared__ float Ps[8][TW];
    int blk = blockIdx.x;
    int head = blk & 7;
    int j = (blk >> 3) % TJ;
    int b = (blk >> 3) / TJ;
    int qlo = blockIdx.y * QCH, qhi = qlo + QCH;
    int tid = threadIdx.x;
    int sd = tid & 15, sr = tid >> 4;   // sr 0..31
    for (int r = sr; r < qhi; r += 32) {
        size_t off = (size_t)((r * TB + b) * TJ + j) * TH + head * THD + sd;
        Ks[r][sd] = K[off]; Vs[r][sd] = V[off];
        if (r >= qlo) Qs[r - qlo][sd] = Q[off];
    }
    __syncthreads();
    int wave = tid >> 6, lane = tid & 63;
    int dd = lane & 15, c = lane >> 4;
    for (int q = qlo + wave; q < qhi; q += 8) {
        int k0 = lane, k1 = lane + 64;
        float s0 = -1e30f, s1 = -1e30f;
        if (k0 <= q) {
            float a = 0.f;
            #pragma unroll
            for (int u = 0; u < THD; ++u) a += Qs[q - qlo][u] * Ks[k0][u];
            s0 = a * 0.25f;
        }
        if (k1 <= q) {
            float a = 0.f;
            #pragma unroll
            for (int u = 0; u < THD; ++u) a += Qs[q - qlo][u] * Ks[k1][u];
            s1 = a * 0.25f;
        }
        float m = fmaxf(s0, s1);
        #pragma unroll
        for (int o = 32; o > 0; o >>= 1) m = fmaxf(m, __shfl_xor(m, o));
        float p0 = (k0 <= q) ? __expf(s0 - m) : 0.f;
        float p1 = (k1 <= q) ? __expf(s1 - m) : 0.f;
        float sum = p0 + p1;
        #pragma unroll
        for (int o = 32; o > 0; o >>= 1) sum += __shfl_xor(sum, o);
        float inv = 1.0f / sum;
        Ps[wave][k0] = p0;
        if (k1 < TW) Ps[wave][k1] = p1;
        // Ps slice is wave-private; intra-wave DS ops are in-order -> no barrier
        float acc = 0.f;
        for (int k = c; k <= q; k += 4) acc += Ps[wave][k] * Vs[k][dd];
        acc += __shfl_xor(acc, 16);
        acc += __shfl_xor(acc, 32);
        if (lane < 16)
            O[(size_t)((q * TB + b) * TJ + j) * TH + head * THD + dd] = acc * inv;
    }
}

// ---------------- special-row temporal attention (query-chunked) ------------
// keys 0..t-1 from baseline Kb/Vb; key t from special Ksp/Vsp (chunk rows only)
__global__ __launch_bounds__(512) void attn_special2_kernel(
        const float* __restrict__ Qsp_g, const float* __restrict__ Ksp_g,
        const float* __restrict__ Vsp_g, const float* __restrict__ Kb_g,
        const float* __restrict__ Vb_g, float* __restrict__ O) {
    __shared__ float Qsp[QCH][APAD], Ksp[QCH][APAD], Vsp[QCH][APAD];
    __shared__ float Kb[TW][APAD], Vb[TW][APAD];
    __shared__ float Ps[8][TW];
    int blk = blockIdx.x;
    int head = blk & 7;
    int j = (blk >> 3) % TJ;
    int b = (blk >> 3) / TJ;
    int qlo = blockIdx.y * QCH, qhi = qlo + QCH;
    int tid = threadIdx.x;
    int sd = tid & 15, sr = tid >> 4;
    for (int r = sr; r < qhi; r += 32) {
        size_t off = (size_t)((r * TB + b) * TJ + j) * TH + head * THD + sd;
        Kb[r][sd] = Kb_g[off]; Vb[r][sd] = Vb_g[off];
        if (r >= qlo) {
            Qsp[r - qlo][sd] = Qsp_g[off];
            Ksp[r - qlo][sd] = Ksp_g[off];
            Vsp[r - qlo][sd] = Vsp_g[off];
        }
    }
    __syncthreads();
    int wave = tid >> 6, lane = tid & 63;
    int dd = lane & 15, c = lane >> 4;
    for (int t = qlo + wave; t < qhi; t += 8) {
        int k0 = lane, k1 = lane + 64;
        float s0 = -1e30f, s1 = -1e30f;
        if (k0 <= t) {
            const float* krow = (k0 == t) ? Ksp[t - qlo] : Kb[k0];
            float a = 0.f;
            #pragma unroll
            for (int u = 0; u < THD; ++u) a += Qsp[t - qlo][u] * krow[u];
            s0 = a * 0.25f;
        }
        if (k1 <= t) {
            const float* krow = (k1 == t) ? Ksp[t - qlo] : Kb[k1];
            float a = 0.f;
            #pragma unroll
            for (int u = 0; u < THD; ++u) a += Qsp[t - qlo][u] * krow[u];
            s1 = a * 0.25f;
        }
        float m = fmaxf(s0, s1);
        #pragma unroll
        for (int o = 32; o > 0; o >>= 1) m = fmaxf(m, __shfl_xor(m, o));
        float p0 = (k0 <= t) ? __expf(s0 - m) : 0.f;
        float p1 = (k1 <= t) ? __expf(s1 - m) : 0.f;
        float sum = p0 + p1;
        #pragma unroll
        for (int o = 32; o > 0; o >>= 1) sum += __shfl_xor(sum, o);
        float inv = 1.0f / sum;
        Ps[wave][k0] = p0;
        if (k1 < TW) Ps[wave][k1] = p1;
        float acc = 0.f;
        for (int k = c; k < t; k += 4) acc += Ps[wave][k] * Vb[k][dd];
        if ((t & 3) == c) acc += Ps[wave][t] * Vsp[t - qlo][dd];
        acc += __shfl_xor(acc, 16);
        acc += __shfl_xor(acc, 32);
        if (lane < 16)
            O[(size_t)((t * TB + b) * TJ + j) * TH + head * THD + dd] = acc * inv;
    }
}

// ---------------- spatial attention over joints (batched per frame) ----------
// grid TW*TB = 240 blocks, 192 threads; thread = (head, qj); K/V/Q rows for a
// frame are CONTIGUOUS (j fastest) -> f4-coalesced staging.
#define SPAD (TH + 4)
__global__ __launch_bounds__(192) void attn_spatial2_kernel(
        const float* __restrict__ Q, const float* __restrict__ K,
        const float* __restrict__ V, float* __restrict__ O) {
    __shared__ __align__(16) float Qs[TJ][SPAD], Ks[TJ][SPAD], Vs[TJ][SPAD];
    int blk = blockIdx.x;
    int b = blk & 1, t = blk >> 1;
    int base = (t * TB + b) * TJ;
    int tid = threadIdx.x;
    for (int i = tid; i < TJ * 32; i += 192) {
        int r = i >> 5, c4 = i & 31;
        ((f4*)&Qs[r][0])[c4] = ((const f4*)(Q + (size_t)(base + r) * TH))[c4];
        ((f4*)&Ks[r][0])[c4] = ((const f4*)(K + (size_t)(base + r) * TH))[c4];
        ((f4*)&Vs[r][0])[c4] = ((const f4*)(V + (size_t)(base + r) * TH))[c4];
    }
    __syncthreads();
    int qj = tid % TJ;
    int head = tid / TJ;   // 0..7
    int hb = head * THD;
    float qv[THD];
    #pragma unroll
    for (int u = 0; u < THD; ++u) qv[u] = Qs[qj][hb + u];
    float sc[TJ];
    float m = -1e30f;
    #pragma unroll
    for (int k = 0; k < TJ; ++k) {
        float a = 0.f;
        #pragma unroll
        for (int u = 0; u < THD; ++u) a += qv[u] * Ks[k][hb + u];
        sc[k] = a * 0.25f;
        m = fmaxf(m, sc[k]);
    }
    float sum = 0.f;
    #pragma unroll
    for (int k = 0; k < TJ; ++k) { sc[k] = __expf(sc[k] - m); sum += sc[k]; }
    float inv = 1.0f / sum;
    float o[THD];
    #pragma unroll
    for (int u = 0; u < THD; ++u) o[u] = 0.f;
    #pragma unroll
    for (int k = 0; k < TJ; ++k) {
        #pragma unroll
        for (int u = 0; u < THD; ++u) o[u] += sc[k] * Vs[k][hb + u];
    }
    size_t off = (size_t)(base + qj) * TH + hb;
    #pragma unroll
    for (int u = 0; u < THD; u += 4) {
        f4 v = {o[u] * inv, o[u+1] * inv, o[u+2] * inv, o[u+3] * inv};
        *(f4*)&O[off + u] = v;
    }
}

// ---------------- final projection + residual ----------------
__global__ void final_kernel(const float* __restrict__ r4, const float* __restrict__ Wout,
                             const float* __restrict__ bout, const float* __restrict__ src,
                             const float* __restrict__ tgt, float* __restrict__ out) {
    int idx = blockIdx.x * 256 + threadIdx.x;
    if (idx >= TB * TW * TD) return;
    int d = idx % TD;
    int t = (idx / TD) % TW;
    int b = idx / (TD * TW);
    int j = d / 9, o = d % 9;
    const float* rr = r4 + (size_t)((t * TB + b) * TJ + j) * TH;
    const float* wt = Wout + (size_t)o * TH;
    float acc = bout[o];
    #pragma unroll 4
    for (int h = 0; h < TH; ++h) acc += rr[h] * wt[h];
    float cv = (t < 60) ? src[((size_t)b * 60 + t) * TD + d]
                        : tgt[((size_t)b * 61 + (t - 60)) * TD + d];
    out[idx] = acc + cv;
}

extern "C" void kernel_launch(void* const* d_in, const int* in_sizes, int n_in,
                              void* d_out, int out_size, void* d_ws, size_t ws_size,
                              hipStream_t stream) {
    const float* src    = (const float*)d_in[0];
    const float* tgt    = (const float*)d_in[1];
    const float* Wemb   = (const float*)d_in[2];
    const float* bemb   = (const float*)d_in[3];
    const float* Wqkv_s = (const float*)d_in[4];
    const float* bqkv_s = (const float*)d_in[5];
    const float* Wo_s   = (const float*)d_in[6];
    const float* bo_s   = (const float*)d_in[7];
    const float* sn_g   = (const float*)d_in[8];
    const float* sn_b   = (const float*)d_in[9];
    const float* Wqkv_t = (const float*)d_in[10];
    const float* bqkv_t = (const float*)d_in[11];
    const float* Wo_t   = (const float*)d_in[12];
    const float* bo_t   = (const float*)d_in[13];
    const float* tn_g   = (const float*)d_in[14];
    const float* tn_b   = (const float*)d_in[15];
    const float* W1     = (const float*)d_in[16];
    const float* b1     = (const float*)d_in[17];
    const float* W2     = (const float*)d_in[18];
    const float* b2     = (const float*)d_in[19];
    const float* Wout   = (const float*)d_in[20];
    const float* bout   = (const float*)d_in[21];
    float* out = (float*)d_out;

    float* ws = (float*)d_ws;
    const size_t RH = (size_t)TROWS * TH;   // 737280
    float* x0    = ws;
    float* Kbase = x0 + RH;          // 4*RH
    float* Vbase = Kbase + 4 * RH;   // 4*RH
    float* r     = Vbase + 4 * RH;
    float* Qb    = r + RH;
    float* Kb    = Qb + RH;
    float* Vb    = Kb + RH;
    float* attnb = Vb + RH;
    float* yb    = attnb + RH;
    float* spoutb= yb + RH;
    float* Bb0   = spoutb + RH;
    float* Bb1   = Bb0 + RH;
    float* fbuf  = Bb1 + RH;         // TROWS*TF (also reused as cbuf for embed)

    // 1. gather concat, then embedding GEMM (+PE)
    gather_kernel<<<(TBF * TD + 255) / 256, 256, 0, stream>>>(src, tgt, fbuf);
    gemm_embed_kernel<<<dim3(4, 48), 256, 0, stream>>>(fbuf, Wemb, bemb, x0);

    // 2. baseline pass (temporal-only stack); save per-layer K/V projections
    const float* Bin = x0;
    for (int l = 0; l < 4; ++l) {
        gemm_qkv_kernel<<<dim3(4, 6, 24), 256, 0, stream>>>(
            Bin, Wqkv_t + (size_t)l * TJ * 3 * TH * TH, bqkv_t + (size_t)l * TJ * 3 * TH,
            Qb, Kbase + l * RH, Vbase + l * RH, 1);
        if (l < 3) {
            attn_causal2_kernel<<<dim3(TB * TJ * TNH, 2), 512, 0, stream>>>(
                Qb, Kbase + l * RH, Vbase + l * RH, attnb);
            gemm_oln_kernel<<<dim3(4, 1, 24), 256, 0, stream>>>(
                attnb, Wo_t + (size_t)l * TJ * TH * TH, bo_t + (size_t)l * TJ * TH,
                Bin, tn_g + l * TH, tn_b + l * TH, nullptr, yb, 1);
            gemm_ffn1_kernel<<<dim3(90, 4), 256, 0, stream>>>(
                yb, W1 + (size_t)l * TF * TH, b1 + (size_t)l * TF, fbuf);
            float* Bout = (l & 1) ? Bb1 : Bb0;
            gemm_ffn2_kernel<<<dim3(90, 2), 256, 0, stream>>>(
                fbuf, W2 + (size_t)l * TH * TF, b2 + (size_t)l * TH, Bout);
            Bin = Bout;
        }
    }

    // 3. per-t special-row chains (all 120 t in parallel)
    hipMemcpyAsync(r, x0, RH * sizeof(float), hipMemcpyDeviceToDevice, stream);
    for (int l = 0; l < 4; ++l) {
        gemm_qkv_kernel<<<dim3(4, 6, 24), 256, 0, stream>>>(
            r, Wqkv_s + (size_t)l * 3 * TH * TH, bqkv_s + (size_t)l * 3 * TH, Qb, Kb, Vb, 0);
        attn_spatial2_kernel<<<TW * TB, 192, 0, stream>>>(Qb, Kb, Vb, attnb);
        gemm_oln_kernel<<<dim3(4, 1, 24), 256, 0, stream>>>(
            attnb, Wo_s + (size_t)l * TH * TH, bo_s + (size_t)l * TH,
            r, sn_g + l * TH, sn_b + l * TH, nullptr, spoutb, 0);
        gemm_qkv_kernel<<<dim3(4, 6, 24), 256, 0, stream>>>(
            r, Wqkv_t + (size_t)l * TJ * 3 * TH * TH, bqkv_t + (size_t)l * TJ * 3 * TH,
            Qb, Kb, Vb, 1);
        attn_special2_kernel<<<dim3(TB * TJ * TNH, 2), 512, 0, stream>>>(
            Qb, Kb, Vb, Kbase + l * RH, Vbase + l * RH, attnb);
        gemm_oln_kernel<<<dim3(4, 1, 24), 256, 0, stream>>>(
            attnb, Wo_t + (size_t)l * TJ * TH * TH, bo_t + (size_t)l * TJ * TH,
            r, tn_g + l * TH, tn_b + l * TH, spoutb, yb, 1);
        gemm_ffn1_kernel<<<dim3(90, 4), 256, 0, stream>>>(
            yb, W1 + (size_t)l * TF * TH, b1 + (size_t)l * TF, fbuf);
        gemm_ffn2_kernel<<<dim3(90, 2), 256, 0, stream>>>(
            fbuf, W2 + (size_t)l * TH * TF, b2 + (size_t)l * TH, r);
    }

    // 4. output projection + residual
    final_kernel<<<(TB * TW * TD + 255) / 256, 256, 0, stream>>>(r, Wout, bout, src, tgt, out);
}

// Round 7
// 514.736 us; speedup vs baseline: 12.6540x; 1.7162x over previous
//
#include <hip/hip_runtime.h>

// Sizes
#define TW 120     // window / number of parallel t-steps
#define TB 2       // batch
#define TJ 24      // joints
#define TH 128     // hidden
#define TNH 8      // heads
#define THD 16     // head dim
#define TF 256     // ffn
#define TD 216     // input dim
#define TROWS (TW*TB*TJ)   // 5760 rows of H
#define TEMB (TJ*TH)       // 3072
#define TBF 240            // t*b frames

#define KC 32
#define LDA 68     // fp32 GEMM LDS stride (64+4)
#define APAD 17    // attention LDS row pad: 17 coprime 32
#define QCH 60     // query chunk per attention block
#define LDT 136    // bf16 MFMA tile LDS row stride in shorts (128+8)

typedef float f4 __attribute__((ext_vector_type(4)));
typedef short bf8 __attribute__((ext_vector_type(8)));   // 8 bf16 = 4 VGPR
typedef short s4 __attribute__((ext_vector_type(4)));

__device__ __forceinline__ short f2bf(float x) {
    union { float f; unsigned u; } v; v.f = x;
    unsigned r = (v.u + 0x7FFFu + ((v.u >> 16) & 1u)) >> 16;
    return (short)r;
}

// ---------------- weight fp32->bf16 conversion (every call; ws is scratch) ----
#define NW_QKV_S 196608
#define NW_O_S    65536
#define NW_QKV_T 4718592
#define NW_O_T   1572864
#define NW_1      131072
#define NW_2      131072
#define OFF_O_S   (NW_QKV_S)
#define OFF_QKV_T (OFF_O_S + NW_O_S)
#define OFF_O_T   (OFF_QKV_T + NW_QKV_T)
#define OFF_W1    (OFF_O_T + NW_O_T)
#define OFF_W2    (OFF_W1 + NW_1)
#define NW_TOT    (OFF_W2 + NW_2)      // 6815744

__global__ void convert_weights_kernel(const float* __restrict__ Wqkv_s, const float* __restrict__ Wo_s,
                                       const float* __restrict__ Wqkv_t, const float* __restrict__ Wo_t,
                                       const float* __restrict__ W1, const float* __restrict__ W2,
                                       short* __restrict__ dst) {
    size_t i = ((size_t)blockIdx.x * 256 + threadIdx.x) * 4;
    if (i >= NW_TOT) return;
    const float* src; size_t off;
    if (i < NW_QKV_S)       { src = Wqkv_s; off = i; }
    else if (i < OFF_QKV_T) { src = Wo_s;   off = i - OFF_O_S; }
    else if (i < OFF_O_T)   { src = Wqkv_t; off = i - OFF_QKV_T; }
    else if (i < OFF_W1)    { src = Wo_t;   off = i - OFF_O_T; }
    else if (i < OFF_W2)    { src = W1;     off = i - OFF_W1; }
    else                    { src = W2;     off = i - OFF_W2; }
    f4 v = *(const f4*)(src + off);
    s4 o = { f2bf(v[0]), f2bf(v[1]), f2bf(v[2]), f2bf(v[3]) };
    *(s4*)(dst + i) = o;
}

// ---------------- MFMA building blocks ----------------
// stage a 64-row x 128-col bf16 tile (16B vector copies), zero-fill rows >= nrows
__device__ __forceinline__ void stage_bf(short* Ds, const short* __restrict__ src,
                                         size_t rstride, int nrows, int tid) {
    int r = tid >> 2, s = (tid & 3) * 32;
    short* d = Ds + r * LDT + s;
    if (r < nrows) {
        const short* p = src + (size_t)r * rstride + s;
        *(bf8*)(d)      = *(const bf8*)(p);
        *(bf8*)(d + 8)  = *(const bf8*)(p + 8);
        *(bf8*)(d + 16) = *(const bf8*)(p + 16);
        *(bf8*)(d + 24) = *(const bf8*)(p + 24);
    } else {
        bf8 z = {0,0,0,0,0,0,0,0};
        *(bf8*)(d) = z; *(bf8*)(d+8) = z; *(bf8*)(d+16) = z; *(bf8*)(d+24) = z;
    }
}

// 64x64 output tile, K=128 already staged: 4 waves as 2x2, 16 mfma each
__device__ __forceinline__ void mfma_tile64(const short* As, const short* Bs,
                                            int wave, int lane, f4 acc[2][2]) {
    int wm = wave >> 1, wn = wave & 1;
    int lrow = lane & 15, lk = (lane >> 4) * 8;
    #pragma unroll
    for (int ks = 0; ks < 4; ++ks) {
        bf8 a0 = *(const bf8*)&As[(wm*32      + lrow) * LDT + ks*32 + lk];
        bf8 a1 = *(const bf8*)&As[(wm*32 + 16 + lrow) * LDT + ks*32 + lk];
        bf8 b0 = *(const bf8*)&Bs[(wn*32      + lrow) * LDT + ks*32 + lk];
        bf8 b1 = *(const bf8*)&Bs[(wn*32 + 16 + lrow) * LDT + ks*32 + lk];
        acc[0][0] = __builtin_amdgcn_mfma_f32_16x16x32_bf16(a0, b0, acc[0][0], 0, 0, 0);
        acc[0][1] = __builtin_amdgcn_mfma_f32_16x16x32_bf16(a0, b1, acc[0][1], 0, 0, 0);
        acc[1][0] = __builtin_amdgcn_mfma_f32_16x16x32_bf16(a1, b0, acc[1][0], 0, 0, 0);
        acc[1][1] = __builtin_amdgcn_mfma_f32_16x16x32_bf16(a1, b1, acc[1][1], 0, 0, 0);
    }
}

// ---------------- QKV MFMA GEMM (per-joint or shared weights) ----------------
// grid (4, 6, 24): M=240 (bf16 act rows of TEMB, +j*TH), N=384, K=128
__global__ __launch_bounds__(256) void mfma_qkv_kernel(
        const short* __restrict__ Abf, const short* __restrict__ Wbf,
        const float* __restrict__ bias, float* __restrict__ Q,
        float* __restrict__ Kd, float* __restrict__ V, int perJoint) {
    __shared__ short As[64 * LDT], Bs[64 * LDT];
    int tid = threadIdx.x;
    int m0 = blockIdx.x * 64, n0 = blockIdx.y * 64, j = blockIdx.z;
    int mrem = TBF - m0; if (mrem > 64) mrem = 64;
    stage_bf(As, Abf + (size_t)m0 * TEMB + j * TH, TEMB, mrem, tid);
    stage_bf(Bs, Wbf + (perJoint ? (size_t)j * 3 * TH * TH : 0) + (size_t)n0 * TH, TH, 64, tid);
    __syncthreads();
    int wave = tid >> 6, lane = tid & 63;
    f4 acc[2][2] = {{{0,0,0,0},{0,0,0,0}},{{0,0,0,0},{0,0,0,0}}};
    mfma_tile64(As, Bs, wave, lane, acc);
    int wm = wave >> 1, wn = wave & 1, lrow = lane & 15, gr = (lane >> 4) * 4;
    float* dst = (n0 < TH) ? Q : ((n0 < 2 * TH) ? Kd : V);
    int cb = n0 & (TH - 1);
    int bofs = perJoint ? j * 3 * TH : 0;
    #pragma unroll
    for (int ni = 0; ni < 2; ++ni) {
        float bv = bias[bofs + n0 + wn*32 + ni*16 + lrow];
        int col = cb + wn*32 + ni*16 + lrow;
        #pragma unroll
        for (int mi = 0; mi < 2; ++mi)
            #pragma unroll
            for (int rg = 0; rg < 4; ++rg) {
                int tr = wm*32 + mi*16 + gr + rg;
                if (tr < mrem)
                    dst[(size_t)((m0 + tr) * TJ + j) * TH + col] = acc[mi][ni][rg] + bv;
            }
    }
}

// ---------------- out-proj MFMA + residual + LayerNorm (+ add) ----------------
// grid (15, 1, 24): 16 rows/block, N=128 (wave w owns cols [w*32,w*32+32)), K=128
__global__ __launch_bounds__(256) void mfma_oln_kernel(
        const short* __restrict__ Abf, const short* __restrict__ Wbf,
        const float* __restrict__ bias, const float* __restrict__ resid,
        const float* __restrict__ g, const float* __restrict__ bln,
        const float* __restrict__ addv, float* __restrict__ Yf,
        short* __restrict__ Ybf, int perJoint) {
    __shared__ short As[16 * LDT];
    __shared__ short Bs[128 * LDT];
    __shared__ float rsum[4][16], rsq[4][16], lnm[16], lnr[16];
    int tid = threadIdx.x;
    int m0 = blockIdx.x * 16, j = blockIdx.z;
    { int r = tid >> 4, s = (tid & 15) * 8;
      *(bf8*)&As[r * LDT + s] = *(const bf8*)(Abf + (size_t)(m0 + r) * TEMB + j * TH + s); }
    { int r = tid >> 1, s = (tid & 1) * 64;
      const short* p = Wbf + (perJoint ? (size_t)j * TH * TH : 0) + (size_t)r * TH + s;
      short* d = &Bs[r * LDT + s];
      #pragma unroll
      for (int c = 0; c < 64; c += 8) *(bf8*)(d + c) = *(const bf8*)(p + c); }
    __syncthreads();
    int wave = tid >> 6, lane = tid & 63, lrow = lane & 15, lk = (lane >> 4) * 8, gr = (lane >> 4) * 4;
    f4 acc[2] = {{0,0,0,0},{0,0,0,0}};
    #pragma unroll
    for (int ks = 0; ks < 4; ++ks) {
        bf8 a  = *(const bf8*)&As[lrow * LDT + ks*32 + lk];
        bf8 b0 = *(const bf8*)&Bs[(wave*32      + lrow) * LDT + ks*32 + lk];
        bf8 b1 = *(const bf8*)&Bs[(wave*32 + 16 + lrow) * LDT + ks*32 + lk];
        acc[0] = __builtin_amdgcn_mfma_f32_16x16x32_bf16(a, b0, acc[0], 0, 0, 0);
        acc[1] = __builtin_amdgcn_mfma_f32_16x16x32_bf16(a, b1, acc[1], 0, 0, 0);
    }
    int col0 = wave*32 + lrow, col1 = col0 + 16;
    int bofs = perJoint ? j * TH : 0;
    float bv0 = bias[bofs + col0], bv1 = bias[bofs + col1];
    float v0[4], v1[4], sr[4], sq[4];
    #pragma unroll
    for (int rg = 0; rg < 4; ++rg) {
        size_t ro = (size_t)(m0 + gr + rg) * TEMB + j * TH;
        v0[rg] = acc[0][rg] + bv0 + resid[ro + col0];
        v1[rg] = acc[1][rg] + bv1 + resid[ro + col1];
        sr[rg] = v0[rg] + v1[rg];
        sq[rg] = v0[rg]*v0[rg] + v1[rg]*v1[rg];
    }
    #pragma unroll
    for (int o = 1; o < 16; o <<= 1) {
        #pragma unroll
        for (int rg = 0; rg < 4; ++rg) { sr[rg] += __shfl_xor(sr[rg], o); sq[rg] += __shfl_xor(sq[rg], o); }
    }
    if (lrow == 0) {
        #pragma unroll
        for (int rg = 0; rg < 4; ++rg) { rsum[wave][gr + rg] = sr[rg]; rsq[wave][gr + rg] = sq[rg]; }
    }
    __syncthreads();
    if (tid < 16) {
        float s = rsum[0][tid] + rsum[1][tid] + rsum[2][tid] + rsum[3][tid];
        float q = rsq[0][tid] + rsq[1][tid] + rsq[2][tid] + rsq[3][tid];
        float mean = s * (1.0f / TH);
        float var = q * (1.0f / TH) - mean * mean;
        lnm[tid] = mean; lnr[tid] = rsqrtf(var + 1e-5f);
    }
    __syncthreads();
    float g0 = g[col0], g1 = g[col1], l0 = bln[col0], l1 = bln[col1];
    #pragma unroll
    for (int rg = 0; rg < 4; ++rg) {
        int row = gr + rg;
        float mean = lnm[row], rs = lnr[row];
        size_t ro = (size_t)(m0 + row) * TEMB + j * TH;
        float o0 = (v0[rg] - mean) * rs * g0 + l0;
        float o1 = (v1[rg] - mean) * rs * g1 + l1;
        if (addv) { o0 += addv[ro + col0]; o1 += addv[ro + col1]; }
        if (Yf)  { Yf[ro + col0] = o0; Yf[ro + col1] = o1; }
        if (Ybf) { Ybf[ro + col0] = f2bf(o0); Ybf[ro + col1] = f2bf(o1); }
    }
}

// ---------------- FFN MFMA GEMMs ----------------
// grid (90, 4): M=5760 contiguous bf16 [.][128], N=256, K=128; 2*relu -> bf16
__global__ __launch_bounds__(256) void mfma_ffn1_kernel(
        const short* __restrict__ Ybf, const short* __restrict__ W1bf,
        const float* __restrict__ b1, short* __restrict__ Fb) {
    __shared__ short As[64 * LDT], Bs[64 * LDT];
    int tid = threadIdx.x;
    int m0 = blockIdx.x * 64, n0 = blockIdx.y * 64;
    stage_bf(As, Ybf + (size_t)m0 * TH, TH, 64, tid);
    stage_bf(Bs, W1bf + (size_t)n0 * TH, TH, 64, tid);
    __syncthreads();
    int wave = tid >> 6, lane = tid & 63;
    f4 acc[2][2] = {{{0,0,0,0},{0,0,0,0}},{{0,0,0,0},{0,0,0,0}}};
    mfma_tile64(As, Bs, wave, lane, acc);
    int wm = wave >> 1, wn = wave & 1, lrow = lane & 15, gr = (lane >> 4) * 4;
    #pragma unroll
    for (int ni = 0; ni < 2; ++ni) {
        int col = n0 + wn*32 + ni*16 + lrow;
        float bv = b1[col];
        #pragma unroll
        for (int mi = 0; mi < 2; ++mi)
            #pragma unroll
            for (int rg = 0; rg < 4; ++rg) {
                int tr = wm*32 + mi*16 + gr + rg;
                float v = 2.0f * fmaxf(acc[mi][ni][rg] + bv, 0.0f);
                Fb[(size_t)(m0 + tr) * TF + col] = f2bf(v);
            }
    }
}

// grid (90, 2): M=5760 bf16 [.][256], N=128, K=256 (2 staged K-halves)
__global__ __launch_bounds__(256) void mfma_ffn2_kernel(
        const short* __restrict__ Fb, const short* __restrict__ W2bf,
        const float* __restrict__ b2, float* __restrict__ Outf,
        short* __restrict__ Outbf) {
    __shared__ short As[64 * LDT], Bs[64 * LDT];
    int tid = threadIdx.x;
    int m0 = blockIdx.x * 64, n0 = blockIdx.y * 64;
    int wave = tid >> 6, lane = tid & 63;
    f4 acc[2][2] = {{{0,0,0,0},{0,0,0,0}},{{0,0,0,0},{0,0,0,0}}};
    #pragma unroll
    for (int kk = 0; kk < 2; ++kk) {
        stage_bf(As, Fb + (size_t)m0 * TF + kk * 128, TF, 64, tid);
        stage_bf(Bs, W2bf + (size_t)n0 * TF + kk * 128, TF, 64, tid);
        __syncthreads();
        mfma_tile64(As, Bs, wave, lane, acc);
        __syncthreads();
    }
    int wm = wave >> 1, wn = wave & 1, lrow = lane & 15, gr = (lane >> 4) * 4;
    #pragma unroll
    for (int ni = 0; ni < 2; ++ni) {
        int col = n0 + wn*32 + ni*16 + lrow;
        float bv = b2[col];
        #pragma unroll
        for (int mi = 0; mi < 2; ++mi)
            #pragma unroll
            for (int rg = 0; rg < 4; ++rg) {
                int tr = wm*32 + mi*16 + gr + rg;
                float v = acc[mi][ni][rg] + bv;
                size_t off = (size_t)(m0 + tr) * TH + col;
                Outf[off] = v;
                Outbf[off] = f2bf(v);
            }
    }
}

// ---------- fp32 GEMM helpers (embed only) ----------
__device__ __forceinline__ void stageA(float* As, const float* __restrict__ A,
                                       int a_stride, int mrem, int K, int k0, int tid) {
    int r = tid >> 2;
    int kk = (tid & 3) << 3;
    bool rowok = r < mrem;
    const float* ap = A + (size_t)r * a_stride + k0 + kk;
    #pragma unroll
    for (int c = 0; c < 8; c += 4) {
        f4 v = {0.f, 0.f, 0.f, 0.f};
        int kg = k0 + kk + c;
        if (rowok) {
            if (kg + 4 <= K) v = *(const f4*)(ap + c);
            else {
                #pragma unroll
                for (int u = 0; u < 4; ++u) if (kg + u < K) v[u] = ap[c + u];
            }
        }
        As[(kk + c + 0) * LDA + r] = v[0];
        As[(kk + c + 1) * LDA + r] = v[1];
        As[(kk + c + 2) * LDA + r] = v[2];
        As[(kk + c + 3) * LDA + r] = v[3];
    }
}

__device__ __forceinline__ void stageB64(float* Bs, const float* __restrict__ Bw,
                                         int K, int k0, int tid) {
    int r = tid >> 2;
    int kk = (tid & 3) << 3;
    const float* bp = Bw + (size_t)r * K + k0 + kk;
    #pragma unroll
    for (int c = 0; c < 8; c += 4) {
        f4 v = {0.f, 0.f, 0.f, 0.f};
        int kg = k0 + kk + c;
        if (kg + 4 <= K) v = *(const f4*)(bp + c);
        else {
            #pragma unroll
            for (int u = 0; u < 4; ++u) if (kg + u < K) v[u] = bp[c + u];
        }
        Bs[(kk + c + 0) * LDA + r] = v[0];
        Bs[(kk + c + 1) * LDA + r] = v[1];
        Bs[(kk + c + 2) * LDA + r] = v[2];
        Bs[(kk + c + 3) * LDA + r] = v[3];
    }
}

__device__ __forceinline__ void mac64(const float* As, const float* Bs, int tr, int tc, f4 acc[4]) {
    #pragma unroll
    for (int kk = 0; kk < KC; ++kk) {
        f4 a = *(const f4*)&As[kk * LDA + tr * 4];
        f4 b = *(const f4*)&Bs[kk * LDA + tc * 4];
        acc[0] += a[0] * b;
        acc[1] += a[1] * b;
        acc[2] += a[2] * b;
        acc[3] += a[3] * b;
    }
}

// ---------------- gather concat into contiguous [240][216] ----------------
__global__ void gather_kernel(const float* __restrict__ src, const float* __restrict__ tgt,
                              float* __restrict__ cbuf) {
    int idx = blockIdx.x * 256 + threadIdx.x;
    if (idx >= TBF * TD) return;
    int d = idx % TD;
    int row = idx / TD;
    int b = row & 1, t = row >> 1;
    cbuf[idx] = (t < 60) ? src[((size_t)b * 60 + t) * TD + d]
                         : tgt[((size_t)b * 61 + (t - 60)) * TD + d];
}

// ---------------- embedding GEMM + bias + PE (fp32; writes fp32 + bf16) ------
__global__ __launch_bounds__(256) void gemm_embed_kernel(
        const float* __restrict__ cbuf, const float* __restrict__ Wemb,
        const float* __restrict__ bemb, float* __restrict__ x0,
        short* __restrict__ x0bf) {
    __shared__ __align__(16) float As[KC * LDA];
    __shared__ __align__(16) float Bs[KC * LDA];
    int tid = threadIdx.x;
    int m0 = blockIdx.x * 64;
    int n0 = blockIdx.y * 64;
    int mrem = TBF - m0; if (mrem > 64) mrem = 64;
    const float* A = cbuf + (size_t)m0 * TD;
    const float* Bw = Wemb + (size_t)n0 * TD;
    f4 acc[4] = {{0,0,0,0},{0,0,0,0},{0,0,0,0},{0,0,0,0}};
    for (int k0 = 0; k0 < TD; k0 += KC) {
        stageA(As, A, TD, mrem, TD, k0, tid);
        stageB64(Bs, Bw, TD, k0, tid);
        __syncthreads();
        mac64(As, Bs, tid >> 4, tid & 15, acc);
        __syncthreads();
    }
    int tr = tid >> 4, tc = tid & 15;
    int nb = n0 + tc * 4;
    f4 b4 = *(const f4*)&bemb[nb];
    #pragma unroll
    for (int i = 0; i < 4; ++i) {
        int row = tr * 4 + i;
        if (row < mrem) {
            int grow = m0 + row;
            int t = grow >> 1;
            f4 o = acc[i] + b4;
            #pragma unroll
            for (int u = 0; u < 4; ++u) {
                int n = nb + u;
                float freq = expf((float)(n & ~1) * (-9.2103403719761836f / 3072.0f));
                float ang = (float)t * freq;
                o[u] += (n & 1) ? cosf(ang) : sinf(ang);
            }
            *(f4*)&x0[(size_t)grow * TEMB + nb] = o;
            s4 ob = { f2bf(o[0]), f2bf(o[1]), f2bf(o[2]), f2bf(o[3]) };
            *(s4*)&x0bf[(size_t)grow * TEMB + nb] = ob;
        }
    }
}

// ---------------- baseline causal temporal attention (query-chunked) --------
__global__ __launch_bounds__(512) void attn_causal2_kernel(
        const float* __restrict__ Q, const float* __restrict__ K,
        const float* __restrict__ V, short* __restrict__ O) {
    __shared__ float Qs[QCH][APAD], Ks[TW][APAD], Vs[TW][APAD];
    __shared__ float Ps[8][TW];
    int blk = blockIdx.x;
    int head = blk & 7;
    int j = (blk >> 3) % TJ;
    int b = (blk >> 3) / TJ;
    int qlo = blockIdx.y * QCH, qhi = qlo + QCH;
    int tid = threadIdx.x;
    int sd = tid & 15, sr = tid >> 4;
    for (int r = sr; r < qhi; r += 32) {
        size_t off = (size_t)((r * TB + b) * TJ + j) * TH + head * THD + sd;
        Ks[r][sd] = K[off]; Vs[r][sd] = V[off];
        if (r >= qlo) Qs[r - qlo][sd] = Q[off];
    }
    __syncthreads();
    int wave = tid >> 6, lane = tid & 63;
    int dd = lane & 15, c = lane >> 4;
    for (int q = qlo + wave; q < qhi; q += 8) {
        int k0 = lane, k1 = lane + 64;
        float s0 = -1e30f, s1 = -1e30f;
        if (k0 <= q) {
            float a = 0.f;
            #pragma unroll
            for (int u = 0; u < THD; ++u) a += Qs[q - qlo][u] * Ks[k0][u];
            s0 = a * 0.25f;
        }
        if (k1 <= q) {
            float a = 0.f;
            #pragma unroll
            for (int u = 0; u < THD; ++u) a += Qs[q - qlo][u] * Ks[k1][u];
            s1 = a * 0.25f;
        }
        float m = fmaxf(s0, s1);
        #pragma unroll
        for (int o = 32; o > 0; o >>= 1) m = fmaxf(m, __shfl_xor(m, o));
        float p0 = (k0 <= q) ? __expf(s0 - m) : 0.f;
        float p1 = (k1 <= q) ? __expf(s1 - m) : 0.f;
        float sum = p0 + p1;
        #pragma unroll
        for (int o = 32; o > 0; o >>= 1) sum += __shfl_xor(sum, o);
        float inv = 1.0f / sum;
        Ps[wave][k0] = p0;
        if (k1 < TW) Ps[wave][k1] = p1;
        float acc = 0.f;
        for (int k = c; k <= q; k += 4) acc += Ps[wave][k] * Vs[k][dd];
        acc += __shfl_xor(acc, 16);
        acc += __shfl_xor(acc, 32);
        if (lane < 16)
            O[(size_t)((q * TB + b) * TJ + j) * TH + head * THD + dd] = f2bf(acc * inv);
    }
}

// ---------------- special-row temporal attention (query-chunked) ------------
__global__ __launch_bounds__(512) void attn_special2_kernel(
        const float* __restrict__ Qsp_g, const float* __restrict__ Ksp_g,
        const float* __restrict__ Vsp_g, const float* __restrict__ Kb_g,
        const float* __restrict__ Vb_g, short* __restrict__ O) {
    __shared__ float Qsp[QCH][APAD], Ksp[QCH][APAD], Vsp[QCH][APAD];
    __shared__ float Kb[TW][APAD], Vb[TW][APAD];
    __shared__ float Ps[8][TW];
    int blk = blockIdx.x;
    int head = blk & 7;
    int j = (blk >> 3) % TJ;
    int b = (blk >> 3) / TJ;
    int qlo = blockIdx.y * QCH, qhi = qlo + QCH;
    int tid = threadIdx.x;
    int sd = tid & 15, sr = tid >> 4;
    for (int r = sr; r < qhi; r += 32) {
        size_t off = (size_t)((r * TB + b) * TJ + j) * TH + head * THD + sd;
        Kb[r][sd] = Kb_g[off]; Vb[r][sd] = Vb_g[off];
        if (r >= qlo) {
            Qsp[r - qlo][sd] = Qsp_g[off];
            Ksp[r - qlo][sd] = Ksp_g[off];
            Vsp[r - qlo][sd] = Vsp_g[off];
        }
    }
    __syncthreads();
    int wave = tid >> 6, lane = tid & 63;
    int dd = lane & 15, c = lane >> 4;
    for (int t = qlo + wave; t < qhi; t += 8) {
        int k0 = lane, k1 = lane + 64;
        float s0 = -1e30f, s1 = -1e30f;
        if (k0 <= t) {
            const float* krow = (k0 == t) ? Ksp[t - qlo] : Kb[k0];
            float a = 0.f;
            #pragma unroll
            for (int u = 0; u < THD; ++u) a += Qsp[t - qlo][u] * krow[u];
            s0 = a * 0.25f;
        }
        if (k1 <= t) {
            const float* krow = (k1 == t) ? Ksp[t - qlo] : Kb[k1];
            float a = 0.f;
            #pragma unroll
            for (int u = 0; u < THD; ++u) a += Qsp[t - qlo][u] * krow[u];
            s1 = a * 0.25f;
        }
        float m = fmaxf(s0, s1);
        #pragma unroll
        for (int o = 32; o > 0; o >>= 1) m = fmaxf(m, __shfl_xor(m, o));
        float p0 = (k0 <= t) ? __expf(s0 - m) : 0.f;
        float p1 = (k1 <= t) ? __expf(s1 - m) : 0.f;
        float sum = p0 + p1;
        #pragma unroll
        for (int o = 32; o > 0; o >>= 1) sum += __shfl_xor(sum, o);
        float inv = 1.0f / sum;
        Ps[wave][k0] = p0;
        if (k1 < TW) Ps[wave][k1] = p1;
        float acc = 0.f;
        for (int k = c; k < t; k += 4) acc += Ps[wave][k] * Vb[k][dd];
        if ((t & 3) == c) acc += Ps[wave][t] * Vsp[t - qlo][dd];
        acc += __shfl_xor(acc, 16);
        acc += __shfl_xor(acc, 32);
        if (lane < 16)
            O[(size_t)((t * TB + b) * TJ + j) * TH + head * THD + dd] = f2bf(acc * inv);
    }
}

// ---------------- spatial attention over joints (batched per frame) ----------
#define SPAD (TH + 4)
__global__ __launch_bounds__(192) void attn_spatial2_kernel(
        const float* __restrict__ Q, const float* __restrict__ K,
        const float* __restrict__ V, short* __restrict__ O) {
    __shared__ __align__(16) float Qs[TJ][SPAD], Ks[TJ][SPAD], Vs[TJ][SPAD];
    int blk = blockIdx.x;
    int b = blk & 1, t = blk >> 1;
    int base = (t * TB + b) * TJ;
    int tid = threadIdx.x;
    for (int i = tid; i < TJ * 32; i += 192) {
        int r = i >> 5, c4 = i & 31;
        ((f4*)&Qs[r][0])[c4] = ((const f4*)(Q + (size_t)(base + r) * TH))[c4];
        ((f4*)&Ks[r][0])[c4] = ((const f4*)(K + (size_t)(base + r) * TH))[c4];
        ((f4*)&Vs[r][0])[c4] = ((const f4*)(V + (size_t)(base + r) * TH))[c4];
    }
    __syncthreads();
    int qj = tid % TJ;
    int head = tid / TJ;
    int hb = head * THD;
    float qv[THD];
    #pragma unroll
    for (int u = 0; u < THD; ++u) qv[u] = Qs[qj][hb + u];
    float sc[TJ];
    float m = -1e30f;
    #pragma unroll
    for (int k = 0; k < TJ; ++k) {
        float a = 0.f;
        #pragma unroll
        for (int u = 0; u < THD; ++u) a += qv[u] * Ks[k][hb + u];
        sc[k] = a * 0.25f;
        m = fmaxf(m, sc[k]);
    }
    float sum = 0.f;
    #pragma unroll
    for (int k = 0; k < TJ; ++k) { sc[k] = __expf(sc[k] - m); sum += sc[k]; }
    float inv = 1.0f / sum;
    float o[THD];
    #pragma unroll
    for (int u = 0; u < THD; ++u) o[u] = 0.f;
    #pragma unroll
    for (int k = 0; k < TJ; ++k) {
        #pragma unroll
        for (int u = 0; u < THD; ++u) o[u] += sc[k] * Vs[k][hb + u];
    }
    size_t off = (size_t)(base + qj) * TH + hb;
    #pragma unroll
    for (int u = 0; u < THD; ++u) O[off + u] = f2bf(o[u] * inv);
}

// ---------------- final projection + residual ----------------
__global__ void final_kernel(const float* __restrict__ r4, const float* __restrict__ Wout,
                             const float* __restrict__ bout, const float* __restrict__ src,
                             const float* __restrict__ tgt, float* __restrict__ out) {
    int idx = blockIdx.x * 256 + threadIdx.x;
    if (idx >= TB * TW * TD) return;
    int d = idx % TD;
    int t = (idx / TD) % TW;
    int b = idx / (TD * TW);
    int j = d / 9, o = d % 9;
    const float* rr = r4 + (size_t)((t * TB + b) * TJ + j) * TH;
    const float* wt = Wout + (size_t)o * TH;
    float acc = bout[o];
    #pragma unroll 4
    for (int h = 0; h < TH; ++h) acc += rr[h] * wt[h];
    float cv = (t < 60) ? src[((size_t)b * 60 + t) * TD + d]
                        : tgt[((size_t)b * 61 + (t - 60)) * TD + d];
    out[idx] = acc + cv;
}

extern "C" void kernel_launch(void* const* d_in, const int* in_sizes, int n_in,
                              void* d_out, int out_size, void* d_ws, size_t ws_size,
                              hipStream_t stream) {
    const float* src    = (const float*)d_in[0];
    const float* tgt    = (const float*)d_in[1];
    const float* Wemb   = (const float*)d_in[2];
    const float* bemb   = (const float*)d_in[3];
    const float* Wqkv_s = (const float*)d_in[4];
    const float* bqkv_s = (const float*)d_in[5];
    const float* Wo_s   = (const float*)d_in[6];
    const float* bo_s   = (const float*)d_in[7];
    const float* sn_g   = (const float*)d_in[8];
    const float* sn_b   = (const float*)d_in[9];
    const float* Wqkv_t = (const float*)d_in[10];
    const float* bqkv_t = (const float*)d_in[11];
    const float* Wo_t   = (const float*)d_in[12];
    const float* bo_t   = (const float*)d_in[13];
    const float* tn_g   = (const float*)d_in[14];
    const float* tn_b   = (const float*)d_in[15];
    const float* W1     = (const float*)d_in[16];
    const float* b1     = (const float*)d_in[17];
    const float* W2     = (const float*)d_in[18];
    const float* b2     = (const float*)d_in[19];
    const float* Wout   = (const float*)d_in[20];
    const float* bout   = (const float*)d_in[21];
    float* out = (float*)d_out;

    const size_t RH = (size_t)TROWS * TH;   // 737280
    float* f = (float*)d_ws;
    float* cbuf  = f;                    // 51840
    float* x0    = cbuf + 51840;
    float* Kbase = x0 + RH;              // 4*RH
    float* Vbase = Kbase + 4 * RH;       // 4*RH
    float* r     = Vbase + 4 * RH;
    float* Qb    = r + RH;
    float* Kb    = Qb + RH;
    float* Vb    = Kb + RH;
    float* spout = Vb + RH;
    float* Bb0   = spout + RH;
    float* Bb1   = Bb0 + RH;
    short* sbase = (short*)(Bb1 + RH);
    short* x0bf  = sbase;
    short* rbf   = x0bf + RH;
    short* attnb = rbf + RH;
    short* ybbf  = attnb + RH;
    short* fbufb = ybbf + RH;            // TROWS*TF
    short* Bb0bf = fbufb + (size_t)TROWS * TF;
    short* Bb1bf = Bb0bf + RH;
    short* wbf   = Bb1bf + RH;           // NW_TOT shorts

    const short* wqkvs_bf = wbf;
    const short* wos_bf   = wbf + OFF_O_S;
    const short* wqkvt_bf = wbf + OFF_QKV_T;
    const short* wot_bf   = wbf + OFF_O_T;
    const short* w1bf     = wbf + OFF_W1;
    const short* w2bf     = wbf + OFF_W2;

    // 0. weights -> bf16 (scratch is volatile; redo every call)
    convert_weights_kernel<<<(NW_TOT / 4 + 255) / 256, 256, 0, stream>>>(
        Wqkv_s, Wo_s, Wqkv_t, Wo_t, W1, W2, wbf);

    // 1. gather concat, then embedding GEMM (+PE), dual-write
    gather_kernel<<<(TBF * TD + 255) / 256, 256, 0, stream>>>(src, tgt, cbuf);
    gemm_embed_kernel<<<dim3(4, 48), 256, 0, stream>>>(cbuf, Wemb, bemb, x0, x0bf);

    // 2. baseline pass (temporal-only stack); save per-layer K/V projections
    const float* Binf = x0;
    const short* Binbf = x0bf;
    for (int l = 0; l < 4; ++l) {
        mfma_qkv_kernel<<<dim3(4, 6, 24), 256, 0, stream>>>(
            Binbf, wqkvt_bf + (size_t)l * TJ * 3 * TH * TH, bqkv_t + (size_t)l * TJ * 3 * TH,
            Qb, Kbase + l * RH, Vbase + l * RH, 1);
        if (l < 3) {
            attn_causal2_kernel<<<dim3(TB * TJ * TNH, 2), 512, 0, stream>>>(
                Qb, Kbase + l * RH, Vbase + l * RH, attnb);
            mfma_oln_kernel<<<dim3(15, 1, 24), 256, 0, stream>>>(
                attnb, wot_bf + (size_t)l * TJ * TH * TH, bo_t + (size_t)l * TJ * TH,
                Binf, tn_g + l * TH, tn_b + l * TH, nullptr, nullptr, ybbf, 1);
            mfma_ffn1_kernel<<<dim3(90, 4), 256, 0, stream>>>(
                ybbf, w1bf + (size_t)l * TF * TH, b1 + l * TF, fbufb);
            float* Boutf = (l & 1) ? Bb1 : Bb0;
            short* Boutbf = (l & 1) ? Bb1bf : Bb0bf;
            mfma_ffn2_kernel<<<dim3(90, 2), 256, 0, stream>>>(
                fbufb, w2bf + (size_t)l * TH * TF, b2 + l * TH, Boutf, Boutbf);
            Binf = Boutf; Binbf = Boutbf;
        }
    }

    // 3. per-t special-row chains (all 120 t in parallel)
    hipMemcpyAsync(r, x0, RH * sizeof(float), hipMemcpyDeviceToDevice, stream);
    hipMemcpyAsync(rbf, x0bf, RH * sizeof(short), hipMemcpyDeviceToDevice, stream);
    for (int l = 0; l < 4; ++l) {
        mfma_qkv_kernel<<<dim3(4, 6, 24), 256, 0, stream>>>(
            rbf, wqkvs_bf + (size_t)l * 3 * TH * TH, bqkv_s + (size_t)l * 3 * TH,
            Qb, Kb, Vb, 0);
        attn_spatial2_kernel<<<TW * TB, 192, 0, stream>>>(Qb, Kb, Vb, attnb);
        mfma_oln_kernel<<<dim3(15, 1, 24), 256, 0, stream>>>(
            attnb, wos_bf + (size_t)l * TH * TH, bo_s + (size_t)l * TH,
            r, sn_g + l * TH, sn_b + l * TH, nullptr, spout, nullptr, 0);
        mfma_qkv_kernel<<<dim3(4, 6, 24), 256, 0, stream>>>(
            rbf, wqkvt_bf + (size_t)l * TJ * 3 * TH * TH, bqkv_t + (size_t)l * TJ * 3 * TH,
            Qb, Kb, Vb, 1);
        attn_special2_kernel<<<dim3(TB * TJ * TNH, 2), 512, 0, stream>>>(
            Qb, Kb, Vb, Kbase + l * RH, Vbase + l * RH, attnb);
        mfma_oln_kernel<<<dim3(15, 1, 24), 256, 0, stream>>>(
            attnb, wot_bf + (size_t)l * TJ * TH * TH, bo_t + (size_t)l * TJ * TH,
            r, tn_g + l * TH, tn_b + l * TH, spout, nullptr, ybbf, 1);
        mfma_ffn1_kernel<<<dim3(90, 4), 256, 0, stream>>>(
            ybbf, w1bf + (size_t)l * TF * TH, b1 + l * TF, fbufb);
        mfma_ffn2_kernel<<<dim3(90, 2), 256, 0, stream>>>(
            fbufb, w2bf + (size_t)l * TH * TF, b2 + l * TH, r, rbf);
    }

    // 4. output projection + residual
    final_kernel<<<(TB * TW * TD + 255) / 256, 256, 0, stream>>>(r, Wout, bout, src, tgt, out);
}

// Round 9
// 451.433 us; speedup vs baseline: 14.4284x; 1.1402x over previous
//
#include <hip/hip_runtime.h>

// Sizes
#define TW 120     // window / number of parallel t-steps
#define TB 2       // batch
#define TJ 24      // joints
#define TH 128     // hidden
#define TNH 8      // heads
#define THD 16     // head dim
#define TF 256     // ffn
#define TD 216     // input dim
#define TROWS (TW*TB*TJ)   // 5760 rows of H
#define TEMB (TJ*TH)       // 3072
#define TBF 240            // t*b frames

#define KC 32
#define LDA 68     // fp32 GEMM LDS stride (64+4)
#define APAD 20    // attention LDS row pad: 16B-aligned rows, ~2-way bank aliasing (free)
#define QCH 60     // query chunk per attention block
#define LDT 136    // bf16 MFMA tile LDS row stride in shorts (128+8)

typedef float f4 __attribute__((ext_vector_type(4)));
typedef short bf8 __attribute__((ext_vector_type(8)));   // 8 bf16 = 4 VGPR
typedef short s4 __attribute__((ext_vector_type(4)));

__device__ __forceinline__ short f2bf(float x) {
    union { float f; unsigned u; } v; v.f = x;
    unsigned r = (v.u + 0x7FFFu + ((v.u >> 16) & 1u)) >> 16;
    return (short)r;
}

// ---------------- weight fp32->bf16 conversion (every call; ws is scratch) ----
#define NW_QKV_S 196608
#define NW_O_S    65536
#define NW_QKV_T 4718592
#define NW_O_T   1572864
#define NW_1      131072
#define NW_2      131072
#define OFF_O_S   (NW_QKV_S)
#define OFF_QKV_T (OFF_O_S + NW_O_S)
#define OFF_O_T   (OFF_QKV_T + NW_QKV_T)
#define OFF_W1    (OFF_O_T + NW_O_T)
#define OFF_W2    (OFF_W1 + NW_1)
#define NW_TOT    (OFF_W2 + NW_2)      // 6815744

__global__ void convert_weights_kernel(const float* __restrict__ Wqkv_s, const float* __restrict__ Wo_s,
                                       const float* __restrict__ Wqkv_t, const float* __restrict__ Wo_t,
                                       const float* __restrict__ W1, const float* __restrict__ W2,
                                       short* __restrict__ dst) {
    size_t i = ((size_t)blockIdx.x * 256 + threadIdx.x) * 4;
    if (i >= NW_TOT) return;
    const float* src; size_t off;
    if (i < NW_QKV_S)       { src = Wqkv_s; off = i; }
    else if (i < OFF_QKV_T) { src = Wo_s;   off = i - OFF_O_S; }
    else if (i < OFF_O_T)   { src = Wqkv_t; off = i - OFF_QKV_T; }
    else if (i < OFF_W1)    { src = Wo_t;   off = i - OFF_O_T; }
    else if (i < OFF_W2)    { src = W1;     off = i - OFF_W1; }
    else                    { src = W2;     off = i - OFF_W2; }
    f4 v = *(const f4*)(src + off);
    s4 o = { f2bf(v[0]), f2bf(v[1]), f2bf(v[2]), f2bf(v[3]) };
    *(s4*)(dst + i) = o;
}

// ---------------- MFMA building blocks ----------------
__device__ __forceinline__ void stage_bf(short* Ds, const short* __restrict__ src,
                                         size_t rstride, int nrows, int tid) {
    int r = tid >> 2, s = (tid & 3) * 32;
    short* d = Ds + r * LDT + s;
    if (r < nrows) {
        const short* p = src + (size_t)r * rstride + s;
        *(bf8*)(d)      = *(const bf8*)(p);
        *(bf8*)(d + 8)  = *(const bf8*)(p + 8);
        *(bf8*)(d + 16) = *(const bf8*)(p + 16);
        *(bf8*)(d + 24) = *(const bf8*)(p + 24);
    } else {
        bf8 z = {0,0,0,0,0,0,0,0};
        *(bf8*)(d) = z; *(bf8*)(d+8) = z; *(bf8*)(d+16) = z; *(bf8*)(d+24) = z;
    }
}

__device__ __forceinline__ void mfma_tile64(const short* As, const short* Bs,
                                            int wave, int lane, f4 acc[2][2]) {
    int wm = wave >> 1, wn = wave & 1;
    int lrow = lane & 15, lk = (lane >> 4) * 8;
    #pragma unroll
    for (int ks = 0; ks < 4; ++ks) {
        bf8 a0 = *(const bf8*)&As[(wm*32      + lrow) * LDT + ks*32 + lk];
        bf8 a1 = *(const bf8*)&As[(wm*32 + 16 + lrow) * LDT + ks*32 + lk];
        bf8 b0 = *(const bf8*)&Bs[(wn*32      + lrow) * LDT + ks*32 + lk];
        bf8 b1 = *(const bf8*)&Bs[(wn*32 + 16 + lrow) * LDT + ks*32 + lk];
        acc[0][0] = __builtin_amdgcn_mfma_f32_16x16x32_bf16(a0, b0, acc[0][0], 0, 0, 0);
        acc[0][1] = __builtin_amdgcn_mfma_f32_16x16x32_bf16(a0, b1, acc[0][1], 0, 0, 0);
        acc[1][0] = __builtin_amdgcn_mfma_f32_16x16x32_bf16(a1, b0, acc[1][0], 0, 0, 0);
        acc[1][1] = __builtin_amdgcn_mfma_f32_16x16x32_bf16(a1, b1, acc[1][1], 0, 0, 0);
    }
}

// ---------------- QKV MFMA GEMM (part 2; per-joint weights; n0base skips Q) ---
__global__ __launch_bounds__(256) void mfma_qkv_kernel(
        const short* __restrict__ Abf, const short* __restrict__ Wbf,
        const float* __restrict__ bias, float* __restrict__ Q,
        float* __restrict__ Kd, float* __restrict__ V, int n0base) {
    __shared__ short As[64 * LDT], Bs[64 * LDT];
    int tid = threadIdx.x;
    int m0 = blockIdx.x * 64, n0 = n0base + blockIdx.y * 64, j = blockIdx.z;
    int mrem = TBF - m0; if (mrem > 64) mrem = 64;
    stage_bf(As, Abf + (size_t)m0 * TEMB + j * TH, TEMB, mrem, tid);
    stage_bf(Bs, Wbf + (size_t)j * 3 * TH * TH + (size_t)n0 * TH, TH, 64, tid);
    __syncthreads();
    int wave = tid >> 6, lane = tid & 63;
    f4 acc[2][2] = {{{0,0,0,0},{0,0,0,0}},{{0,0,0,0},{0,0,0,0}}};
    mfma_tile64(As, Bs, wave, lane, acc);
    int wm = wave >> 1, wn = wave & 1, lrow = lane & 15, gr = (lane >> 4) * 4;
    float* dst = (n0 < TH) ? Q : ((n0 < 2 * TH) ? Kd : V);
    int cb = n0 & (TH - 1);
    #pragma unroll
    for (int ni = 0; ni < 2; ++ni) {
        float bv = bias[j * 3 * TH + n0 + wn*32 + ni*16 + lrow];
        int col = cb + wn*32 + ni*16 + lrow;
        #pragma unroll
        for (int mi = 0; mi < 2; ++mi)
            #pragma unroll
            for (int rg = 0; rg < 4; ++rg) {
                int tr = wm*32 + mi*16 + gr + rg;
                if (tr < mrem)
                    dst[(size_t)((m0 + tr) * TJ + j) * TH + col] = acc[mi][ni][rg] + bv;
            }
    }
}

// ---------------- combined spatial+temporal QKV (part 3) ----------------
// grid (4, 12, 24): y<6 -> shared weights -> Qs/Ks/Vs; y>=6 -> per-joint -> Qt/Kt/Vt
__global__ __launch_bounds__(256) void mfma_qkv2_kernel(
        const short* __restrict__ Abf, const short* __restrict__ Ws,
        const short* __restrict__ Wt, const float* __restrict__ bs,
        const float* __restrict__ bt,
        float* __restrict__ Qs_, float* __restrict__ Ks_, float* __restrict__ Vs_,
        float* __restrict__ Qt_, float* __restrict__ Kt_, float* __restrict__ Vt_) {
    __shared__ short As[64 * LDT], Bs[64 * LDT];
    int tid = threadIdx.x;
    int m0 = blockIdx.x * 64, j = blockIdx.z;
    int yy = blockIdx.y;
    int temporal = (yy >= 6);
    int n0 = (temporal ? (yy - 6) : yy) * 64;
    int mrem = TBF - m0; if (mrem > 64) mrem = 64;
    const short* Wbf = temporal ? (Wt + (size_t)j * 3 * TH * TH + (size_t)n0 * TH)
                                : (Ws + (size_t)n0 * TH);
    const float* bias = temporal ? (bt + j * 3 * TH) : bs;
    stage_bf(As, Abf + (size_t)m0 * TEMB + j * TH, TEMB, mrem, tid);
    stage_bf(Bs, Wbf, TH, 64, tid);
    __syncthreads();
    int wave = tid >> 6, lane = tid & 63;
    f4 acc[2][2] = {{{0,0,0,0},{0,0,0,0}},{{0,0,0,0},{0,0,0,0}}};
    mfma_tile64(As, Bs, wave, lane, acc);
    int wm = wave >> 1, wn = wave & 1, lrow = lane & 15, gr = (lane >> 4) * 4;
    float* dst = temporal ? ((n0 < TH) ? Qt_ : ((n0 < 2*TH) ? Kt_ : Vt_))
                          : ((n0 < TH) ? Qs_ : ((n0 < 2*TH) ? Ks_ : Vs_));
    int cb = n0 & (TH - 1);
    #pragma unroll
    for (int ni = 0; ni < 2; ++ni) {
        float bv = bias[n0 + wn*32 + ni*16 + lrow];
        int col = cb + wn*32 + ni*16 + lrow;
        #pragma unroll
        for (int mi = 0; mi < 2; ++mi)
            #pragma unroll
            for (int rg = 0; rg < 4; ++rg) {
                int tr = wm*32 + mi*16 + gr + rg;
                if (tr < mrem)
                    dst[(size_t)((m0 + tr) * TJ + j) * TH + col] = acc[mi][ni][rg] + bv;
            }
    }
}

// ---------------- out-proj MFMA + residual + LayerNorm (+ add) ----------------
__global__ __launch_bounds__(256) void mfma_oln_kernel(
        const short* __restrict__ Abf, const short* __restrict__ Wbf,
        const float* __restrict__ bias, const float* __restrict__ resid,
        const float* __restrict__ g, const float* __restrict__ bln,
        const float* __restrict__ addv, float* __restrict__ Yf,
        short* __restrict__ Ybf, int perJoint) {
    __shared__ short As[16 * LDT];
    __shared__ short Bs[128 * LDT];
    __shared__ float rsum[4][16], rsq[4][16], lnm[16], lnr[16];
    int tid = threadIdx.x;
    int m0 = blockIdx.x * 16, j = blockIdx.z;
    { int r = tid >> 4, s = (tid & 15) * 8;
      *(bf8*)&As[r * LDT + s] = *(const bf8*)(Abf + (size_t)(m0 + r) * TEMB + j * TH + s); }
    { int r = tid >> 1, s = (tid & 1) * 64;
      const short* p = Wbf + (perJoint ? (size_t)j * TH * TH : 0) + (size_t)r * TH + s;
      short* d = &Bs[r * LDT + s];
      #pragma unroll
      for (int c = 0; c < 64; c += 8) *(bf8*)(d + c) = *(const bf8*)(p + c); }
    __syncthreads();
    int wave = tid >> 6, lane = tid & 63, lrow = lane & 15, lk = (lane >> 4) * 8, gr = (lane >> 4) * 4;
    f4 acc[2] = {{0,0,0,0},{0,0,0,0}};
    #pragma unroll
    for (int ks = 0; ks < 4; ++ks) {
        bf8 a  = *(const bf8*)&As[lrow * LDT + ks*32 + lk];
        bf8 b0 = *(const bf8*)&Bs[(wave*32      + lrow) * LDT + ks*32 + lk];
        bf8 b1 = *(const bf8*)&Bs[(wave*32 + 16 + lrow) * LDT + ks*32 + lk];
        acc[0] = __builtin_amdgcn_mfma_f32_16x16x32_bf16(a, b0, acc[0], 0, 0, 0);
        acc[1] = __builtin_amdgcn_mfma_f32_16x16x32_bf16(a, b1, acc[1], 0, 0, 0);
    }
    int col0 = wave*32 + lrow, col1 = col0 + 16;
    int bofs = perJoint ? j * TH : 0;
    float bv0 = bias[bofs + col0], bv1 = bias[bofs + col1];
    float v0[4], v1[4], sr[4], sq[4];
    #pragma unroll
    for (int rg = 0; rg < 4; ++rg) {
        size_t ro = (size_t)(m0 + gr + rg) * TEMB + j * TH;
        v0[rg] = acc[0][rg] + bv0 + resid[ro + col0];
        v1[rg] = acc[1][rg] + bv1 + resid[ro + col1];
        sr[rg] = v0[rg] + v1[rg];
        sq[rg] = v0[rg]*v0[rg] + v1[rg]*v1[rg];
    }
    #pragma unroll
    for (int o = 1; o < 16; o <<= 1) {
        #pragma unroll
        for (int rg = 0; rg < 4; ++rg) { sr[rg] += __shfl_xor(sr[rg], o); sq[rg] += __shfl_xor(sq[rg], o); }
    }
    if (lrow == 0) {
        #pragma unroll
        for (int rg = 0; rg < 4; ++rg) { rsum[wave][gr + rg] = sr[rg]; rsq[wave][gr + rg] = sq[rg]; }
    }
    __syncthreads();
    if (tid < 16) {
        float s = rsum[0][tid] + rsum[1][tid] + rsum[2][tid] + rsum[3][tid];
        float q = rsq[0][tid] + rsq[1][tid] + rsq[2][tid] + rsq[3][tid];
        float mean = s * (1.0f / TH);
        float var = q * (1.0f / TH) - mean * mean;
        lnm[tid] = mean; lnr[tid] = rsqrtf(var + 1e-5f);
    }
    __syncthreads();
    float g0 = g[col0], g1 = g[col1], l0 = bln[col0], l1 = bln[col1];
    #pragma unroll
    for (int rg = 0; rg < 4; ++rg) {
        int row = gr + rg;
        float mean = lnm[row], rs = lnr[row];
        size_t ro = (size_t)(m0 + row) * TEMB + j * TH;
        float o0 = (v0[rg] - mean) * rs * g0 + l0;
        float o1 = (v1[rg] - mean) * rs * g1 + l1;
        if (addv) { o0 += addv[ro + col0]; o1 += addv[ro + col1]; }
        if (Yf)  { Yf[ro + col0] = o0; Yf[ro + col1] = o1; }
        if (Ybf) { Ybf[ro + col0] = f2bf(o0); Ybf[ro + col1] = f2bf(o1); }
    }
}

// ---------------- FFN MFMA GEMMs ----------------
__global__ __launch_bounds__(256) void mfma_ffn1_kernel(
        const short* __restrict__ Ybf, const short* __restrict__ W1bf,
        const float* __restrict__ b1, short* __restrict__ Fb) {
    __shared__ short As[64 * LDT], Bs[64 * LDT];
    int tid = threadIdx.x;
    int m0 = blockIdx.x * 64, n0 = blockIdx.y * 64;
    stage_bf(As, Ybf + (size_t)m0 * TH, TH, 64, tid);
    stage_bf(Bs, W1bf + (size_t)n0 * TH, TH, 64, tid);
    __syncthreads();
    int wave = tid >> 6, lane = tid & 63;
    f4 acc[2][2] = {{{0,0,0,0},{0,0,0,0}},{{0,0,0,0},{0,0,0,0}}};
    mfma_tile64(As, Bs, wave, lane, acc);
    int wm = wave >> 1, wn = wave & 1, lrow = lane & 15, gr = (lane >> 4) * 4;
    #pragma unroll
    for (int ni = 0; ni < 2; ++ni) {
        int col = n0 + wn*32 + ni*16 + lrow;
        float bv = b1[col];
        #pragma unroll
        for (int mi = 0; mi < 2; ++mi)
            #pragma unroll
            for (int rg = 0; rg < 4; ++rg) {
                int tr = wm*32 + mi*16 + gr + rg;
                float v = 2.0f * fmaxf(acc[mi][ni][rg] + bv, 0.0f);
                Fb[(size_t)(m0 + tr) * TF + col] = f2bf(v);
            }
    }
}

__global__ __launch_bounds__(256) void mfma_ffn2_kernel(
        const short* __restrict__ Fb, const short* __restrict__ W2bf,
        const float* __restrict__ b2, float* __restrict__ Outf,
        short* __restrict__ Outbf) {
    __shared__ short As[64 * LDT], Bs[64 * LDT];
    int tid = threadIdx.x;
    int m0 = blockIdx.x * 64, n0 = blockIdx.y * 64;
    int wave = tid >> 6, lane = tid & 63;
    f4 acc[2][2] = {{{0,0,0,0},{0,0,0,0}},{{0,0,0,0},{0,0,0,0}}};
    #pragma unroll
    for (int kk = 0; kk < 2; ++kk) {
        stage_bf(As, Fb + (size_t)m0 * TF + kk * 128, TF, 64, tid);
        stage_bf(Bs, W2bf + (size_t)n0 * TF + kk * 128, TF, 64, tid);
        __syncthreads();
        mfma_tile64(As, Bs, wave, lane, acc);
        __syncthreads();
    }
    int wm = wave >> 1, wn = wave & 1, lrow = lane & 15, gr = (lane >> 4) * 4;
    #pragma unroll
    for (int ni = 0; ni < 2; ++ni) {
        int col = n0 + wn*32 + ni*16 + lrow;
        float bv = b2[col];
        #pragma unroll
        for (int mi = 0; mi < 2; ++mi)
            #pragma unroll
            for (int rg = 0; rg < 4; ++rg) {
                int tr = wm*32 + mi*16 + gr + rg;
                float v = acc[mi][ni][rg] + bv;
                size_t off = (size_t)(m0 + tr) * TH + col;
                Outf[off] = v;
                Outbf[off] = f2bf(v);
            }
    }
}

// ---------- fp32 GEMM helpers (embed only) ----------
__device__ __forceinline__ void stageA(float* As, const float* __restrict__ A,
                                       int a_stride, int mrem, int K, int k0, int tid) {
    int r = tid >> 2;
    int kk = (tid & 3) << 3;
    bool rowok = r < mrem;
    const float* ap = A + (size_t)r * a_stride + k0 + kk;
    #pragma unroll
    for (int c = 0; c < 8; c += 4) {
        f4 v = {0.f, 0.f, 0.f, 0.f};
        int kg = k0 + kk + c;
        if (rowok) {
            if (kg + 4 <= K) v = *(const f4*)(ap + c);
            else {
                #pragma unroll
                for (int u = 0; u < 4; ++u) if (kg + u < K) v[u] = ap[c + u];
            }
        }
        As[(kk + c + 0) * LDA + r] = v[0];
        As[(kk + c + 1) * LDA + r] = v[1];
        As[(kk + c + 2) * LDA + r] = v[2];
        As[(kk + c + 3) * LDA + r] = v[3];
    }
}

__device__ __forceinline__ void stageB64(float* Bs, const float* __restrict__ Bw,
                                         int K, int k0, int tid) {
    int r = tid >> 2;
    int kk = (tid & 3) << 3;
    const float* bp = Bw + (size_t)r * K + k0 + kk;
    #pragma unroll
    for (int c = 0; c < 8; c += 4) {
        f4 v = {0.f, 0.f, 0.f, 0.f};
        int kg = k0 + kk + c;
        if (kg + 4 <= K) v = *(const f4*)(bp + c);
        else {
            #pragma unroll
            for (int u = 0; u < 4; ++u) if (kg + u < K) v[u] = bp[c + u];
        }
        Bs[(kk + c + 0) * LDA + r] = v[0];
        Bs[(kk + c + 1) * LDA + r] = v[1];
        Bs[(kk + c + 2) * LDA + r] = v[2];
        Bs[(kk + c + 3) * LDA + r] = v[3];
    }
}

__device__ __forceinline__ void mac64(const float* As, const float* Bs, int tr, int tc, f4 acc[4]) {
    #pragma unroll
    for (int kk = 0; kk < KC; ++kk) {
        f4 a = *(const f4*)&As[kk * LDA + tr * 4];
        f4 b = *(const f4*)&Bs[kk * LDA + tc * 4];
        acc[0] += a[0] * b;
        acc[1] += a[1] * b;
        acc[2] += a[2] * b;
        acc[3] += a[3] * b;
    }
}

// ---------------- gather concat into contiguous [240][216] ----------------
__global__ void gather_kernel(const float* __restrict__ src, const float* __restrict__ tgt,
                              float* __restrict__ cbuf) {
    int idx = blockIdx.x * 256 + threadIdx.x;
    if (idx >= TBF * TD) return;
    int d = idx % TD;
    int row = idx / TD;
    int b = row & 1, t = row >> 1;
    cbuf[idx] = (t < 60) ? src[((size_t)b * 60 + t) * TD + d]
                         : tgt[((size_t)b * 61 + (t - 60)) * TD + d];
}

// ---------------- embedding GEMM + bias + PE (writes x0, x0bf, r, rbf) -------
__global__ __launch_bounds__(256) void gemm_embed_kernel(
        const float* __restrict__ cbuf, const float* __restrict__ Wemb,
        const float* __restrict__ bemb, float* __restrict__ x0,
        short* __restrict__ x0bf, float* __restrict__ r0,
        short* __restrict__ r0bf) {
    __shared__ __align__(16) float As[KC * LDA];
    __shared__ __align__(16) float Bs[KC * LDA];
    int tid = threadIdx.x;
    int m0 = blockIdx.x * 64;
    int n0 = blockIdx.y * 64;
    int mrem = TBF - m0; if (mrem > 64) mrem = 64;
    const float* A = cbuf + (size_t)m0 * TD;
    const float* Bw = Wemb + (size_t)n0 * TD;
    f4 acc[4] = {{0,0,0,0},{0,0,0,0},{0,0,0,0},{0,0,0,0}};
    for (int k0 = 0; k0 < TD; k0 += KC) {
        stageA(As, A, TD, mrem, TD, k0, tid);
        stageB64(Bs, Bw, TD, k0, tid);
        __syncthreads();
        mac64(As, Bs, tid >> 4, tid & 15, acc);
        __syncthreads();
    }
    int tr = tid >> 4, tc = tid & 15;
    int nb = n0 + tc * 4;
    f4 b4 = *(const f4*)&bemb[nb];
    #pragma unroll
    for (int i = 0; i < 4; ++i) {
        int row = tr * 4 + i;
        if (row < mrem) {
            int grow = m0 + row;
            int t = grow >> 1;
            f4 o = acc[i] + b4;
            #pragma unroll
            for (int u = 0; u < 4; ++u) {
                int n = nb + u;
                float freq = expf((float)(n & ~1) * (-9.2103403719761836f / 3072.0f));
                float ang = (float)t * freq;
                o[u] += (n & 1) ? cosf(ang) : sinf(ang);
            }
            size_t off = (size_t)grow * TEMB + nb;
            *(f4*)&x0[off] = o;
            *(f4*)&r0[off] = o;
            s4 ob = { f2bf(o[0]), f2bf(o[1]), f2bf(o[2]), f2bf(o[3]) };
            *(s4*)&x0bf[off] = ob;
            *(s4*)&r0bf[off] = ob;
        }
    }
}

// ---------------- baseline causal temporal attention (query-chunked) --------
__global__ __launch_bounds__(512) void attn_causal2_kernel(
        const float* __restrict__ Q, const float* __restrict__ K,
        const float* __restrict__ V, short* __restrict__ O) {
    __shared__ float Qs[QCH][APAD], Ks[TW][APAD], Vs[TW][APAD];
    __shared__ float Ps[8][TW];
    int blk = blockIdx.x;
    int head = blk & 7;
    int j = (blk >> 3) % TJ;
    int b = (blk >> 3) / TJ;
    int qlo = blockIdx.y * QCH, qhi = qlo + QCH;
    int tid = threadIdx.x;
    int sd = tid & 15, sr = tid >> 4;
    for (int r = sr; r < qhi; r += 32) {
        size_t off = (size_t)((r * TB + b) * TJ + j) * TH + head * THD + sd;
        Ks[r][sd] = K[off]; Vs[r][sd] = V[off];
        if (r >= qlo) Qs[r - qlo][sd] = Q[off];
    }
    __syncthreads();
    int wave = tid >> 6, lane = tid & 63;
    int dd = lane & 15, c = lane >> 4;
    for (int q = qlo + wave; q < qhi; q += 8) {
        f4 qa = *(const f4*)&Qs[q - qlo][0];
        f4 qb = *(const f4*)&Qs[q - qlo][4];
        f4 qc = *(const f4*)&Qs[q - qlo][8];
        f4 qd = *(const f4*)&Qs[q - qlo][12];
        int k0 = lane, k1 = lane + 64;
        float s0 = -1e30f, s1 = -1e30f;
        if (k0 <= q) {
            f4 d = qa * *(const f4*)&Ks[k0][0] + qb * *(const f4*)&Ks[k0][4]
                 + qc * *(const f4*)&Ks[k0][8] + qd * *(const f4*)&Ks[k0][12];
            s0 = (d[0] + d[1] + d[2] + d[3]) * 0.25f;
        }
        if (k1 <= q) {
            f4 d = qa * *(const f4*)&Ks[k1][0] + qb * *(const f4*)&Ks[k1][4]
                 + qc * *(const f4*)&Ks[k1][8] + qd * *(const f4*)&Ks[k1][12];
            s1 = (d[0] + d[1] + d[2] + d[3]) * 0.25f;
        }
        float m = fmaxf(s0, s1);
        #pragma unroll
        for (int o = 32; o > 0; o >>= 1) m = fmaxf(m, __shfl_xor(m, o));
        float p0 = (k0 <= q) ? __expf(s0 - m) : 0.f;
        float p1 = (k1 <= q) ? __expf(s1 - m) : 0.f;
        float sum = p0 + p1;
        #pragma unroll
        for (int o = 32; o > 0; o >>= 1) sum += __shfl_xor(sum, o);
        float inv = 1.0f / sum;
        Ps[wave][k0] = p0;
        if (k1 < TW) Ps[wave][k1] = p1;
        float acc = 0.f;
        for (int k = c; k <= q; k += 4) acc += Ps[wave][k] * Vs[k][dd];
        acc += __shfl_xor(acc, 16);
        acc += __shfl_xor(acc, 32);
        if (lane < 16)
            O[(size_t)((q * TB + b) * TJ + j) * TH + head * THD + dd] = f2bf(acc * inv);
    }
}

// ---------------- special-row temporal attention (query-chunked) ------------
__global__ __launch_bounds__(512) void attn_special2_kernel(
        const float* __restrict__ Qsp_g, const float* __restrict__ Ksp_g,
        const float* __restrict__ Vsp_g, const float* __restrict__ Kb_g,
        const float* __restrict__ Vb_g, short* __restrict__ O) {
    __shared__ float Qsp[QCH][APAD], Ksp[QCH][APAD], Vsp[QCH][APAD];
    __shared__ float Kb[TW][APAD], Vb[TW][APAD];
    __shared__ float Ps[8][TW];
    int blk = blockIdx.x;
    int head = blk & 7;
    int j = (blk >> 3) % TJ;
    int b = (blk >> 3) / TJ;
    int qlo = blockIdx.y * QCH, qhi = qlo + QCH;
    int tid = threadIdx.x;
    int sd = tid & 15, sr = tid >> 4;
    for (int r = sr; r < qhi; r += 32) {
        size_t off = (size_t)((r * TB + b) * TJ + j) * TH + head * THD + sd;
        Kb[r][sd] = Kb_g[off]; Vb[r][sd] = Vb_g[off];
        if (r >= qlo) {
            Qsp[r - qlo][sd] = Qsp_g[off];
            Ksp[r - qlo][sd] = Ksp_g[off];
            Vsp[r - qlo][sd] = Vsp_g[off];
        }
    }
    __syncthreads();
    int wave = tid >> 6, lane = tid & 63;
    int dd = lane & 15, c = lane >> 4;
    for (int t = qlo + wave; t < qhi; t += 8) {
        f4 qa = *(const f4*)&Qsp[t - qlo][0];
        f4 qb = *(const f4*)&Qsp[t - qlo][4];
        f4 qc = *(const f4*)&Qsp[t - qlo][8];
        f4 qd = *(const f4*)&Qsp[t - qlo][12];
        int k0 = lane, k1 = lane + 64;
        float s0 = -1e30f, s1 = -1e30f;
        if (k0 <= t) {
            const float* kr = (k0 == t) ? &Ksp[t - qlo][0] : &Kb[k0][0];
            f4 d = qa * *(const f4*)(kr) + qb * *(const f4*)(kr + 4)
                 + qc * *(const f4*)(kr + 8) + qd * *(const f4*)(kr + 12);
            s0 = (d[0] + d[1] + d[2] + d[3]) * 0.25f;
        }
        if (k1 <= t) {
            const float* kr = (k1 == t) ? &Ksp[t - qlo][0] : &Kb[k1][0];
            f4 d = qa * *(const f4*)(kr) + qb * *(const f4*)(kr + 4)
                 + qc * *(const f4*)(kr + 8) + qd * *(const f4*)(kr + 12);
            s1 = (d[0] + d[1] + d[2] + d[3]) * 0.25f;
        }
        float m = fmaxf(s0, s1);
        #pragma unroll
        for (int o = 32; o > 0; o >>= 1) m = fmaxf(m, __shfl_xor(m, o));
        float p0 = (k0 <= t) ? __expf(s0 - m) : 0.f;
        float p1 = (k1 <= t) ? __expf(s1 - m) : 0.f;
        float sum = p0 + p1;
        #pragma unroll
        for (int o = 32; o > 0; o >>= 1) sum += __shfl_xor(sum, o);
        float inv = 1.0f / sum;
        Ps[wave][k0] = p0;
        if (k1 < TW) Ps[wave][k1] = p1;
        float acc = 0.f;
        for (int k = c; k < t; k += 4) acc += Ps[wave][k] * Vb[k][dd];
        if ((t & 3) == c) acc += Ps[wave][t] * Vsp[t - qlo][dd];
        acc += __shfl_xor(acc, 16);
        acc += __shfl_xor(acc, 32);
        if (lane < 16)
            O[(size_t)((t * TB + b) * TJ + j) * TH + head * THD + dd] = f2bf(acc * inv);
    }
}

// ---------------- spatial attention over joints (batched per frame) ----------
#define SPAD (TH + 4)
__global__ __launch_bounds__(192) void attn_spatial2_kernel(
        const float* __restrict__ Q, const float* __restrict__ K,
        const float* __restrict__ V, short* __restrict__ O) {
    __shared__ __align__(16) float Qs[TJ][SPAD], Ks[TJ][SPAD], Vs[TJ][SPAD];
    int blk = blockIdx.x;
    int b = blk & 1, t = blk >> 1;
    int base = (t * TB + b) * TJ;
    int tid = threadIdx.x;
    for (int i = tid; i < TJ * 32; i += 192) {
        int r = i >> 5, c4 = i & 31;
        ((f4*)&Qs[r][0])[c4] = ((const f4*)(Q + (size_t)(base + r) * TH))[c4];
        ((f4*)&Ks[r][0])[c4] = ((const f4*)(K + (size_t)(base + r) * TH))[c4];
        ((f4*)&Vs[r][0])[c4] = ((const f4*)(V + (size_t)(base + r) * TH))[c4];
    }
    __syncthreads();
    int qj = tid % TJ;
    int head = tid / TJ;
    int hb = head * THD;
    float qv[THD];
    #pragma unroll
    for (int u = 0; u < THD; ++u) qv[u] = Qs[qj][hb + u];
    float sc[TJ];
    float m = -1e30f;
    #pragma unroll
    for (int k = 0; k < TJ; ++k) {
        float a = 0.f;
        #pragma unroll
        for (int u = 0; u < THD; ++u) a += qv[u] * Ks[k][hb + u];
        sc[k] = a * 0.25f;
        m = fmaxf(m, sc[k]);
    }
    float sum = 0.f;
    #pragma unroll
    for (int k = 0; k < TJ; ++k) { sc[k] = __expf(sc[k] - m); sum += sc[k]; }
    float inv = 1.0f / sum;
    float o[THD];
    #pragma unroll
    for (int u = 0; u < THD; ++u) o[u] = 0.f;
    #pragma unroll
    for (int k = 0; k < TJ; ++k) {
        #pragma unroll
        for (int u = 0; u < THD; ++u) o[u] += sc[k] * Vs[k][hb + u];
    }
    size_t off = (size_t)(base + qj) * TH + hb;
    #pragma unroll
    for (int u = 0; u < THD; ++u) O[off + u] = f2bf(o[u] * inv);
}

// ---------------- final projection + residual ----------------
__global__ void final_kernel(const float* __restrict__ r4, const float* __restrict__ Wout,
                             const float* __restrict__ bout, const float* __restrict__ src,
                             const float* __restrict__ tgt, float* __restrict__ out) {
    int idx = blockIdx.x * 256 + threadIdx.x;
    if (idx >= TB * TW * TD) return;
    int d = idx % TD;
    int t = (idx / TD) % TW;
    int b = idx / (TD * TW);
    int j = d / 9, o = d % 9;
    const float* rr = r4 + (size_t)((t * TB + b) * TJ + j) * TH;
    const float* wt = Wout + (size_t)o * TH;
    float acc = bout[o];
    #pragma unroll 4
    for (int h = 0; h < TH; ++h) acc += rr[h] * wt[h];
    float cv = (t < 60) ? src[((size_t)b * 60 + t) * TD + d]
                        : tgt[((size_t)b * 61 + (t - 60)) * TD + d];
    out[idx] = acc + cv;
}

extern "C" void kernel_launch(void* const* d_in, const int* in_sizes, int n_in,
                              void* d_out, int out_size, void* d_ws, size_t ws_size,
                              hipStream_t stream) {
    const float* src    = (const float*)d_in[0];
    const float* tgt    = (const float*)d_in[1];
    const float* Wemb   = (const float*)d_in[2];
    const float* bemb   = (const float*)d_in[3];
    const float* Wqkv_s = (const float*)d_in[4];
    const float* bqkv_s = (const float*)d_in[5];
    const float* Wo_s   = (const float*)d_in[6];
    const float* bo_s   = (const float*)d_in[7];
    const float* sn_g   = (const float*)d_in[8];
    const float* sn_b   = (const float*)d_in[9];
    const float* Wqkv_t = (const float*)d_in[10];
    const float* bqkv_t = (const float*)d_in[11];
    const float* Wo_t   = (const float*)d_in[12];
    const float* bo_t   = (const float*)d_in[13];
    const float* tn_g   = (const float*)d_in[14];
    const float* tn_b   = (const float*)d_in[15];
    const float* W1     = (const float*)d_in[16];
    const float* b1     = (const float*)d_in[17];
    const float* W2     = (const float*)d_in[18];
    const float* b2     = (const float*)d_in[19];
    const float* Wout   = (const float*)d_in[20];
    const float* bout   = (const float*)d_in[21];
    float* out = (float*)d_out;

    const size_t RH = (size_t)TROWS * TH;   // 737280
    float* f = (float*)d_ws;
    float* cbuf  = f;                    // 51840
    float* x0    = cbuf + 51840;
    float* Kbase = x0 + RH;              // 4*RH
    float* Vbase = Kbase + 4 * RH;       // 4*RH
    float* r     = Vbase + 4 * RH;
    float* Qb    = r + RH;
    float* Kb    = Qb + RH;
    float* Vb    = Kb + RH;
    float* Qt    = Vb + RH;
    float* Kt    = Qt + RH;
    float* Vt    = Kt + RH;
    float* spout = Vt + RH;
    float* Bb0   = spout + RH;
    float* Bb1   = Bb0 + RH;
    short* sbase = (short*)(Bb1 + RH);
    short* x0bf  = sbase;
    short* rbf   = x0bf + RH;
    short* attnb = rbf + RH;
    short* ybbf  = attnb + RH;
    short* fbufb = ybbf + RH;            // TROWS*TF
    short* Bb0bf = fbufb + (size_t)TROWS * TF;
    short* Bb1bf = Bb0bf + RH;
    short* wbf   = Bb1bf + RH;           // NW_TOT shorts

    const short* wqkvs_bf = wbf;
    const short* wos_bf   = wbf + OFF_O_S;
    const short* wqkvt_bf = wbf + OFF_QKV_T;
    const short* wot_bf   = wbf + OFF_O_T;
    const short* w1bf     = wbf + OFF_W1;
    const short* w2bf     = wbf + OFF_W2;

    // 0. weights -> bf16 (scratch is volatile; redo every call)
    convert_weights_kernel<<<(NW_TOT / 4 + 255) / 256, 256, 0, stream>>>(
        Wqkv_s, Wo_s, Wqkv_t, Wo_t, W1, W2, wbf);

    // 1. gather concat, then embedding GEMM (+PE); writes x0/x0bf and r/rbf
    gather_kernel<<<(TBF * TD + 255) / 256, 256, 0, stream>>>(src, tgt, cbuf);
    gemm_embed_kernel<<<dim3(4, 48), 256, 0, stream>>>(cbuf, Wemb, bemb, x0, x0bf, r, rbf);

    // 2. baseline pass (temporal-only stack); save per-layer K/V projections
    const float* Binf = x0;
    const short* Binbf = x0bf;
    for (int l = 0; l < 4; ++l) {
        int nblk = (l < 3) ? 6 : 4;          // l==3 needs only K,V
        int n0base = (l < 3) ? 0 : 128;
        mfma_qkv_kernel<<<dim3(4, nblk, 24), 256, 0, stream>>>(
            Binbf, wqkvt_bf + (size_t)l * TJ * 3 * TH * TH, bqkv_t + (size_t)l * TJ * 3 * TH,
            Qb, Kbase + l * RH, Vbase + l * RH, n0base);
        if (l < 3) {
            attn_causal2_kernel<<<dim3(TB * TJ * TNH, 2), 512, 0, stream>>>(
                Qb, Kbase + l * RH, Vbase + l * RH, attnb);
            mfma_oln_kernel<<<dim3(15, 1, 24), 256, 0, stream>>>(
                attnb, wot_bf + (size_t)l * TJ * TH * TH, bo_t + (size_t)l * TJ * TH,
                Binf, tn_g + l * TH, tn_b + l * TH, nullptr, nullptr, ybbf, 1);
            mfma_ffn1_kernel<<<dim3(90, 4), 256, 0, stream>>>(
                ybbf, w1bf + (size_t)l * TF * TH, b1 + l * TF, fbufb);
            float* Boutf = (l & 1) ? Bb1 : Bb0;
            short* Boutbf = (l & 1) ? Bb1bf : Bb0bf;
            mfma_ffn2_kernel<<<dim3(90, 2), 256, 0, stream>>>(
                fbufb, w2bf + (size_t)l * TH * TF, b2 + l * TH, Boutf, Boutbf);
            Binf = Boutf; Binbf = Boutbf;
        }
    }

    // 3. per-t special-row chains (all 120 t in parallel)
    for (int l = 0; l < 4; ++l) {
        mfma_qkv2_kernel<<<dim3(4, 12, 24), 256, 0, stream>>>(
            rbf, wqkvs_bf + (size_t)l * 3 * TH * TH,
            wqkvt_bf + (size_t)l * TJ * 3 * TH * TH,
            bqkv_s + (size_t)l * 3 * TH, bqkv_t + (size_t)l * TJ * 3 * TH,
            Qb, Kb, Vb, Qt, Kt, Vt);
        attn_spatial2_kernel<<<TW * TB, 192, 0, stream>>>(Qb, Kb, Vb, attnb);
        mfma_oln_kernel<<<dim3(15, 1, 24), 256, 0, stream>>>(
            attnb, wos_bf + (size_t)l * TH * TH, bo_s + (size_t)l * TH,
            r, sn_g + l * TH, sn_b + l * TH, nullptr, spout, nullptr, 0);
        attn_special2_kernel<<<dim3(TB * TJ * TNH, 2), 512, 0, stream>>>(
            Qt, Kt, Vt, Kbase + l * RH, Vbase + l * RH, attnb);
        mfma_oln_kernel<<<dim3(15, 1, 24), 256, 0, stream>>>(
            attnb, wot_bf + (size_t)l * TJ * TH * TH, bo_t + (size_t)l * TJ * TH,
            r, tn_g + l * TH, tn_b + l * TH, spout, nullptr, ybbf, 1);
        mfma_ffn1_kernel<<<dim3(90, 4), 256, 0, stream>>>(
            ybbf, w1bf + (size_t)l * TF * TH, b1 + l * TF, fbufb);
        mfma_ffn2_kernel<<<dim3(90, 2), 256, 0, stream>>>(
            fbufb, w2bf + (size_t)l * TH * TF, b2 + l * TH, r, rbf);
    }

    // 4. output projection + residual
    final_kernel<<<(TB * TW * TD + 255) / 256, 256, 0, stream>>>(r, Wout, bout, src, tgt, out);
}

// Round 10
// 371.442 us; speedup vs baseline: 17.5356x; 1.2154x over previous
//
#include <hip/hip_runtime.h>

// Sizes
#define TW 120
#define TB 2
#define TJ 24
#define TH 128
#define TNH 8
#define THD 16
#define TF 256
#define TD 216
#define TROWS (TW*TB*TJ)   // 5760
#define TEMB (TJ*TH)       // 3072
#define TBF 240

#define KC 32
#define LDA 68
#define APAD 20    // attention LDS row pad (floats): 16B-aligned, ~2-way aliasing
#define QCH 60
#define LDT 136    // bf16 MFMA LDS row stride (shorts)
#define SPAD (TH + 4)

typedef float f4 __attribute__((ext_vector_type(4)));
typedef short bf8 __attribute__((ext_vector_type(8)));
typedef short s4 __attribute__((ext_vector_type(4)));

__device__ __forceinline__ short f2bf(float x) {
    union { float f; unsigned u; } v; v.f = x;
    unsigned r = (v.u + 0x7FFFu + ((v.u >> 16) & 1u)) >> 16;
    return (short)r;
}

// ---------------- weight conversion + gather (fused) ----------------
#define NW_QKV_S 196608
#define NW_O_S    65536
#define NW_QKV_T 4718592
#define NW_O_T   1572864
#define NW_1      131072
#define NW_2      131072
#define OFF_O_S   (NW_QKV_S)
#define OFF_QKV_T (OFF_O_S + NW_O_S)
#define OFF_O_T   (OFF_QKV_T + NW_QKV_T)
#define OFF_W1    (OFF_O_T + NW_O_T)
#define OFF_W2    (OFF_W1 + NW_1)
#define NW_TOT    (OFF_W2 + NW_2)      // 6815744
#define NB_CONV   (NW_TOT / 4 / 256)   // 6656 exact
#define NB_GATH   ((TBF*TD + 255) / 256)

__global__ void convgather_kernel(const float* __restrict__ Wqkv_s, const float* __restrict__ Wo_s,
                                  const float* __restrict__ Wqkv_t, const float* __restrict__ Wo_t,
                                  const float* __restrict__ W1, const float* __restrict__ W2,
                                  short* __restrict__ dst,
                                  const float* __restrict__ src, const float* __restrict__ tgt,
                                  float* __restrict__ cbuf) {
    if (blockIdx.x < NB_CONV) {
        size_t i = ((size_t)blockIdx.x * 256 + threadIdx.x) * 4;
        const float* s; size_t off;
        if (i < NW_QKV_S)       { s = Wqkv_s; off = i; }
        else if (i < OFF_QKV_T) { s = Wo_s;   off = i - OFF_O_S; }
        else if (i < OFF_O_T)   { s = Wqkv_t; off = i - OFF_QKV_T; }
        else if (i < OFF_W1)    { s = Wo_t;   off = i - OFF_O_T; }
        else if (i < OFF_W2)    { s = W1;     off = i - OFF_W1; }
        else                    { s = W2;     off = i - OFF_W2; }
        f4 v = *(const f4*)(s + off);
        s4 o = { f2bf(v[0]), f2bf(v[1]), f2bf(v[2]), f2bf(v[3]) };
        *(s4*)(dst + i) = o;
    } else {
        int idx = (blockIdx.x - NB_CONV) * 256 + threadIdx.x;
        if (idx >= TBF * TD) return;
        int d = idx % TD;
        int row = idx / TD;
        int b = row & 1, t = row >> 1;
        cbuf[idx] = (t < 60) ? src[((size_t)b * 60 + t) * TD + d]
                             : tgt[((size_t)b * 61 + (t - 60)) * TD + d];
    }
}

// ---------------- MFMA building blocks ----------------
__device__ __forceinline__ void stage_bf(short* Ds, const short* __restrict__ src,
                                         size_t rstride, int nrows, int tid) {
    int r = tid >> 2, s = (tid & 3) * 32;
    short* d = Ds + r * LDT + s;
    if (r < nrows) {
        const short* p = src + (size_t)r * rstride + s;
        *(bf8*)(d)      = *(const bf8*)(p);
        *(bf8*)(d + 8)  = *(const bf8*)(p + 8);
        *(bf8*)(d + 16) = *(const bf8*)(p + 16);
        *(bf8*)(d + 24) = *(const bf8*)(p + 24);
    } else {
        bf8 z = {0,0,0,0,0,0,0,0};
        *(bf8*)(d) = z; *(bf8*)(d+8) = z; *(bf8*)(d+16) = z; *(bf8*)(d+24) = z;
    }
}

__device__ __forceinline__ void mfma_tile64(const short* As, const short* Bs,
                                            int wave, int lane, f4 acc[2][2]) {
    int wm = wave >> 1, wn = wave & 1;
    int lrow = lane & 15, lk = (lane >> 4) * 8;
    #pragma unroll
    for (int ks = 0; ks < 4; ++ks) {
        bf8 a0 = *(const bf8*)&As[(wm*32      + lrow) * LDT + ks*32 + lk];
        bf8 a1 = *(const bf8*)&As[(wm*32 + 16 + lrow) * LDT + ks*32 + lk];
        bf8 b0 = *(const bf8*)&Bs[(wn*32      + lrow) * LDT + ks*32 + lk];
        bf8 b1 = *(const bf8*)&Bs[(wn*32 + 16 + lrow) * LDT + ks*32 + lk];
        acc[0][0] = __builtin_amdgcn_mfma_f32_16x16x32_bf16(a0, b0, acc[0][0], 0, 0, 0);
        acc[0][1] = __builtin_amdgcn_mfma_f32_16x16x32_bf16(a0, b1, acc[0][1], 0, 0, 0);
        acc[1][0] = __builtin_amdgcn_mfma_f32_16x16x32_bf16(a1, b0, acc[1][0], 0, 0, 0);
        acc[1][1] = __builtin_amdgcn_mfma_f32_16x16x32_bf16(a1, b1, acc[1][1], 0, 0, 0);
    }
}

// ---------------- mega QKV: part2 (per-joint) + part3 (shared + per-joint) ----
// grid (4, p2n+12, 24). yy < p2n: part2 temporal slices (n0base offset).
// else: part3 — first 6 slices spatial (shared W), next 6 temporal (per-joint).
__global__ __launch_bounds__(256) void mfma_qkvmega_kernel(
        const short* __restrict__ A2, const short* __restrict__ A3,
        const short* __restrict__ Wt, const short* __restrict__ Ws,
        const float* __restrict__ bt, const float* __restrict__ bs,
        float* __restrict__ Qp2, float* __restrict__ Kb2, float* __restrict__ Vb2,
        float* __restrict__ Qs_, float* __restrict__ Ks_, float* __restrict__ Vs_,
        float* __restrict__ Qt_, float* __restrict__ Kt_, float* __restrict__ Vt_,
        int p2n, int n0base) {
    __shared__ short As[64 * LDT], Bs[64 * LDT];
    int tid = threadIdx.x;
    int m0 = blockIdx.x * 64, j = blockIdx.z, yy = blockIdx.y;
    int mrem = TBF - m0; if (mrem > 64) mrem = 64;
    const short* Abf; const short* Wbf; const float* bias; int bofs, n0;
    float *dq, *dk, *dv;
    if (yy < p2n) {
        n0 = n0base + yy * 64;
        Abf = A2;
        Wbf = Wt + (size_t)j * 3 * TH * TH + (size_t)n0 * TH;
        bias = bt; bofs = j * 3 * TH;
        dq = Qp2; dk = Kb2; dv = Vb2;
    } else {
        int y2 = yy - p2n;
        int tmp = (y2 >= 6);
        n0 = (tmp ? y2 - 6 : y2) * 64;
        Abf = A3;
        if (tmp) { Wbf = Wt + (size_t)j * 3 * TH * TH + (size_t)n0 * TH; bias = bt; bofs = j * 3 * TH;
                   dq = Qt_; dk = Kt_; dv = Vt_; }
        else     { Wbf = Ws + (size_t)n0 * TH; bias = bs; bofs = 0;
                   dq = Qs_; dk = Ks_; dv = Vs_; }
    }
    stage_bf(As, Abf + (size_t)m0 * TEMB + j * TH, TEMB, mrem, tid);
    stage_bf(Bs, Wbf, TH, 64, tid);
    __syncthreads();
    int wave = tid >> 6, lane = tid & 63;
    f4 acc[2][2] = {{{0,0,0,0},{0,0,0,0}},{{0,0,0,0},{0,0,0,0}}};
    mfma_tile64(As, Bs, wave, lane, acc);
    int wm = wave >> 1, wn = wave & 1, lrow = lane & 15, gr = (lane >> 4) * 4;
    float* dst = (n0 < TH) ? dq : ((n0 < 2 * TH) ? dk : dv);
    int cb = n0 & (TH - 1);
    #pragma unroll
    for (int ni = 0; ni < 2; ++ni) {
        float bv = bias[bofs + n0 + wn*32 + ni*16 + lrow];
        int col = cb + wn*32 + ni*16 + lrow;
        #pragma unroll
        for (int mi = 0; mi < 2; ++mi)
            #pragma unroll
            for (int rg = 0; rg < 4; ++rg) {
                int tr = wm*32 + mi*16 + gr + rg;
                if (tr < mrem)
                    dst[(size_t)((m0 + tr) * TJ + j) * TH + col] = acc[mi][ni][rg] + bv;
            }
    }
}

// ---------------- mega attention: spatial (240) + causal (ncausal) + special (768)
__global__ __launch_bounds__(512) void attn_mega_kernel(
        const float* __restrict__ Qc_g, const float* __restrict__ Kc_g, const float* __restrict__ Vc_g,
        const float* __restrict__ Qs_g, const float* __restrict__ Ks_g, const float* __restrict__ Vs_g,
        const float* __restrict__ Qt_g, const float* __restrict__ Kt_g, const float* __restrict__ Vt_g,
        short* __restrict__ Oc, short* __restrict__ Os, short* __restrict__ Ot,
        int ncausal) {
    __shared__ __align__(16) float smem[9504];   // 38,016 B: max(spatial, special)
    int bx = blockIdx.x;
    int tid = threadIdx.x;

    if (bx < 240) {
        // ---- spatial: per-frame, 192 compute roles ----
        float* Qs = smem;
        float* Ks = smem + TJ * SPAD;
        float* Vs = smem + 2 * TJ * SPAD;
        int b = bx & 1, t = bx >> 1;
        int base = (t * TB + b) * TJ;
        for (int i = tid; i < TJ * 32; i += 512) {
            int rr = i >> 5, c4 = i & 31;
            ((f4*)(Qs + rr * SPAD))[c4] = ((const f4*)(Qs_g + (size_t)(base + rr) * TH))[c4];
            ((f4*)(Ks + rr * SPAD))[c4] = ((const f4*)(Ks_g + (size_t)(base + rr) * TH))[c4];
            ((f4*)(Vs + rr * SPAD))[c4] = ((const f4*)(Vs_g + (size_t)(base + rr) * TH))[c4];
        }
        __syncthreads();
        if (tid >= 192) return;
        int qj = tid % TJ;
        int head = tid / TJ;
        int hb = head * THD;
        float qv[THD];
        #pragma unroll
        for (int u = 0; u < THD; ++u) qv[u] = Qs[qj * SPAD + hb + u];
        float sc[TJ];
        float m = -1e30f;
        #pragma unroll
        for (int k = 0; k < TJ; ++k) {
            float a = 0.f;
            #pragma unroll
            for (int u = 0; u < THD; ++u) a += qv[u] * Ks[k * SPAD + hb + u];
            sc[k] = a * 0.25f;
            m = fmaxf(m, sc[k]);
        }
        float sum = 0.f;
        #pragma unroll
        for (int k = 0; k < TJ; ++k) { sc[k] = __expf(sc[k] - m); sum += sc[k]; }
        float inv = 1.0f / sum;
        float o[THD];
        #pragma unroll
        for (int u = 0; u < THD; ++u) o[u] = 0.f;
        #pragma unroll
        for (int k = 0; k < TJ; ++k) {
            #pragma unroll
            for (int u = 0; u < THD; ++u) o[u] += sc[k] * Vs[k * SPAD + hb + u];
        }
        size_t off = (size_t)(base + qj) * TH + hb;
        #pragma unroll
        for (int u = 0; u < THD; ++u) Os[off + u] = f2bf(o[u] * inv);
        return;
    }

    int cx = bx - 240;
    int wave = tid >> 6, lane = tid & 63;
    int dd = lane & 15, c = lane >> 4;
    int sd = tid & 15, sr = tid >> 4;

    if (cx < ncausal) {
        // ---- causal (part 2) ----
        float* Qc = smem;                       // QCH*APAD
        float* Kc = Qc + QCH * APAD;            // TW*APAD
        float* Vc = Kc + TW * APAD;             // TW*APAD
        float* Ps = Vc + TW * APAD;             // 8*TW
        int bhj = cx % 384, chunk = cx / 384;
        int head = bhj & 7;
        int j = (bhj >> 3) % TJ;
        int b = (bhj >> 3) / TJ;
        int qlo = chunk * QCH, qhi = qlo + QCH;
        for (int rr = sr; rr < qhi; rr += 32) {
            size_t off = (size_t)((rr * TB + b) * TJ + j) * TH + head * THD + sd;
            Kc[rr * APAD + sd] = Kc_g[off]; Vc[rr * APAD + sd] = Vc_g[off];
            if (rr >= qlo) Qc[(rr - qlo) * APAD + sd] = Qc_g[off];
        }
        __syncthreads();
        for (int q = qlo + wave; q < qhi; q += 8) {
            const float* qr = Qc + (q - qlo) * APAD;
            f4 qa = *(const f4*)(qr), qb = *(const f4*)(qr + 4);
            f4 qc = *(const f4*)(qr + 8), qd = *(const f4*)(qr + 12);
            int k0 = lane, k1 = lane + 64;
            float s0 = -1e30f, s1 = -1e30f;
            if (k0 <= q) {
                const float* kr = Kc + k0 * APAD;
                f4 d = qa * *(const f4*)(kr) + qb * *(const f4*)(kr + 4)
                     + qc * *(const f4*)(kr + 8) + qd * *(const f4*)(kr + 12);
                s0 = (d[0] + d[1] + d[2] + d[3]) * 0.25f;
            }
            if (k1 <= q) {
                const float* kr = Kc + k1 * APAD;
                f4 d = qa * *(const f4*)(kr) + qb * *(const f4*)(kr + 4)
                     + qc * *(const f4*)(kr + 8) + qd * *(const f4*)(kr + 12);
                s1 = (d[0] + d[1] + d[2] + d[3]) * 0.25f;
            }
            float m = fmaxf(s0, s1);
            #pragma unroll
            for (int o = 32; o > 0; o >>= 1) m = fmaxf(m, __shfl_xor(m, o));
            float p0 = (k0 <= q) ? __expf(s0 - m) : 0.f;
            float p1 = (k1 <= q) ? __expf(s1 - m) : 0.f;
            float sum = p0 + p1;
            #pragma unroll
            for (int o = 32; o > 0; o >>= 1) sum += __shfl_xor(sum, o);
            float inv = 1.0f / sum;
            Ps[wave * TW + k0] = p0;
            if (k1 < TW) Ps[wave * TW + k1] = p1;
            float acc = 0.f;
            for (int k = c; k <= q; k += 4) acc += Ps[wave * TW + k] * Vc[k * APAD + dd];
            acc += __shfl_xor(acc, 16);
            acc += __shfl_xor(acc, 32);
            if (lane < 16)
                Oc[(size_t)((q * TB + b) * TJ + j) * TH + head * THD + dd] = f2bf(acc * inv);
        }
        return;
    }

    // ---- special (part 3) ----
    int sx = cx - ncausal;
    float* Qsp = smem;                      // QCH*APAD
    float* Ksp = Qsp + QCH * APAD;
    float* Vsp = Ksp + QCH * APAD;
    float* Kb  = Vsp + QCH * APAD;          // TW*APAD
    float* Vb  = Kb + TW * APAD;
    float* Ps  = Vb + TW * APAD;            // 8*TW
    int bhj = sx % 384, chunk = sx / 384;
    int head = bhj & 7;
    int j = (bhj >> 3) % TJ;
    int b = (bhj >> 3) / TJ;
    int qlo = chunk * QCH, qhi = qlo + QCH;
    for (int rr = sr; rr < qhi; rr += 32) {
        size_t off = (size_t)((rr * TB + b) * TJ + j) * TH + head * THD + sd;
        Kb[rr * APAD + sd] = Kc_g[off]; Vb[rr * APAD + sd] = Vc_g[off];
        if (rr >= qlo) {
            Qsp[(rr - qlo) * APAD + sd] = Qt_g[off];
            Ksp[(rr - qlo) * APAD + sd] = Kt_g[off];
            Vsp[(rr - qlo) * APAD + sd] = Vt_g[off];
        }
    }
    __syncthreads();
    for (int t = qlo + wave; t < qhi; t += 8) {
        const float* qr = Qsp + (t - qlo) * APAD;
        f4 qa = *(const f4*)(qr), qb = *(const f4*)(qr + 4);
        f4 qc = *(const f4*)(qr + 8), qd = *(const f4*)(qr + 12);
        int k0 = lane, k1 = lane + 64;
        float s0 = -1e30f, s1 = -1e30f;
        if (k0 <= t) {
            const float* kr = (k0 == t) ? (Ksp + (t - qlo) * APAD) : (Kb + k0 * APAD);
            f4 d = qa * *(const f4*)(kr) + qb * *(const f4*)(kr + 4)
                 + qc * *(const f4*)(kr + 8) + qd * *(const f4*)(kr + 12);
            s0 = (d[0] + d[1] + d[2] + d[3]) * 0.25f;
        }
        if (k1 <= t) {
            const float* kr = (k1 == t) ? (Ksp + (t - qlo) * APAD) : (Kb + k1 * APAD);
            f4 d = qa * *(const f4*)(kr) + qb * *(const f4*)(kr + 4)
                 + qc * *(const f4*)(kr + 8) + qd * *(const f4*)(kr + 12);
            s1 = (d[0] + d[1] + d[2] + d[3]) * 0.25f;
        }
        float m = fmaxf(s0, s1);
        #pragma unroll
        for (int o = 32; o > 0; o >>= 1) m = fmaxf(m, __shfl_xor(m, o));
        float p0 = (k0 <= t) ? __expf(s0 - m) : 0.f;
        float p1 = (k1 <= t) ? __expf(s1 - m) : 0.f;
        float sum = p0 + p1;
        #pragma unroll
        for (int o = 32; o > 0; o >>= 1) sum += __shfl_xor(sum, o);
        float inv = 1.0f / sum;
        Ps[wave * TW + k0] = p0;
        if (k1 < TW) Ps[wave * TW + k1] = p1;
        float acc = 0.f;
        for (int k = c; k < t; k += 4) acc += Ps[wave * TW + k] * Vb[k * APAD + dd];
        if ((t & 3) == c) acc += Ps[wave * TW + t] * Vsp[(t - qlo) * APAD + dd];
        acc += __shfl_xor(acc, 16);
        acc += __shfl_xor(acc, 32);
        if (lane < 16)
            Ot[(size_t)((t * TB + b) * TJ + j) * TH + head * THD + dd] = f2bf(acc * inv);
    }
}

// ---------------- OLN core (out-proj MFMA + residual + LN + optional add) -----
__device__ __forceinline__ void oln_core(
        const short* __restrict__ Abf, const short* __restrict__ Wbf,
        const float* __restrict__ bias, const float* __restrict__ resid,
        const float* __restrict__ g, const float* __restrict__ bln,
        const float* __restrict__ addv, float* __restrict__ Yf,
        short* __restrict__ Ybf, int perJoint, int m0, int j,
        short* As, short* Bs, float* rsum, float* rsq, float* lnm, float* lnr) {
    int tid = threadIdx.x;
    { int r = tid >> 4, s = (tid & 15) * 8;
      *(bf8*)&As[r * LDT + s] = *(const bf8*)(Abf + (size_t)(m0 + r) * TEMB + j * TH + s); }
    { int r = tid >> 1, s = (tid & 1) * 64;
      const short* p = Wbf + (perJoint ? (size_t)j * TH * TH : 0) + (size_t)r * TH + s;
      short* d = &Bs[r * LDT + s];
      #pragma unroll
      for (int cc = 0; cc < 64; cc += 8) *(bf8*)(d + cc) = *(const bf8*)(p + cc); }
    __syncthreads();
    int wave = tid >> 6, lane = tid & 63, lrow = lane & 15, lk = (lane >> 4) * 8, gr = (lane >> 4) * 4;
    f4 acc[2] = {{0,0,0,0},{0,0,0,0}};
    #pragma unroll
    for (int ks = 0; ks < 4; ++ks) {
        bf8 a  = *(const bf8*)&As[lrow * LDT + ks*32 + lk];
        bf8 b0 = *(const bf8*)&Bs[(wave*32      + lrow) * LDT + ks*32 + lk];
        bf8 b1 = *(const bf8*)&Bs[(wave*32 + 16 + lrow) * LDT + ks*32 + lk];
        acc[0] = __builtin_amdgcn_mfma_f32_16x16x32_bf16(a, b0, acc[0], 0, 0, 0);
        acc[1] = __builtin_amdgcn_mfma_f32_16x16x32_bf16(a, b1, acc[1], 0, 0, 0);
    }
    int col0 = wave*32 + lrow, col1 = col0 + 16;
    int bofs = perJoint ? j * TH : 0;
    float bv0 = bias[bofs + col0], bv1 = bias[bofs + col1];
    float v0[4], v1[4], sr_[4], sq_[4];
    #pragma unroll
    for (int rg = 0; rg < 4; ++rg) {
        size_t ro = (size_t)(m0 + gr + rg) * TEMB + j * TH;
        v0[rg] = acc[0][rg] + bv0 + resid[ro + col0];
        v1[rg] = acc[1][rg] + bv1 + resid[ro + col1];
        sr_[rg] = v0[rg] + v1[rg];
        sq_[rg] = v0[rg]*v0[rg] + v1[rg]*v1[rg];
    }
    #pragma unroll
    for (int o = 1; o < 16; o <<= 1) {
        #pragma unroll
        for (int rg = 0; rg < 4; ++rg) { sr_[rg] += __shfl_xor(sr_[rg], o); sq_[rg] += __shfl_xor(sq_[rg], o); }
    }
    if (lrow == 0) {
        #pragma unroll
        for (int rg = 0; rg < 4; ++rg) { rsum[wave*16 + gr + rg] = sr_[rg]; rsq[wave*16 + gr + rg] = sq_[rg]; }
    }
    __syncthreads();
    if (tid < 16) {
        float s = rsum[tid] + rsum[16 + tid] + rsum[32 + tid] + rsum[48 + tid];
        float q = rsq[tid] + rsq[16 + tid] + rsq[32 + tid] + rsq[48 + tid];
        float mean = s * (1.0f / TH);
        float var = q * (1.0f / TH) - mean * mean;
        lnm[tid] = mean; lnr[tid] = rsqrtf(var + 1e-5f);
    }
    __syncthreads();
    float g0 = g[col0], g1 = g[col1], l0 = bln[col0], l1 = bln[col1];
    #pragma unroll
    for (int rg = 0; rg < 4; ++rg) {
        int row = gr + rg;
        float mean = lnm[row], rs = lnr[row];
        size_t ro = (size_t)(m0 + row) * TEMB + j * TH;
        float o0 = (v0[rg] - mean) * rs * g0 + l0;
        float o1 = (v1[rg] - mean) * rs * g1 + l1;
        if (addv) { o0 += addv[ro + col0]; o1 += addv[ro + col1]; }
        if (Yf)  { Yf[ro + col0] = o0; Yf[ro + col1] = o1; }
        if (Ybf) { Ybf[ro + col0] = f2bf(o0); Ybf[ro + col1] = f2bf(o1); }
    }
}

// launch-3 mega: part2-oln (np2 blocks) + part3-spatial-oln (360 blocks)
__global__ __launch_bounds__(256) void mfma_olnmega_kernel(
        const short* __restrict__ A2, const short* __restrict__ Wt,
        const float* __restrict__ bt, const float* __restrict__ res2,
        const float* __restrict__ g2, const float* __restrict__ l2,
        short* __restrict__ Yb2,
        const short* __restrict__ A3, const short* __restrict__ Ws,
        const float* __restrict__ bs, const float* __restrict__ res3,
        const float* __restrict__ g3, const float* __restrict__ l3,
        float* __restrict__ Yf3, int np2) {
    __shared__ short As[16 * LDT];
    __shared__ short Bs[128 * LDT];
    __shared__ float rsum[64], rsq[64], lnm[16], lnr[16];
    int bx = blockIdx.x;
    if (bx < np2) {
        int m0 = (bx % 15) * 16, j = bx / 15;
        oln_core(A2, Wt, bt, res2, g2, l2, nullptr, nullptr, Yb2, 1, m0, j,
                 As, Bs, rsum, rsq, lnm, lnr);
    } else {
        int idx = bx - np2;
        int m0 = (idx % 15) * 16, j = idx / 15;
        oln_core(A3, Ws, bs, res3, g3, l3, nullptr, Yf3, nullptr, 0, m0, j,
                 As, Bs, rsum, rsq, lnm, lnr);
    }
}

// launch-4: part3 temporal oln (360 blocks)
__global__ __launch_bounds__(256) void mfma_oln_kernel(
        const short* __restrict__ Abf, const short* __restrict__ Wbf,
        const float* __restrict__ bias, const float* __restrict__ resid,
        const float* __restrict__ g, const float* __restrict__ bln,
        const float* __restrict__ addv, float* __restrict__ Yf,
        short* __restrict__ Ybf, int perJoint) {
    __shared__ short As[16 * LDT];
    __shared__ short Bs[128 * LDT];
    __shared__ float rsum[64], rsq[64], lnm[16], lnr[16];
    int bx = blockIdx.x;
    int m0 = (bx % 15) * 16, j = bx / 15;
    oln_core(Abf, Wbf, bias, resid, g, bln, addv, Yf, Ybf, perJoint, m0, j,
             As, Bs, rsum, rsq, lnm, lnr);
}

// ---------------- FFN MFMA GEMMs (batched over part2+part3 rows) -------------
__global__ __launch_bounds__(256) void mfma_ffn1_kernel(
        const short* __restrict__ Ybf, const short* __restrict__ W1bf,
        const float* __restrict__ b1, short* __restrict__ Fb) {
    __shared__ short As[64 * LDT], Bs[64 * LDT];
    int tid = threadIdx.x;
    int m0 = blockIdx.x * 64, n0 = blockIdx.y * 64;
    stage_bf(As, Ybf + (size_t)m0 * TH, TH, 64, tid);
    stage_bf(Bs, W1bf + (size_t)n0 * TH, TH, 64, tid);
    __syncthreads();
    int wave = tid >> 6, lane = tid & 63;
    f4 acc[2][2] = {{{0,0,0,0},{0,0,0,0}},{{0,0,0,0},{0,0,0,0}}};
    mfma_tile64(As, Bs, wave, lane, acc);
    int wm = wave >> 1, wn = wave & 1, lrow = lane & 15, gr = (lane >> 4) * 4;
    #pragma unroll
    for (int ni = 0; ni < 2; ++ni) {
        int col = n0 + wn*32 + ni*16 + lrow;
        float bv = b1[col];
        #pragma unroll
        for (int mi = 0; mi < 2; ++mi)
            #pragma unroll
            for (int rg = 0; rg < 4; ++rg) {
                int tr = wm*32 + mi*16 + gr + rg;
                float v = 2.0f * fmaxf(acc[mi][ni][rg] + bv, 0.0f);
                Fb[(size_t)(m0 + tr) * TF + col] = f2bf(v);
            }
    }
}

// rows < splitrow -> OutA (f32+bf16); rows >= splitrow -> OutB[row-splitrow]
__global__ __launch_bounds__(256) void mfma_ffn2_kernel(
        const short* __restrict__ Fb, const short* __restrict__ W2bf,
        const float* __restrict__ b2, float* __restrict__ OutAf,
        short* __restrict__ OutAbf, float* __restrict__ OutBf,
        short* __restrict__ OutBbf, int splitrow) {
    __shared__ short As[64 * LDT], Bs[64 * LDT];
    int tid = threadIdx.x;
    int m0 = blockIdx.x * 64, n0 = blockIdx.y * 64;
    int wave = tid >> 6, lane = tid & 63;
    f4 acc[2][2] = {{{0,0,0,0},{0,0,0,0}},{{0,0,0,0},{0,0,0,0}}};
    #pragma unroll
    for (int kk = 0; kk < 2; ++kk) {
        stage_bf(As, Fb + (size_t)m0 * TF + kk * 128, TF, 64, tid);
        stage_bf(Bs, W2bf + (size_t)n0 * TF + kk * 128, TF, 64, tid);
        __syncthreads();
        mfma_tile64(As, Bs, wave, lane, acc);
        __syncthreads();
    }
    int wm = wave >> 1, wn = wave & 1, lrow = lane & 15, gr = (lane >> 4) * 4;
    #pragma unroll
    for (int ni = 0; ni < 2; ++ni) {
        int col = n0 + wn*32 + ni*16 + lrow;
        float bv = b2[col];
        #pragma unroll
        for (int mi = 0; mi < 2; ++mi)
            #pragma unroll
            for (int rg = 0; rg < 4; ++rg) {
                int tr = wm*32 + mi*16 + gr + rg;
                int row = m0 + tr;
                float v = acc[mi][ni][rg] + bv;
                if (row < splitrow) {
                    size_t off = (size_t)row * TH + col;
                    OutAf[off] = v; OutAbf[off] = f2bf(v);
                } else {
                    size_t off = (size_t)(row - splitrow) * TH + col;
                    OutBf[off] = v; OutBbf[off] = f2bf(v);
                }
            }
    }
}

// ---------- fp32 GEMM helpers (embed only) ----------
__device__ __forceinline__ void stageA(float* As, const float* __restrict__ A,
                                       int a_stride, int mrem, int K, int k0, int tid) {
    int r = tid >> 2;
    int kk = (tid & 3) << 3;
    bool rowok = r < mrem;
    const float* ap = A + (size_t)r * a_stride + k0 + kk;
    #pragma unroll
    for (int c = 0; c < 8; c += 4) {
        f4 v = {0.f, 0.f, 0.f, 0.f};
        int kg = k0 + kk + c;
        if (rowok) {
            if (kg + 4 <= K) v = *(const f4*)(ap + c);
            else {
                #pragma unroll
                for (int u = 0; u < 4; ++u) if (kg + u < K) v[u] = ap[c + u];
            }
        }
        As[(kk + c + 0) * LDA + r] = v[0];
        As[(kk + c + 1) * LDA + r] = v[1];
        As[(kk + c + 2) * LDA + r] = v[2];
        As[(kk + c + 3) * LDA + r] = v[3];
    }
}

__device__ __forceinline__ void stageB64(float* Bs, const float* __restrict__ Bw,
                                         int K, int k0, int tid) {
    int r = tid >> 2;
    int kk = (tid & 3) << 3;
    const float* bp = Bw + (size_t)r * K + k0 + kk;
    #pragma unroll
    for (int c = 0; c < 8; c += 4) {
        f4 v = {0.f, 0.f, 0.f, 0.f};
        int kg = k0 + kk + c;
        if (kg + 4 <= K) v = *(const f4*)(bp + c);
        else {
            #pragma unroll
            for (int u = 0; u < 4; ++u) if (kg + u < K) v[u] = bp[c + u];
        }
        Bs[(kk + c + 0) * LDA + r] = v[0];
        Bs[(kk + c + 1) * LDA + r] = v[1];
        Bs[(kk + c + 2) * LDA + r] = v[2];
        Bs[(kk + c + 3) * LDA + r] = v[3];
    }
}

__device__ __forceinline__ void mac64(const float* As, const float* Bs, int tr, int tc, f4 acc[4]) {
    #pragma unroll
    for (int kk = 0; kk < KC; ++kk) {
        f4 a = *(const f4*)&As[kk * LDA + tr * 4];
        f4 b = *(const f4*)&Bs[kk * LDA + tc * 4];
        acc[0] += a[0] * b;
        acc[1] += a[1] * b;
        acc[2] += a[2] * b;
        acc[3] += a[3] * b;
    }
}

// ---------------- embedding GEMM + bias + PE (writes x0, x0bf, r, rbf) -------
__global__ __launch_bounds__(256) void gemm_embed_kernel(
        const float* __restrict__ cbuf, const float* __restrict__ Wemb,
        const float* __restrict__ bemb, float* __restrict__ x0,
        short* __restrict__ x0bf, float* __restrict__ r0,
        short* __restrict__ r0bf) {
    __shared__ __align__(16) float As[KC * LDA];
    __shared__ __align__(16) float Bs[KC * LDA];
    int tid = threadIdx.x;
    int m0 = blockIdx.x * 64;
    int n0 = blockIdx.y * 64;
    int mrem = TBF - m0; if (mrem > 64) mrem = 64;
    const float* A = cbuf + (size_t)m0 * TD;
    const float* Bw = Wemb + (size_t)n0 * TD;
    f4 acc[4] = {{0,0,0,0},{0,0,0,0},{0,0,0,0},{0,0,0,0}};
    for (int k0 = 0; k0 < TD; k0 += KC) {
        stageA(As, A, TD, mrem, TD, k0, tid);
        stageB64(Bs, Bw, TD, k0, tid);
        __syncthreads();
        mac64(As, Bs, tid >> 4, tid & 15, acc);
        __syncthreads();
    }
    int tr = tid >> 4, tc = tid & 15;
    int nb = n0 + tc * 4;
    f4 b4 = *(const f4*)&bemb[nb];
    #pragma unroll
    for (int i = 0; i < 4; ++i) {
        int row = tr * 4 + i;
        if (row < mrem) {
            int grow = m0 + row;
            int t = grow >> 1;
            f4 o = acc[i] + b4;
            #pragma unroll
            for (int u = 0; u < 4; ++u) {
                int n = nb + u;
                float freq = expf((float)(n & ~1) * (-9.2103403719761836f / 3072.0f));
                float ang = (float)t * freq;
                o[u] += (n & 1) ? cosf(ang) : sinf(ang);
            }
            size_t off = (size_t)grow * TEMB + nb;
            *(f4*)&x0[off] = o;
            *(f4*)&r0[off] = o;
            s4 ob = { f2bf(o[0]), f2bf(o[1]), f2bf(o[2]), f2bf(o[3]) };
            *(s4*)&x0bf[off] = ob;
            *(s4*)&r0bf[off] = ob;
        }
    }
}

// ---------------- final projection + residual ----------------
__global__ void final_kernel(const float* __restrict__ r4, const float* __restrict__ Wout,
                             const float* __restrict__ bout, const float* __restrict__ src,
                             const float* __restrict__ tgt, float* __restrict__ out) {
    int idx = blockIdx.x * 256 + threadIdx.x;
    if (idx >= TB * TW * TD) return;
    int d = idx % TD;
    int t = (idx / TD) % TW;
    int b = idx / (TD * TW);
    int j = d / 9, o = d % 9;
    const float* rr = r4 + (size_t)((t * TB + b) * TJ + j) * TH;
    const float* wt = Wout + (size_t)o * TH;
    float acc = bout[o];
    #pragma unroll 4
    for (int h = 0; h < TH; ++h) acc += rr[h] * wt[h];
    float cv = (t < 60) ? src[((size_t)b * 60 + t) * TD + d]
                        : tgt[((size_t)b * 61 + (t - 60)) * TD + d];
    out[idx] = acc + cv;
}

extern "C" void kernel_launch(void* const* d_in, const int* in_sizes, int n_in,
                              void* d_out, int out_size, void* d_ws, size_t ws_size,
                              hipStream_t stream) {
    const float* src    = (const float*)d_in[0];
    const float* tgt    = (const float*)d_in[1];
    const float* Wemb   = (const float*)d_in[2];
    const float* bemb   = (const float*)d_in[3];
    const float* Wqkv_s = (const float*)d_in[4];
    const float* bqkv_s = (const float*)d_in[5];
    const float* Wo_s   = (const float*)d_in[6];
    const float* bo_s   = (const float*)d_in[7];
    const float* sn_g   = (const float*)d_in[8];
    const float* sn_b   = (const float*)d_in[9];
    const float* Wqkv_t = (const float*)d_in[10];
    const float* bqkv_t = (const float*)d_in[11];
    const float* Wo_t   = (const float*)d_in[12];
    const float* bo_t   = (const float*)d_in[13];
    const float* tn_g   = (const float*)d_in[14];
    const float* tn_b   = (const float*)d_in[15];
    const float* W1     = (const float*)d_in[16];
    const float* b1     = (const float*)d_in[17];
    const float* W2     = (const float*)d_in[18];
    const float* b2     = (const float*)d_in[19];
    const float* Wout   = (const float*)d_in[20];
    const float* bout   = (const float*)d_in[21];
    float* out = (float*)d_out;

    const size_t RH = (size_t)TROWS * TH;   // 737280
    float* f = (float*)d_ws;
    float* cbuf  = f;                    // 51840
    float* x0    = cbuf + 51840;
    float* Kbase = x0 + RH;              // 4*RH
    float* Vbase = Kbase + 4 * RH;       // 4*RH
    float* r     = Vbase + 4 * RH;
    float* Qp2   = r + RH;
    float* Qs    = Qp2 + RH;
    float* Ks    = Qs + RH;
    float* Vs    = Ks + RH;
    float* Qt    = Vs + RH;
    float* Kt    = Qt + RH;
    float* Vt    = Kt + RH;
    float* spout = Vt + RH;
    float* Bb0   = spout + RH;
    float* Bb1   = Bb0 + RH;
    short* sbase   = (short*)(Bb1 + RH);
    short* x0bf    = sbase;
    short* rbf     = x0bf + RH;
    short* attnb_c = rbf + RH;
    short* attnb_s = attnb_c + RH;
    short* attnb_t = attnb_s + RH;
    short* yball   = attnb_t + RH;       // 2*RH (part2 lower, part3 upper)
    short* fball   = yball + 2 * RH;     // 2*TROWS*TF
    short* Bb0bf   = fball + 2 * (size_t)TROWS * TF;
    short* Bb1bf   = Bb0bf + RH;
    short* wbf     = Bb1bf + RH;         // NW_TOT shorts

    const short* wqkvs_bf = wbf;
    const short* wos_bf   = wbf + OFF_O_S;
    const short* wqkvt_bf = wbf + OFF_QKV_T;
    const short* wot_bf   = wbf + OFF_O_T;
    const short* w1bf     = wbf + OFF_W1;
    const short* w2bf     = wbf + OFF_W2;

    // 0. weights -> bf16 + gather concat (fused)
    convgather_kernel<<<NB_CONV + NB_GATH, 256, 0, stream>>>(
        Wqkv_s, Wo_s, Wqkv_t, Wo_t, W1, W2, wbf, src, tgt, cbuf);

    // 1. embedding GEMM (+PE); writes x0/x0bf and r/rbf
    gemm_embed_kernel<<<dim3(4, 48), 256, 0, stream>>>(cbuf, Wemb, bemb, x0, x0bf, r, rbf);

    // 2+3. per-layer mega launches
    const float* Binf = x0;
    const short* Binbf = x0bf;
    for (int l = 0; l < 4; ++l) {
        int p2n = (l < 3) ? 6 : 4;
        int n0base = (l < 3) ? 0 : 128;
        int ncausal = (l < 3) ? 768 : 0;
        int np2 = (l < 3) ? 360 : 0;
        const short* wt_l = wqkvt_bf + (size_t)l * TJ * 3 * TH * TH;
        const short* ws_l = wqkvs_bf + (size_t)l * 3 * TH * TH;
        const float* bt_l = bqkv_t + (size_t)l * TJ * 3 * TH;
        const float* bs_l = bqkv_s + (size_t)l * 3 * TH;

        mfma_qkvmega_kernel<<<dim3(4, p2n + 12, 24), 256, 0, stream>>>(
            Binbf, rbf, wt_l, ws_l, bt_l, bs_l,
            Qp2, Kbase + l * RH, Vbase + l * RH,
            Qs, Ks, Vs, Qt, Kt, Vt, p2n, n0base);

        attn_mega_kernel<<<240 + ncausal + 768, 512, 0, stream>>>(
            Qp2, Kbase + l * RH, Vbase + l * RH,
            Qs, Ks, Vs, Qt, Kt, Vt,
            attnb_c, attnb_s, attnb_t, ncausal);

        mfma_olnmega_kernel<<<np2 + 360, 256, 0, stream>>>(
            attnb_c, wot_bf + (size_t)l * TJ * TH * TH, bo_t + (size_t)l * TJ * TH,
            Binf, tn_g + l * TH, tn_b + l * TH, yball,
            attnb_s, wos_bf + (size_t)l * TH * TH, bo_s + (size_t)l * TH,
            r, sn_g + l * TH, sn_b + l * TH, spout, np2);

        mfma_oln_kernel<<<360, 256, 0, stream>>>(
            attnb_t, wot_bf + (size_t)l * TJ * TH * TH, bo_t + (size_t)l * TJ * TH,
            r, tn_g + l * TH, tn_b + l * TH, spout, nullptr, yball + RH, 1);

        if (l < 3) {
            mfma_ffn1_kernel<<<dim3(180, 4), 256, 0, stream>>>(
                yball, w1bf + (size_t)l * TF * TH, b1 + l * TF, fball);
            float* Boutf = (l & 1) ? Bb1 : Bb0;
            short* Boutbf = (l & 1) ? Bb1bf : Bb0bf;
            mfma_ffn2_kernel<<<dim3(180, 2), 256, 0, stream>>>(
                fball, w2bf + (size_t)l * TH * TF, b2 + l * TH,
                Boutf, Boutbf, r, rbf, TROWS);
            Binf = Boutf; Binbf = Boutbf;
        } else {
            mfma_ffn1_kernel<<<dim3(90, 4), 256, 0, stream>>>(
                yball + RH, w1bf + (size_t)l * TF * TH, b1 + l * TF, fball);
            mfma_ffn2_kernel<<<dim3(90, 2), 256, 0, stream>>>(
                fball, w2bf + (size_t)l * TH * TF, b2 + l * TH,
                r, rbf, r, rbf, 0);
        }
    }

    // 4. output projection + residual
    final_kernel<<<(TB * TW * TD + 255) / 256, 256, 0, stream>>>(r, Wout, bout, src, tgt, out);
}

// Round 11
// 354.469 us; speedup vs baseline: 18.3753x; 1.0479x over previous
//
#include <hip/hip_runtime.h>

// Sizes
#define TW 120
#define TB 2
#define TJ 24
#define TH 128
#define TNH 8
#define THD 16
#define TF 256
#define TD 216
#define TROWS (TW*TB*TJ)   // 5760
#define TEMB (TJ*TH)       // 3072
#define TBF 240

#define KC 32
#define LDA 68
#define APAD 20    // attention LDS row pad (floats): 16B-aligned
#define QCH 60
#define LDT 136    // bf16 MFMA LDS row stride (shorts)
#define SPAD (TH + 4)

typedef float f4 __attribute__((ext_vector_type(4)));
typedef short bf8 __attribute__((ext_vector_type(8)));
typedef short s4 __attribute__((ext_vector_type(4)));

__device__ __forceinline__ short f2bf(float x) {
    union { float f; unsigned u; } v; v.f = x;
    unsigned r = (v.u + 0x7FFFu + ((v.u >> 16) & 1u)) >> 16;
    return (short)r;
}

__device__ __forceinline__ f4 shfl_xor_f4(f4 v, int o) {
    f4 r;
    r[0] = __shfl_xor(v[0], o); r[1] = __shfl_xor(v[1], o);
    r[2] = __shfl_xor(v[2], o); r[3] = __shfl_xor(v[3], o);
    return r;
}

// ---------------- weight conversion + gather (fused) ----------------
#define NW_QKV_S 196608
#define NW_O_S    65536
#define NW_QKV_T 4718592
#define NW_O_T   1572864
#define NW_1      131072
#define NW_2      131072
#define OFF_O_S   (NW_QKV_S)
#define OFF_QKV_T (OFF_O_S + NW_O_S)
#define OFF_O_T   (OFF_QKV_T + NW_QKV_T)
#define OFF_W1    (OFF_O_T + NW_O_T)
#define OFF_W2    (OFF_W1 + NW_1)
#define NW_TOT    (OFF_W2 + NW_2)      // 6815744
#define NB_CONV   (NW_TOT / 4 / 256)   // 6656 exact
#define NB_GATH   ((TBF*TD + 255) / 256)

__global__ void convgather_kernel(const float* __restrict__ Wqkv_s, const float* __restrict__ Wo_s,
                                  const float* __restrict__ Wqkv_t, const float* __restrict__ Wo_t,
                                  const float* __restrict__ W1, const float* __restrict__ W2,
                                  short* __restrict__ dst,
                                  const float* __restrict__ src, const float* __restrict__ tgt,
                                  float* __restrict__ cbuf) {
    if (blockIdx.x < NB_CONV) {
        size_t i = ((size_t)blockIdx.x * 256 + threadIdx.x) * 4;
        const float* s; size_t off;
        if (i < NW_QKV_S)       { s = Wqkv_s; off = i; }
        else if (i < OFF_QKV_T) { s = Wo_s;   off = i - OFF_O_S; }
        else if (i < OFF_O_T)   { s = Wqkv_t; off = i - OFF_QKV_T; }
        else if (i < OFF_W1)    { s = Wo_t;   off = i - OFF_O_T; }
        else if (i < OFF_W2)    { s = W1;     off = i - OFF_W1; }
        else                    { s = W2;     off = i - OFF_W2; }
        f4 v = *(const f4*)(s + off);
        s4 o = { f2bf(v[0]), f2bf(v[1]), f2bf(v[2]), f2bf(v[3]) };
        *(s4*)(dst + i) = o;
    } else {
        int idx = (blockIdx.x - NB_CONV) * 256 + threadIdx.x;
        if (idx >= TBF * TD) return;
        int d = idx % TD;
        int row = idx / TD;
        int b = row & 1, t = row >> 1;
        cbuf[idx] = (t < 60) ? src[((size_t)b * 60 + t) * TD + d]
                             : tgt[((size_t)b * 61 + (t - 60)) * TD + d];
    }
}

// ---------------- MFMA building blocks ----------------
__device__ __forceinline__ void stage_bf(short* Ds, const short* __restrict__ src,
                                         size_t rstride, int nrows, int tid) {
    int r = tid >> 2, s = (tid & 3) * 32;
    short* d = Ds + r * LDT + s;
    if (r < nrows) {
        const short* p = src + (size_t)r * rstride + s;
        *(bf8*)(d)      = *(const bf8*)(p);
        *(bf8*)(d + 8)  = *(const bf8*)(p + 8);
        *(bf8*)(d + 16) = *(const bf8*)(p + 16);
        *(bf8*)(d + 24) = *(const bf8*)(p + 24);
    } else {
        bf8 z = {0,0,0,0,0,0,0,0};
        *(bf8*)(d) = z; *(bf8*)(d+8) = z; *(bf8*)(d+16) = z; *(bf8*)(d+24) = z;
    }
}

__device__ __forceinline__ void mfma_tile64(const short* As, const short* Bs,
                                            int wave, int lane, f4 acc[2][2]) {
    int wm = wave >> 1, wn = wave & 1;
    int lrow = lane & 15, lk = (lane >> 4) * 8;
    #pragma unroll
    for (int ks = 0; ks < 4; ++ks) {
        bf8 a0 = *(const bf8*)&As[(wm*32      + lrow) * LDT + ks*32 + lk];
        bf8 a1 = *(const bf8*)&As[(wm*32 + 16 + lrow) * LDT + ks*32 + lk];
        bf8 b0 = *(const bf8*)&Bs[(wn*32      + lrow) * LDT + ks*32 + lk];
        bf8 b1 = *(const bf8*)&Bs[(wn*32 + 16 + lrow) * LDT + ks*32 + lk];
        acc[0][0] = __builtin_amdgcn_mfma_f32_16x16x32_bf16(a0, b0, acc[0][0], 0, 0, 0);
        acc[0][1] = __builtin_amdgcn_mfma_f32_16x16x32_bf16(a0, b1, acc[0][1], 0, 0, 0);
        acc[1][0] = __builtin_amdgcn_mfma_f32_16x16x32_bf16(a1, b0, acc[1][0], 0, 0, 0);
        acc[1][1] = __builtin_amdgcn_mfma_f32_16x16x32_bf16(a1, b1, acc[1][1], 0, 0, 0);
    }
}

// ---------------- mega QKV ----------------
__global__ __launch_bounds__(256) void mfma_qkvmega_kernel(
        const short* __restrict__ A2, const short* __restrict__ A3,
        const short* __restrict__ Wt, const short* __restrict__ Ws,
        const float* __restrict__ bt, const float* __restrict__ bs,
        float* __restrict__ Qp2, float* __restrict__ Kb2, float* __restrict__ Vb2,
        float* __restrict__ Qs_, float* __restrict__ Ks_, float* __restrict__ Vs_,
        float* __restrict__ Qt_, float* __restrict__ Kt_, float* __restrict__ Vt_,
        int p2n, int n0base) {
    __shared__ short As[64 * LDT], Bs[64 * LDT];
    int tid = threadIdx.x;
    int m0 = blockIdx.x * 64, j = blockIdx.z, yy = blockIdx.y;
    int mrem = TBF - m0; if (mrem > 64) mrem = 64;
    const short* Abf; const short* Wbf; const float* bias; int bofs, n0;
    float *dq, *dk, *dv;
    if (yy < p2n) {
        n0 = n0base + yy * 64;
        Abf = A2;
        Wbf = Wt + (size_t)j * 3 * TH * TH + (size_t)n0 * TH;
        bias = bt; bofs = j * 3 * TH;
        dq = Qp2; dk = Kb2; dv = Vb2;
    } else {
        int y2 = yy - p2n;
        int tmp = (y2 >= 6);
        n0 = (tmp ? y2 - 6 : y2) * 64;
        Abf = A3;
        if (tmp) { Wbf = Wt + (size_t)j * 3 * TH * TH + (size_t)n0 * TH; bias = bt; bofs = j * 3 * TH;
                   dq = Qt_; dk = Kt_; dv = Vt_; }
        else     { Wbf = Ws + (size_t)n0 * TH; bias = bs; bofs = 0;
                   dq = Qs_; dk = Ks_; dv = Vs_; }
    }
    stage_bf(As, Abf + (size_t)m0 * TEMB + j * TH, TEMB, mrem, tid);
    stage_bf(Bs, Wbf, TH, 64, tid);
    __syncthreads();
    int wave = tid >> 6, lane = tid & 63;
    f4 acc[2][2] = {{{0,0,0,0},{0,0,0,0}},{{0,0,0,0},{0,0,0,0}}};
    mfma_tile64(As, Bs, wave, lane, acc);
    int wm = wave >> 1, wn = wave & 1, lrow = lane & 15, gr = (lane >> 4) * 4;
    float* dst = (n0 < TH) ? dq : ((n0 < 2 * TH) ? dk : dv);
    int cb = n0 & (TH - 1);
    #pragma unroll
    for (int ni = 0; ni < 2; ++ni) {
        float bv = bias[bofs + n0 + wn*32 + ni*16 + lrow];
        int col = cb + wn*32 + ni*16 + lrow;
        #pragma unroll
        for (int mi = 0; mi < 2; ++mi)
            #pragma unroll
            for (int rg = 0; rg < 4; ++rg) {
                int tr = wm*32 + mi*16 + gr + rg;
                if (tr < mrem)
                    dst[(size_t)((m0 + tr) * TJ + j) * TH + col] = acc[mi][ni][rg] + bv;
            }
    }
}

// ---------------- mega attention: spatial (240) + causal (ncausal) + special (768)
__global__ __launch_bounds__(512) void attn_mega_kernel(
        const float* __restrict__ Qc_g, const float* __restrict__ Kc_g, const float* __restrict__ Vc_g,
        const float* __restrict__ Qs_g, const float* __restrict__ Ks_g, const float* __restrict__ Vs_g,
        const float* __restrict__ Qt_g, const float* __restrict__ Kt_g, const float* __restrict__ Vt_g,
        short* __restrict__ Oc, short* __restrict__ Os, short* __restrict__ Ot,
        int ncausal) {
    __shared__ __align__(16) float smem[9504];
    int bx = blockIdx.x;
    int tid = threadIdx.x;

    if (bx < 240) {
        // ---- spatial ----
        float* Qs = smem;
        float* Ks = smem + TJ * SPAD;
        float* Vs = smem + 2 * TJ * SPAD;
        int b = bx & 1, t = bx >> 1;
        int base = (t * TB + b) * TJ;
        for (int i = tid; i < TJ * 32; i += 512) {
            int rr = i >> 5, c4 = i & 31;
            ((f4*)(Qs + rr * SPAD))[c4] = ((const f4*)(Qs_g + (size_t)(base + rr) * TH))[c4];
            ((f4*)(Ks + rr * SPAD))[c4] = ((const f4*)(Ks_g + (size_t)(base + rr) * TH))[c4];
            ((f4*)(Vs + rr * SPAD))[c4] = ((const f4*)(Vs_g + (size_t)(base + rr) * TH))[c4];
        }
        __syncthreads();
        if (tid >= 192) return;
        int qj = tid % TJ;
        int head = tid / TJ;
        int hb = head * THD;
        float qv[THD];
        #pragma unroll
        for (int u = 0; u < THD; ++u) qv[u] = Qs[qj * SPAD + hb + u];
        float sc[TJ];
        float m = -1e30f;
        #pragma unroll
        for (int k = 0; k < TJ; ++k) {
            float a = 0.f;
            #pragma unroll
            for (int u = 0; u < THD; ++u) a += qv[u] * Ks[k * SPAD + hb + u];
            sc[k] = a * 0.25f;
            m = fmaxf(m, sc[k]);
        }
        float sum = 0.f;
        #pragma unroll
        for (int k = 0; k < TJ; ++k) { sc[k] = __expf(sc[k] - m); sum += sc[k]; }
        float inv = 1.0f / sum;
        float o[THD];
        #pragma unroll
        for (int u = 0; u < THD; ++u) o[u] = 0.f;
        #pragma unroll
        for (int k = 0; k < TJ; ++k) {
            #pragma unroll
            for (int u = 0; u < THD; ++u) o[u] += sc[k] * Vs[k * SPAD + hb + u];
        }
        size_t off = (size_t)(base + qj) * TH + hb;
        #pragma unroll
        for (int u = 0; u < THD; ++u) Os[off + u] = f2bf(o[u] * inv);
        return;
    }

    int cx = bx - 240;
    int wave = tid >> 6, lane = tid & 63;
    int sd = tid & 15, sr = tid >> 4;
    int dq = lane & 3, ch = lane >> 2;

    if (cx < ncausal) {
        // ---- causal (part 2) ----
        float* Qc = smem;
        float* Kc = Qc + QCH * APAD;
        float* Vc = Kc + TW * APAD;
        float* Ps = Vc + TW * APAD;
        int bhj = cx % 384, chunk = cx / 384;
        int head = bhj & 7;
        int j = (bhj >> 3) % TJ;
        int b = (bhj >> 3) / TJ;
        int qlo = chunk * QCH, qhi = qlo + QCH;
        for (int rr = sr; rr < qhi; rr += 32) {
            size_t off = (size_t)((rr * TB + b) * TJ + j) * TH + head * THD + sd;
            Kc[rr * APAD + sd] = Kc_g[off]; Vc[rr * APAD + sd] = Vc_g[off];
            if (rr >= qlo) Qc[(rr - qlo) * APAD + sd] = Qc_g[off];
        }
        __syncthreads();
        for (int q = qlo + wave; q < qhi; q += 8) {
            const float* qr = Qc + (q - qlo) * APAD;
            f4 qa = *(const f4*)(qr), qb = *(const f4*)(qr + 4);
            f4 qc = *(const f4*)(qr + 8), qd = *(const f4*)(qr + 12);
            int k0 = lane, k1 = lane + 64;
            float s0 = -1e30f, s1 = -1e30f;
            if (k0 <= q) {
                const float* kr = Kc + k0 * APAD;
                f4 d = qa * *(const f4*)(kr) + qb * *(const f4*)(kr + 4)
                     + qc * *(const f4*)(kr + 8) + qd * *(const f4*)(kr + 12);
                s0 = (d[0] + d[1] + d[2] + d[3]) * 0.25f;
            }
            if (k1 <= q) {
                const float* kr = Kc + k1 * APAD;
                f4 d = qa * *(const f4*)(kr) + qb * *(const f4*)(kr + 4)
                     + qc * *(const f4*)(kr + 8) + qd * *(const f4*)(kr + 12);
                s1 = (d[0] + d[1] + d[2] + d[3]) * 0.25f;
            }
            float m = fmaxf(s0, s1);
            #pragma unroll
            for (int o = 32; o > 0; o >>= 1) m = fmaxf(m, __shfl_xor(m, o));
            float p0 = (k0 <= q) ? __expf(s0 - m) : 0.f;
            float p1 = (k1 <= q) ? __expf(s1 - m) : 0.f;
            float sum = p0 + p1;
            #pragma unroll
            for (int o = 32; o > 0; o >>= 1) sum += __shfl_xor(sum, o);
            float inv = 1.0f / sum;
            Ps[wave * TW + k0] = p0;
            if (k1 < TW) Ps[wave * TW + k1] = p1;
            // intra-wave LDS RAW: in-order DS pipe
            f4 acc = {0.f, 0.f, 0.f, 0.f};
            for (int k = ch; k <= q; k += 16)
                acc += Ps[wave * TW + k] * *(const f4*)(Vc + k * APAD + dq * 4);
            #pragma unroll
            for (int o = 4; o < 64; o <<= 1) acc += shfl_xor_f4(acc, o);
            if (ch == 0) {
                size_t off = (size_t)((q * TB + b) * TJ + j) * TH + head * THD + dq * 4;
                s4 ov = { f2bf(acc[0] * inv), f2bf(acc[1] * inv),
                          f2bf(acc[2] * inv), f2bf(acc[3] * inv) };
                *(s4*)(Oc + off) = ov;
            }
        }
        return;
    }

    // ---- special (part 3) ----
    int sx = cx - ncausal;
    float* Qsp = smem;
    float* Ksp = Qsp + QCH * APAD;
    float* Vsp = Ksp + QCH * APAD;
    float* Kb  = Vsp + QCH * APAD;
    float* Vb  = Kb + TW * APAD;
    float* Ps  = Vb + TW * APAD;
    int bhj = sx % 384, chunk = sx / 384;
    int head = bhj & 7;
    int j = (bhj >> 3) % TJ;
    int b = (bhj >> 3) / TJ;
    int qlo = chunk * QCH, qhi = qlo + QCH;
    for (int rr = sr; rr < qhi; rr += 32) {
        size_t off = (size_t)((rr * TB + b) * TJ + j) * TH + head * THD + sd;
        Kb[rr * APAD + sd] = Kc_g[off]; Vb[rr * APAD + sd] = Vc_g[off];
        if (rr >= qlo) {
            Qsp[(rr - qlo) * APAD + sd] = Qt_g[off];
            Ksp[(rr - qlo) * APAD + sd] = Kt_g[off];
            Vsp[(rr - qlo) * APAD + sd] = Vt_g[off];
        }
    }
    __syncthreads();
    for (int t = qlo + wave; t < qhi; t += 8) {
        const float* qr = Qsp + (t - qlo) * APAD;
        f4 qa = *(const f4*)(qr), qb = *(const f4*)(qr + 4);
        f4 qc = *(const f4*)(qr + 8), qd = *(const f4*)(qr + 12);
        int k0 = lane, k1 = lane + 64;
        float s0 = -1e30f, s1 = -1e30f;
        if (k0 <= t) {
            const float* kr = (k0 == t) ? (Ksp + (t - qlo) * APAD) : (Kb + k0 * APAD);
            f4 d = qa * *(const f4*)(kr) + qb * *(const f4*)(kr + 4)
                 + qc * *(const f4*)(kr + 8) + qd * *(const f4*)(kr + 12);
            s0 = (d[0] + d[1] + d[2] + d[3]) * 0.25f;
        }
        if (k1 <= t) {
            const float* kr = (k1 == t) ? (Ksp + (t - qlo) * APAD) : (Kb + k1 * APAD);
            f4 d = qa * *(const f4*)(kr) + qb * *(const f4*)(kr + 4)
                 + qc * *(const f4*)(kr + 8) + qd * *(const f4*)(kr + 12);
            s1 = (d[0] + d[1] + d[2] + d[3]) * 0.25f;
        }
        float m = fmaxf(s0, s1);
        #pragma unroll
        for (int o = 32; o > 0; o >>= 1) m = fmaxf(m, __shfl_xor(m, o));
        float p0 = (k0 <= t) ? __expf(s0 - m) : 0.f;
        float p1 = (k1 <= t) ? __expf(s1 - m) : 0.f;
        float sum = p0 + p1;
        #pragma unroll
        for (int o = 32; o > 0; o >>= 1) sum += __shfl_xor(sum, o);
        float inv = 1.0f / sum;
        Ps[wave * TW + k0] = p0;
        if (k1 < TW) Ps[wave * TW + k1] = p1;
        f4 acc = {0.f, 0.f, 0.f, 0.f};
        for (int k = ch; k < t; k += 16)
            acc += Ps[wave * TW + k] * *(const f4*)(Vb + k * APAD + dq * 4);
        if ((t & 15) == ch)
            acc += Ps[wave * TW + t] * *(const f4*)(Vsp + (t - qlo) * APAD + dq * 4);
        #pragma unroll
        for (int o = 4; o < 64; o <<= 1) acc += shfl_xor_f4(acc, o);
        if (ch == 0) {
            size_t off = (size_t)((t * TB + b) * TJ + j) * TH + head * THD + dq * 4;
            s4 ov = { f2bf(acc[0] * inv), f2bf(acc[1] * inv),
                      f2bf(acc[2] * inv), f2bf(acc[3] * inv) };
            *(s4*)(Ot + off) = ov;
        }
    }
}

// ---------------- OLN compute core (returns normalized rows in registers) -----
__device__ __forceinline__ void oln_compute(
        const short* __restrict__ Abf, const short* __restrict__ Wbf,
        const float* __restrict__ bias, const float* __restrict__ resid,
        const float* __restrict__ g, const float* __restrict__ bln,
        int perJoint, int m0, int j,
        short* As, short* Bs, float* rsum, float* rsq, float* lnm, float* lnr,
        float o0[4], float o1[4]) {
    int tid = threadIdx.x;
    { int r = tid >> 4, s = (tid & 15) * 8;
      *(bf8*)&As[r * LDT + s] = *(const bf8*)(Abf + (size_t)(m0 + r) * TEMB + j * TH + s); }
    { int r = tid >> 1, s = (tid & 1) * 64;
      const short* p = Wbf + (perJoint ? (size_t)j * TH * TH : 0) + (size_t)r * TH + s;
      short* d = &Bs[r * LDT + s];
      #pragma unroll
      for (int cc = 0; cc < 64; cc += 8) *(bf8*)(d + cc) = *(const bf8*)(p + cc); }
    __syncthreads();
    int wave = tid >> 6, lane = tid & 63, lrow = lane & 15, lk = (lane >> 4) * 8, gr = (lane >> 4) * 4;
    f4 acc[2] = {{0,0,0,0},{0,0,0,0}};
    #pragma unroll
    for (int ks = 0; ks < 4; ++ks) {
        bf8 a  = *(const bf8*)&As[lrow * LDT + ks*32 + lk];
        bf8 b0 = *(const bf8*)&Bs[(wave*32      + lrow) * LDT + ks*32 + lk];
        bf8 b1 = *(const bf8*)&Bs[(wave*32 + 16 + lrow) * LDT + ks*32 + lk];
        acc[0] = __builtin_amdgcn_mfma_f32_16x16x32_bf16(a, b0, acc[0], 0, 0, 0);
        acc[1] = __builtin_amdgcn_mfma_f32_16x16x32_bf16(a, b1, acc[1], 0, 0, 0);
    }
    int col0 = wave*32 + lrow, col1 = col0 + 16;
    int bofs = perJoint ? j * TH : 0;
    float bv0 = bias[bofs + col0], bv1 = bias[bofs + col1];
    float v0[4], v1[4], sr_[4], sq_[4];
    #pragma unroll
    for (int rg = 0; rg < 4; ++rg) {
        size_t ro = (size_t)(m0 + gr + rg) * TEMB + j * TH;
        v0[rg] = acc[0][rg] + bv0 + resid[ro + col0];
        v1[rg] = acc[1][rg] + bv1 + resid[ro + col1];
        sr_[rg] = v0[rg] + v1[rg];
        sq_[rg] = v0[rg]*v0[rg] + v1[rg]*v1[rg];
    }
    #pragma unroll
    for (int o = 1; o < 16; o <<= 1) {
        #pragma unroll
        for (int rg = 0; rg < 4; ++rg) { sr_[rg] += __shfl_xor(sr_[rg], o); sq_[rg] += __shfl_xor(sq_[rg], o); }
    }
    if (lrow == 0) {
        #pragma unroll
        for (int rg = 0; rg < 4; ++rg) { rsum[wave*16 + gr + rg] = sr_[rg]; rsq[wave*16 + gr + rg] = sq_[rg]; }
    }
    __syncthreads();
    if (tid < 16) {
        float s = rsum[tid] + rsum[16 + tid] + rsum[32 + tid] + rsum[48 + tid];
        float q = rsq[tid] + rsq[16 + tid] + rsq[32 + tid] + rsq[48 + tid];
        float mean = s * (1.0f / TH);
        float var = q * (1.0f / TH) - mean * mean;
        lnm[tid] = mean; lnr[tid] = rsqrtf(var + 1e-5f);
    }
    __syncthreads();
    float g0 = g[col0], g1 = g[col1], l0 = bln[col0], l1 = bln[col1];
    #pragma unroll
    for (int rg = 0; rg < 4; ++rg) {
        int row = gr + rg;
        float mean = lnm[row], rs = lnr[row];
        o0[rg] = (v0[rg] - mean) * rs * g0 + l0;
        o1[rg] = (v1[rg] - mean) * rs * g1 + l1;
    }
}

// fused OLN: part2-temporal (np2 blocks) + part3 spatial+temporal (360 blocks)
__global__ __launch_bounds__(256) void mfma_olnfused_kernel(
        const short* __restrict__ A2, const short* __restrict__ Wt,
        const float* __restrict__ bt, const float* __restrict__ res2,
        const float* __restrict__ tg, const float* __restrict__ tl,
        short* __restrict__ Yb2,
        const short* __restrict__ A3s, const short* __restrict__ Ws,
        const float* __restrict__ bs, const short* __restrict__ A3t,
        const float* __restrict__ res3,
        const float* __restrict__ sg, const float* __restrict__ sl,
        short* __restrict__ Yb3, int np2) {
    __shared__ short As[16 * LDT];
    __shared__ short Bs[128 * LDT];
    __shared__ float rsum[64], rsq[64], lnm[16], lnr[16];
    int bx = blockIdx.x;
    int tid = threadIdx.x;
    int wave = tid >> 6, lane = tid & 63, lrow = lane & 15, gr = (lane >> 4) * 4;
    int col0 = wave*32 + lrow, col1 = col0 + 16;
    if (bx < np2) {
        int m0 = (bx % 15) * 16, j = bx / 15;
        float o0[4], o1[4];
        oln_compute(A2, Wt, bt, res2, tg, tl, 1, m0, j,
                    As, Bs, rsum, rsq, lnm, lnr, o0, o1);
        #pragma unroll
        for (int rg = 0; rg < 4; ++rg) {
            size_t ro = (size_t)(m0 + gr + rg) * TEMB + j * TH;
            Yb2[ro + col0] = f2bf(o0[rg]);
            Yb2[ro + col1] = f2bf(o1[rg]);
        }
    } else {
        int idx = bx - np2;
        int m0 = (idx % 15) * 16, j = idx / 15;
        float s0[4], s1[4], t0[4], t1[4];
        oln_compute(A3s, Ws, bs, res3, sg, sl, 0, m0, j,
                    As, Bs, rsum, rsq, lnm, lnr, s0, s1);
        __syncthreads();
        oln_compute(A3t, Wt, bt, res3, tg, tl, 1, m0, j,
                    As, Bs, rsum, rsq, lnm, lnr, t0, t1);
        #pragma unroll
        for (int rg = 0; rg < 4; ++rg) {
            size_t ro = (size_t)(m0 + gr + rg) * TEMB + j * TH;
            Yb3[ro + col0] = f2bf(t0[rg] + s0[rg]);
            Yb3[ro + col1] = f2bf(t1[rg] + s1[rg]);
        }
    }
}

// ---------------- FFN MFMA GEMMs ----------------
__global__ __launch_bounds__(256) void mfma_ffn1_kernel(
        const short* __restrict__ Ybf, const short* __restrict__ W1bf,
        const float* __restrict__ b1, short* __restrict__ Fb) {
    __shared__ short As[64 * LDT], Bs[64 * LDT];
    int tid = threadIdx.x;
    int m0 = blockIdx.x * 64, n0 = blockIdx.y * 64;
    stage_bf(As, Ybf + (size_t)m0 * TH, TH, 64, tid);
    stage_bf(Bs, W1bf + (size_t)n0 * TH, TH, 64, tid);
    __syncthreads();
    int wave = tid >> 6, lane = tid & 63;
    f4 acc[2][2] = {{{0,0,0,0},{0,0,0,0}},{{0,0,0,0},{0,0,0,0}}};
    mfma_tile64(As, Bs, wave, lane, acc);
    int wm = wave >> 1, wn = wave & 1, lrow = lane & 15, gr = (lane >> 4) * 4;
    #pragma unroll
    for (int ni = 0; ni < 2; ++ni) {
        int col = n0 + wn*32 + ni*16 + lrow;
        float bv = b1[col];
        #pragma unroll
        for (int mi = 0; mi < 2; ++mi)
            #pragma unroll
            for (int rg = 0; rg < 4; ++rg) {
                int tr = wm*32 + mi*16 + gr + rg;
                float v = 2.0f * fmaxf(acc[mi][ni][rg] + bv, 0.0f);
                Fb[(size_t)(m0 + tr) * TF + col] = f2bf(v);
            }
    }
}

// rows < splitrow -> OutA (f32+bf16); rows >= splitrow -> OutB[row-splitrow]
__global__ __launch_bounds__(256) void mfma_ffn2_kernel(
        const short* __restrict__ Fb, const short* __restrict__ W2bf,
        const float* __restrict__ b2, float* __restrict__ OutAf,
        short* __restrict__ OutAbf, float* __restrict__ OutBf,
        short* __restrict__ OutBbf, int splitrow) {
    __shared__ short As[64 * LDT], Bs[64 * LDT];
    int tid = threadIdx.x;
    int m0 = blockIdx.x * 64, n0 = blockIdx.y * 64;
    int wave = tid >> 6, lane = tid & 63;
    f4 acc[2][2] = {{{0,0,0,0},{0,0,0,0}},{{0,0,0,0},{0,0,0,0}}};
    #pragma unroll
    for (int kk = 0; kk < 2; ++kk) {
        stage_bf(As, Fb + (size_t)m0 * TF + kk * 128, TF, 64, tid);
        stage_bf(Bs, W2bf + (size_t)n0 * TF + kk * 128, TF, 64, tid);
        __syncthreads();
        mfma_tile64(As, Bs, wave, lane, acc);
        __syncthreads();
    }
    int wm = wave >> 1, wn = wave & 1, lrow = lane & 15, gr = (lane >> 4) * 4;
    #pragma unroll
    for (int ni = 0; ni < 2; ++ni) {
        int col = n0 + wn*32 + ni*16 + lrow;
        float bv = b2[col];
        #pragma unroll
        for (int mi = 0; mi < 2; ++mi)
            #pragma unroll
            for (int rg = 0; rg < 4; ++rg) {
                int tr = wm*32 + mi*16 + gr + rg;
                int row = m0 + tr;
                float v = acc[mi][ni][rg] + bv;
                if (row < splitrow) {
                    size_t off = (size_t)row * TH + col;
                    OutAf[off] = v; OutAbf[off] = f2bf(v);
                } else {
                    size_t off = (size_t)(row - splitrow) * TH + col;
                    OutBf[off] = v; OutBbf[off] = f2bf(v);
                }
            }
    }
}

// ---------- fp32 GEMM helpers (embed only) ----------
__device__ __forceinline__ void stageA(float* As, const float* __restrict__ A,
                                       int a_stride, int mrem, int K, int k0, int tid) {
    int r = tid >> 2;
    int kk = (tid & 3) << 3;
    bool rowok = r < mrem;
    const float* ap = A + (size_t)r * a_stride + k0 + kk;
    #pragma unroll
    for (int c = 0; c < 8; c += 4) {
        f4 v = {0.f, 0.f, 0.f, 0.f};
        int kg = k0 + kk + c;
        if (rowok) {
            if (kg + 4 <= K) v = *(const f4*)(ap + c);
            else {
                #pragma unroll
                for (int u = 0; u < 4; ++u) if (kg + u < K) v[u] = ap[c + u];
            }
        }
        As[(kk + c + 0) * LDA + r] = v[0];
        As[(kk + c + 1) * LDA + r] = v[1];
        As[(kk + c + 2) * LDA + r] = v[2];
        As[(kk + c + 3) * LDA + r] = v[3];
    }
}

__device__ __forceinline__ void stageB64(float* Bs, const float* __restrict__ Bw,
                                         int K, int k0, int tid) {
    int r = tid >> 2;
    int kk = (tid & 3) << 3;
    const float* bp = Bw + (size_t)r * K + k0 + kk;
    #pragma unroll
    for (int c = 0; c < 8; c += 4) {
        f4 v = {0.f, 0.f, 0.f, 0.f};
        int kg = k0 + kk + c;
        if (kg + 4 <= K) v = *(const f4*)(bp + c);
        else {
            #pragma unroll
            for (int u = 0; u < 4; ++u) if (kg + u < K) v[u] = bp[c + u];
        }
        Bs[(kk + c + 0) * LDA + r] = v[0];
        Bs[(kk + c + 1) * LDA + r] = v[1];
        Bs[(kk + c + 2) * LDA + r] = v[2];
        Bs[(kk + c + 3) * LDA + r] = v[3];
    }
}

__device__ __forceinline__ void mac64(const float* As, const float* Bs, int tr, int tc, f4 acc[4]) {
    #pragma unroll
    for (int kk = 0; kk < KC; ++kk) {
        f4 a = *(const f4*)&As[kk * LDA + tr * 4];
        f4 b = *(const f4*)&Bs[kk * LDA + tc * 4];
        acc[0] += a[0] * b;
        acc[1] += a[1] * b;
        acc[2] += a[2] * b;
        acc[3] += a[3] * b;
    }
}

// ---------------- embedding GEMM + bias + PE (writes x0, x0bf, r, rbf) -------
__global__ __launch_bounds__(256) void gemm_embed_kernel(
        const float* __restrict__ cbuf, const float* __restrict__ Wemb,
        const float* __restrict__ bemb, float* __restrict__ x0,
        short* __restrict__ x0bf, float* __restrict__ r0,
        short* __restrict__ r0bf) {
    __shared__ __align__(16) float As[KC * LDA];
    __shared__ __align__(16) float Bs[KC * LDA];
    int tid = threadIdx.x;
    int m0 = blockIdx.x * 64;
    int n0 = blockIdx.y * 64;
    int mrem = TBF - m0; if (mrem > 64) mrem = 64;
    const float* A = cbuf + (size_t)m0 * TD;
    const float* Bw = Wemb + (size_t)n0 * TD;
    f4 acc[4] = {{0,0,0,0},{0,0,0,0},{0,0,0,0},{0,0,0,0}};
    for (int k0 = 0; k0 < TD; k0 += KC) {
        stageA(As, A, TD, mrem, TD, k0, tid);
        stageB64(Bs, Bw, TD, k0, tid);
        __syncthreads();
        mac64(As, Bs, tid >> 4, tid & 15, acc);
        __syncthreads();
    }
    int tr = tid >> 4, tc = tid & 15;
    int nb = n0 + tc * 4;
    f4 b4 = *(const f4*)&bemb[nb];
    #pragma unroll
    for (int i = 0; i < 4; ++i) {
        int row = tr * 4 + i;
        if (row < mrem) {
            int grow = m0 + row;
            int t = grow >> 1;
            f4 o = acc[i] + b4;
            #pragma unroll
            for (int u = 0; u < 4; ++u) {
                int n = nb + u;
                float freq = expf((float)(n & ~1) * (-9.2103403719761836f / 3072.0f));
                float ang = (float)t * freq;
                o[u] += (n & 1) ? cosf(ang) : sinf(ang);
            }
            size_t off = (size_t)grow * TEMB + nb;
            *(f4*)&x0[off] = o;
            *(f4*)&r0[off] = o;
            s4 ob = { f2bf(o[0]), f2bf(o[1]), f2bf(o[2]), f2bf(o[3]) };
            *(s4*)&x0bf[off] = ob;
            *(s4*)&r0bf[off] = ob;
        }
    }
}

// ---------------- final projection + residual ----------------
__global__ void final_kernel(const float* __restrict__ r4, const float* __restrict__ Wout,
                             const float* __restrict__ bout, const float* __restrict__ src,
                             const float* __restrict__ tgt, float* __restrict__ out) {
    int idx = blockIdx.x * 256 + threadIdx.x;
    if (idx >= TB * TW * TD) return;
    int d = idx % TD;
    int t = (idx / TD) % TW;
    int b = idx / (TD * TW);
    int j = d / 9, o = d % 9;
    const float* rr = r4 + (size_t)((t * TB + b) * TJ + j) * TH;
    const float* wt = Wout + (size_t)o * TH;
    float acc = bout[o];
    #pragma unroll 4
    for (int h = 0; h < TH; ++h) acc += rr[h] * wt[h];
    float cv = (t < 60) ? src[((size_t)b * 60 + t) * TD + d]
                        : tgt[((size_t)b * 61 + (t - 60)) * TD + d];
    out[idx] = acc + cv;
}

extern "C" void kernel_launch(void* const* d_in, const int* in_sizes, int n_in,
                              void* d_out, int out_size, void* d_ws, size_t ws_size,
                              hipStream_t stream) {
    const float* src    = (const float*)d_in[0];
    const float* tgt    = (const float*)d_in[1];
    const float* Wemb   = (const float*)d_in[2];
    const float* bemb   = (const float*)d_in[3];
    const float* Wqkv_s = (const float*)d_in[4];
    const float* bqkv_s = (const float*)d_in[5];
    const float* Wo_s   = (const float*)d_in[6];
    const float* bo_s   = (const float*)d_in[7];
    const float* sn_g   = (const float*)d_in[8];
    const float* sn_b   = (const float*)d_in[9];
    const float* Wqkv_t = (const float*)d_in[10];
    const float* bqkv_t = (const float*)d_in[11];
    const float* Wo_t   = (const float*)d_in[12];
    const float* bo_t   = (const float*)d_in[13];
    const float* tn_g   = (const float*)d_in[14];
    const float* tn_b   = (const float*)d_in[15];
    const float* W1     = (const float*)d_in[16];
    const float* b1     = (const float*)d_in[17];
    const float* W2     = (const float*)d_in[18];
    const float* b2     = (const float*)d_in[19];
    const float* Wout   = (const float*)d_in[20];
    const float* bout   = (const float*)d_in[21];
    float* out = (float*)d_out;

    const size_t RH = (size_t)TROWS * TH;   // 737280
    float* f = (float*)d_ws;
    float* cbuf  = f;                    // 51840
    float* x0    = cbuf + 51840;
    float* Kbase = x0 + RH;              // 4*RH
    float* Vbase = Kbase + 4 * RH;       // 4*RH
    float* r     = Vbase + 4 * RH;
    float* Qp2   = r + RH;
    float* Qs    = Qp2 + RH;
    float* Ks    = Qs + RH;
    float* Vs    = Ks + RH;
    float* Qt    = Vs + RH;
    float* Kt    = Qt + RH;
    float* Vt    = Kt + RH;
    float* Bb0   = Vt + RH;
    float* Bb1   = Bb0 + RH;
    short* sbase   = (short*)(Bb1 + RH);
    short* x0bf    = sbase;
    short* rbf     = x0bf + RH;
    short* attnb_c = rbf + RH;
    short* attnb_s = attnb_c + RH;
    short* attnb_t = attnb_s + RH;
    short* yball   = attnb_t + RH;       // 2*RH (part2 lower, part3 upper)
    short* fball   = yball + 2 * RH;     // 2*TROWS*TF
    short* Bb0bf   = fball + 2 * (size_t)TROWS * TF;
    short* Bb1bf   = Bb0bf + RH;
    short* wbf     = Bb1bf + RH;         // NW_TOT shorts

    const short* wqkvs_bf = wbf;
    const short* wos_bf   = wbf + OFF_O_S;
    const short* wqkvt_bf = wbf + OFF_QKV_T;
    const short* wot_bf   = wbf + OFF_O_T;
    const short* w1bf     = wbf + OFF_W1;
    const short* w2bf     = wbf + OFF_W2;

    // 0. weights -> bf16 + gather concat (fused)
    convgather_kernel<<<NB_CONV + NB_GATH, 256, 0, stream>>>(
        Wqkv_s, Wo_s, Wqkv_t, Wo_t, W1, W2, wbf, src, tgt, cbuf);

    // 1. embedding GEMM (+PE); writes x0/x0bf and r/rbf
    gemm_embed_kernel<<<dim3(4, 48), 256, 0, stream>>>(cbuf, Wemb, bemb, x0, x0bf, r, rbf);

    // 2+3. per-layer mega launches
    const float* Binf = x0;
    const short* Binbf = x0bf;
    for (int l = 0; l < 4; ++l) {
        int p2n = (l < 3) ? 6 : 4;
        int n0base = (l < 3) ? 0 : 128;
        int ncausal = (l < 3) ? 768 : 0;
        int np2 = (l < 3) ? 360 : 0;
        const short* wt_l = wqkvt_bf + (size_t)l * TJ * 3 * TH * TH;
        const short* ws_l = wqkvs_bf + (size_t)l * 3 * TH * TH;
        const float* bt_l = bqkv_t + (size_t)l * TJ * 3 * TH;
        const float* bs_l = bqkv_s + (size_t)l * 3 * TH;

        mfma_qkvmega_kernel<<<dim3(4, p2n + 12, 24), 256, 0, stream>>>(
            Binbf, rbf, wt_l, ws_l, bt_l, bs_l,
            Qp2, Kbase + l * RH, Vbase + l * RH,
            Qs, Ks, Vs, Qt, Kt, Vt, p2n, n0base);

        attn_mega_kernel<<<240 + ncausal + 768, 512, 0, stream>>>(
            Qp2, Kbase + l * RH, Vbase + l * RH,
            Qs, Ks, Vs, Qt, Kt, Vt,
            attnb_c, attnb_s, attnb_t, ncausal);

        mfma_olnfused_kernel<<<np2 + 360, 256, 0, stream>>>(
            attnb_c, wot_bf + (size_t)l * TJ * TH * TH, bo_t + (size_t)l * TJ * TH,
            Binf, tn_g + l * TH, tn_b + l * TH, yball,
            attnb_s, wos_bf + (size_t)l * TH * TH, bo_s + (size_t)l * TH,
            attnb_t, r, sn_g + l * TH, sn_b + l * TH, yball + RH, np2);

        if (l < 3) {
            mfma_ffn1_kernel<<<dim3(180, 4), 256, 0, stream>>>(
                yball, w1bf + (size_t)l * TF * TH, b1 + l * TF, fball);
            float* Boutf = (l & 1) ? Bb1 : Bb0;
            short* Boutbf = (l & 1) ? Bb1bf : Bb0bf;
            mfma_ffn2_kernel<<<dim3(180, 2), 256, 0, stream>>>(
                fball, w2bf + (size_t)l * TH * TF, b2 + l * TH,
                Boutf, Boutbf, r, rbf, TROWS);
            Binf = Boutf; Binbf = Boutbf;
        } else {
            mfma_ffn1_kernel<<<dim3(90, 4), 256, 0, stream>>>(
                yball + RH, w1bf + (size_t)l * TF * TH, b1 + l * TF, fball);
            mfma_ffn2_kernel<<<dim3(90, 2), 256, 0, stream>>>(
                fball, w2bf + (size_t)l * TH * TF, b2 + l * TH,
                r, rbf, r, rbf, 0);
        }
    }

    // 4. output projection + residual
    final_kernel<<<(TB * TW * TD + 255) / 256, 256, 0, stream>>>(r, Wout, bout, src, tgt, out);
}